// Round 10
// baseline (799.282 us; speedup 1.0000x reference)
//
#include <hip/hip_runtime.h>
#include <stdint.h>

#define B_TOT 131072
#define GAP_TAU 2.5e-4f

typedef short v8s __attribute__((ext_vector_type(8)));
typedef float v4f __attribute__((ext_vector_type(4)));

__device__ __forceinline__ unsigned short f2bf(float f) {
    union { float f; unsigned u; } v; v.f = f;
    unsigned u = v.u;
    u += 0x7fffu + ((u >> 16) & 1u);      // RNE
    return (unsigned short)(u >> 16);
}
__device__ __forceinline__ float bf2f(unsigned short s) {
    union { unsigned u; float f; } v; v.u = ((unsigned)s) << 16;
    return v.f;
}
__device__ __forceinline__ unsigned pack2(float lo, float hi) {
    return (unsigned)f2bf(lo) | ((unsigned)f2bf(hi) << 16);
}

// ---------------- K0: prep (weights swizzle + fcount zero) ----------------
__global__ void k_prep(const float* __restrict__ W_dh,
                       const float* __restrict__ b_do,
                       const float* __restrict__ dec_b,
                       const float* __restrict__ pre_bias,
                       const float* __restrict__ W_do,
                       const float* __restrict__ W_eh,
                       const float* __restrict__ W_eo,
                       float* __restrict__ WdhT,
                       float* __restrict__ bias3,
                       unsigned short* __restrict__ Wdo_frag,
                       unsigned short* __restrict__ WehHi,
                       unsigned short* __restrict__ WehLo,
                       unsigned short* __restrict__ WeoHi,
                       unsigned short* __restrict__ WeoLo,
                       float* __restrict__ spars_out,
                       int* __restrict__ fcount)
{
    int t = blockIdx.x * blockDim.x + threadIdx.x;
    int nthr = gridDim.x * blockDim.x;
    for (int i = t; i < 512 * 64; i += nthr) {
        int h = i >> 6, l = i & 63;
        WdhT[l * 512 + h] = W_dh[i];
    }
    for (int g = t; g < 16384; g += nthr) {     // Wdo B-frag
        int lane = g & 63;
        int q = g >> 6;
        int nt = q >> 4, kc = q & 15;
        int col = nt * 16 + (lane & 15);
        int kbase = kc * 32 + (lane >> 4) * 8;
        const float* src = &W_do[(size_t)col * 512 + kbase];
        unsigned short* dst = &Wdo_frag[(size_t)g * 8];
        #pragma unroll
        for (int i = 0; i < 8; i++) dst[i] = f2bf(src[i]);
    }
    for (int g = t; g < 32 * 8 * 64; g += nthr) {   // W_eh hi/lo A-frag
        int lane = g & 63;
        int rem = g >> 6;
        int kcg = rem & 7, ct = rem >> 3;
        int c = ct * 16 + (lane & 15);
        int k = kcg * 32 + (lane >> 4) * 8;
        const float* src = &W_eh[(size_t)c * 256 + k];
        #pragma unroll
        for (int i = 0; i < 8; i++) {
            unsigned short hi = f2bf(src[i]);
            WehHi[(size_t)g * 8 + i] = hi;
            WehLo[(size_t)g * 8 + i] = f2bf(src[i] - bf2f(hi));
        }
    }
    for (int g = t; g < 4 * 16 * 64; g += nthr) {   // W_eo hi/lo A-frag
        int lane = g & 63;
        int rem = g >> 6;
        int kcg = rem & 15, lt = rem >> 4;
        int l = lt * 16 + (lane & 15);
        int k = kcg * 32 + (lane >> 4) * 8;
        const float* src = &W_eo[(size_t)l * 512 + k];
        #pragma unroll
        for (int i = 0; i < 8; i++) {
            unsigned short hi = f2bf(src[i]);
            WeoHi[(size_t)g * 8 + i] = hi;
            WeoLo[(size_t)g * 8 + i] = f2bf(src[i] - bf2f(hi));
        }
    }
    if (t < 256) bias3[t] = b_do[t] + dec_b[t] + pre_bias[t];
    if (t == 0) { spars_out[0] = 5.0f / 64.0f; *fcount = 0; }
}

// h planes layout (writer-native, fully coalesced stores):
//   element index H(row,k) = ((rowtile*128 + k/4)*16 + row%16)*4 + k%4

// ---------------- K1: h = relu((x-pb) @ W_eh^T + b_eh), split-bf16 MFMA ----------------
__global__ __launch_bounds__(512, 2)
void k_enc1(const float* __restrict__ x,
            const float* __restrict__ pre_bias,
            const unsigned short* __restrict__ WehHi,
            const unsigned short* __restrict__ WehLo,
            const float* __restrict__ b_eh,
            unsigned short* __restrict__ hHi,   // tiled layout
            unsigned short* __restrict__ hLo)
{
    __shared__ __align__(16) unsigned short aH[8 * 4 * 64 * 8];  // 32 KB
    __shared__ __align__(16) unsigned short aL[8 * 4 * 64 * 8];  // 32 KB
    const int t    = threadIdx.x;
    const int lane = t & 63;
    const int w    = t >> 6;        // 0..7
    const int rb   = blockIdx.x * 64;

    #pragma unroll
    for (int i = 0; i < 4; i++) {
        const int f    = t + i * 512;       // 0..2047
        const int srow = f >> 5;            // 0..63
        const int kc   = (f >> 2) & 7;      // 0..7
        const int skq  = f & 3;             // 0..3
        const float* xp = &x[(size_t)(rb + srow) * 256 + kc * 32 + skq * 8];
        const float* pp = &pre_bias[kc * 32 + skq * 8];
        const float4 v0 = *reinterpret_cast<const float4*>(xp);
        const float4 v1 = *reinterpret_cast<const float4*>(xp + 4);
        const float4 p0 = *reinterpret_cast<const float4*>(pp);
        const float4 p1 = *reinterpret_cast<const float4*>(pp + 4);
        float fv[8] = {v0.x - p0.x, v0.y - p0.y, v0.z - p0.z, v0.w - p0.w,
                       v1.x - p1.x, v1.y - p1.y, v1.z - p1.z, v1.w - p1.w};
        unsigned hi2[4], lo2[4];
        #pragma unroll
        for (int q = 0; q < 4; q++) {
            unsigned short h0 = f2bf(fv[q * 2]), h1 = f2bf(fv[q * 2 + 1]);
            hi2[q] = (unsigned)h0 | ((unsigned)h1 << 16);
            lo2[q] = (unsigned)f2bf(fv[q * 2] - bf2f(h0)) | ((unsigned)f2bf(fv[q * 2 + 1] - bf2f(h1)) << 16);
        }
        const int mt = srow >> 4;
        const int ln = skq * 16 + (srow & 15);
        *reinterpret_cast<uint4*>(&aH[((kc * 4 + mt) * 64 + ln) * 8]) = *reinterpret_cast<uint4*>(hi2);
        *reinterpret_cast<uint4*>(&aL[((kc * 4 + mt) * 64 + ln) * 8]) = *reinterpret_cast<uint4*>(lo2);
    }
    __syncthreads();

    v4f acc[4][4];
    #pragma unroll
    for (int i = 0; i < 4; i++)
        #pragma unroll
        for (int j = 0; j < 4; j++) acc[i][j] = (v4f){0.f, 0.f, 0.f, 0.f};

    #pragma unroll 2
    for (int kc = 0; kc < 8; ++kc) {
        v8s wh[4], wl[4];
        #pragma unroll
        for (int ntl = 0; ntl < 4; ntl++) {
            const int ct = w * 4 + ntl;
            const size_t idx = ((size_t)(ct * 8 + kc) * 64 + lane) * 8;
            wh[ntl] = *reinterpret_cast<const v8s*>(&WehHi[idx]);
            wl[ntl] = *reinterpret_cast<const v8s*>(&WehLo[idx]);
        }
        v8s ah[4], al[4];
        #pragma unroll
        for (int mt = 0; mt < 4; mt++) {
            const int off = ((kc * 4 + mt) * 64 + lane) * 8;
            ah[mt] = *reinterpret_cast<const v8s*>(&aH[off]);
            al[mt] = *reinterpret_cast<const v8s*>(&aL[off]);
        }
        #pragma unroll
        for (int mt = 0; mt < 4; mt++) {
            #pragma unroll
            for (int ntl = 0; ntl < 4; ntl++) {
                acc[mt][ntl] = __builtin_amdgcn_mfma_f32_16x16x32_bf16(wh[ntl], ah[mt], acc[mt][ntl], 0, 0, 0);
                acc[mt][ntl] = __builtin_amdgcn_mfma_f32_16x16x32_bf16(wl[ntl], ah[mt], acc[mt][ntl], 0, 0, 0);
                acc[mt][ntl] = __builtin_amdgcn_mfma_f32_16x16x32_bf16(wh[ntl], al[mt], acc[mt][ntl], 0, 0, 0);
            }
        }
    }
    const int rt0 = rb >> 4;
    #pragma unroll
    for (int mt = 0; mt < 4; mt++) {
        #pragma unroll
        for (int ntl = 0; ntl < 4; ntl++) {
            const int c = w * 64 + ntl * 16 + (lane >> 4) * 4;
            const float4 be = *reinterpret_cast<const float4*>(&b_eh[c]);
            float h0 = fmaxf(acc[mt][ntl][0] + be.x, 0.f);
            float h1 = fmaxf(acc[mt][ntl][1] + be.y, 0.f);
            float h2 = fmaxf(acc[mt][ntl][2] + be.z, 0.f);
            float h3 = fmaxf(acc[mt][ntl][3] + be.w, 0.f);
            unsigned short s0 = f2bf(h0), s1 = f2bf(h1), s2 = f2bf(h2), s3 = f2bf(h3);
            uint2 phi = { (unsigned)s0 | ((unsigned)s1 << 16), (unsigned)s2 | ((unsigned)s3 << 16) };
            uint2 plo = { (unsigned)f2bf(h0 - bf2f(s0)) | ((unsigned)f2bf(h1 - bf2f(s1)) << 16),
                          (unsigned)f2bf(h2 - bf2f(s2)) | ((unsigned)f2bf(h3 - bf2f(s3)) << 16) };
            const int cg = w * 16 + ntl * 4 + (lane >> 4);
            const size_t base = ((size_t)((rt0 + mt) * 128 + cg) * 16 + (lane & 15)) * 4;
            *reinterpret_cast<uint2*>(&hHi[base]) = phi;
            *reinterpret_cast<uint2*>(&hLo[base]) = plo;
        }
    }
}

// ---------------- K2: pre_act (split-bf16 MFMA); top-5; gap-flag; outputs ----------------
__global__ __launch_bounds__(256, 4)
void k_enc2_topk(const unsigned short* __restrict__ hHi,   // tiled layout
                 const unsigned short* __restrict__ hLo,
                 const unsigned short* __restrict__ WeoHi,
                 const unsigned short* __restrict__ WeoLo,
                 const float* __restrict__ b_eo,
                 const float* __restrict__ lat_b,
                 float* __restrict__ pre_out,
                 float* __restrict__ mask_out,
                 float* __restrict__ sl_out,
                 float* __restrict__ t5v,          // global [B][5]
                 int*   __restrict__ t5i,
                 int*   __restrict__ fcount,
                 int*   __restrict__ flist)
{
    __shared__ float pa[64][68];
    __shared__ unsigned long long mbits[64];
    const int t    = threadIdx.x;
    const int lane = t & 63;
    const int w    = t >> 6;
    const int rb   = blockIdx.x * 64;
    const int rt   = (rb >> 4) + w;

    v4f acc[4];
    #pragma unroll
    for (int i = 0; i < 4; i++) acc[i] = (v4f){0.f, 0.f, 0.f, 0.f};

    #pragma unroll 2
    for (int kcl = 0; kcl < 16; ++kcl) {
        const int cg = kcl * 8 + (lane >> 4) * 2;
        const size_t b1 = ((size_t)(rt * 128 + cg) * 16 + (lane & 15)) * 4;
        union { uint4 u; v8s v; } hh, hl;
        {
            const uint2 a0 = *reinterpret_cast<const uint2*>(&hHi[b1]);
            const uint2 a1 = *reinterpret_cast<const uint2*>(&hHi[b1 + 64]);
            hh.u = (uint4){a0.x, a0.y, a1.x, a1.y};
            const uint2 c0 = *reinterpret_cast<const uint2*>(&hLo[b1]);
            const uint2 c1 = *reinterpret_cast<const uint2*>(&hLo[b1 + 64]);
            hl.u = (uint4){c0.x, c0.y, c1.x, c1.y};
        }
        #pragma unroll
        for (int lt = 0; lt < 4; lt++) {
            const size_t idx = ((size_t)(lt * 16 + kcl) * 64 + lane) * 8;
            const v8s wh = *reinterpret_cast<const v8s*>(&WeoHi[idx]);
            const v8s wl = *reinterpret_cast<const v8s*>(&WeoLo[idx]);
            acc[lt] = __builtin_amdgcn_mfma_f32_16x16x32_bf16(wh, hh.v, acc[lt], 0, 0, 0);
            acc[lt] = __builtin_amdgcn_mfma_f32_16x16x32_bf16(wl, hh.v, acc[lt], 0, 0, 0);
            acc[lt] = __builtin_amdgcn_mfma_f32_16x16x32_bf16(wh, hl.v, acc[lt], 0, 0, 0);
        }
    }
    #pragma unroll
    for (int lt = 0; lt < 4; lt++) {
        const int l0 = lt * 16 + ((lane >> 4) << 2);
        const float4 be = *reinterpret_cast<const float4*>(&b_eo[l0]);
        const float4 lb = *reinterpret_cast<const float4*>(&lat_b[l0]);
        float4 o;
        o.x = acc[lt][0] + be.x + lb.x;
        o.y = acc[lt][1] + be.y + lb.y;
        o.z = acc[lt][2] + be.z + lb.z;
        o.w = acc[lt][3] + be.w + lb.w;
        *reinterpret_cast<float4*>(&pa[w * 16 + (lane & 15)][l0]) = o;
    }
    __syncthreads();
    if (t < 64) {
        int r = t;
        unsigned long long used = 0ULL;
        float bv[5]; int bi[5];
        #pragma unroll
        for (int p = 0; p < 5; p++) {
            float best = -3.402823466e38f; int bidx = 0;
            for (int j = 0; j < 64; j++) {
                float v = pa[r][j];
                if (!((used >> j) & 1ULL) && v > best) { best = v; bidx = j; }
            }
            used |= 1ULL << bidx;
            bv[p] = best; bi[p] = bidx;
        }
        mbits[r] = used;
        size_t gr = (size_t)(rb + r);
        #pragma unroll
        for (int p = 0; p < 5; p++) { t5v[gr * 5 + p] = bv[p]; t5i[gr * 5 + p] = bi[p]; }
        float v6 = -3.402823466e38f;
        for (int j = 0; j < 64; j++) {
            float v = pa[r][j];
            if (!((used >> j) & 1ULL) && v > v6) v6 = v;
        }
        if (bv[4] - v6 < GAP_TAU) {
            int slot = atomicAdd(fcount, 1);
            flist[slot] = rb + r;
        }
    }
    __syncthreads();
    {
        int row = t >> 2, c0 = (t & 3) * 16;
        size_t gr = (size_t)(rb + row);
        unsigned long long bits = mbits[row];
        #pragma unroll
        for (int g = 0; g < 4; g++) {
            int c = c0 + g * 4;
            float p0 = pa[row][c + 0], p1 = pa[row][c + 1], p2 = pa[row][c + 2], p3 = pa[row][c + 3];
            float m0 = (float)((bits >> (c + 0)) & 1ULL);
            float m1 = (float)((bits >> (c + 1)) & 1ULL);
            float m2 = (float)((bits >> (c + 2)) & 1ULL);
            float m3 = (float)((bits >> (c + 3)) & 1ULL);
            float4 pv = {p0, p1, p2, p3};
            float4 mv = {m0, m1, m2, m3};
            float4 sv = {m0 * p0, m1 * p1, m2 * p2, m3 * p3};
            *reinterpret_cast<float4*>(&pre_out[gr * 64 + c])  = pv;
            *reinterpret_cast<float4*>(&mask_out[gr * 64 + c]) = mv;
            *reinterpret_cast<float4*>(&sl_out[gr * 64 + c])   = sv;
        }
    }
}

// ---------------- K2b: fp32 exact repair of gap-flagged rows ----------------
__global__ __launch_bounds__(256)
void k_repair(const float* __restrict__ x,
              const float* __restrict__ pre_bias,
              const float* __restrict__ W_eh,     // [512][256]
              const float* __restrict__ b_eh,
              const float* __restrict__ W_eo,     // [64][512]
              const float* __restrict__ b_eo,
              const float* __restrict__ lat_b,
              const int* __restrict__ fcount,
              const int* __restrict__ flist,
              float* __restrict__ pre_out,
              float* __restrict__ mask_out,
              float* __restrict__ sl_out,
              float* __restrict__ t5v,
              int*   __restrict__ t5i)
{
    __shared__ float xs[256];
    __shared__ float hs[512];
    __shared__ float part[64][4];
    __shared__ float pav[64];
    __shared__ unsigned long long bitsS;
    const int t = threadIdx.x;
    const int n = *fcount;
    #pragma unroll 1
    for (int it = blockIdx.x; it < n; it += gridDim.x) {
        const int r = flist[it];
        xs[t] = x[(size_t)r * 256 + t] - pre_bias[t];
        __syncthreads();
        #pragma unroll 1
        for (int j = t; j < 512; j += 256) {
            const float* wr = &W_eh[(size_t)j * 256];
            float acc = 0.f;
            #pragma unroll
            for (int k = 0; k < 256; k += 4) {
                const float4 wv = *reinterpret_cast<const float4*>(&wr[k]);
                acc = fmaf(wv.x, xs[k + 0], acc);
                acc = fmaf(wv.y, xs[k + 1], acc);
                acc = fmaf(wv.z, xs[k + 2], acc);
                acc = fmaf(wv.w, xs[k + 3], acc);
            }
            hs[j] = fmaxf(acc + b_eh[j], 0.f);
        }
        __syncthreads();
        {
            const int l = t & 63, q = t >> 6;
            const float* wr = &W_eo[(size_t)l * 512 + q * 128];
            const float* hp = &hs[q * 128];
            float acc = 0.f;
            #pragma unroll
            for (int k = 0; k < 128; k += 4) {
                const float4 wv = *reinterpret_cast<const float4*>(&wr[k]);
                acc = fmaf(wv.x, hp[k + 0], acc);
                acc = fmaf(wv.y, hp[k + 1], acc);
                acc = fmaf(wv.z, hp[k + 2], acc);
                acc = fmaf(wv.w, hp[k + 3], acc);
            }
            part[l][q] = acc;
        }
        __syncthreads();
        if (t < 64)
            pav[t] = ((part[t][0] + part[t][1]) + (part[t][2] + part[t][3])) + b_eo[t] + lat_b[t];
        __syncthreads();
        if (t == 0) {
            unsigned long long used = 0ULL;
            const size_t gr = (size_t)r;
            #pragma unroll
            for (int p = 0; p < 5; p++) {
                float best = -3.402823466e38f; int bidx = 0;
                for (int j = 0; j < 64; j++) {
                    float v = pav[j];
                    if (!((used >> j) & 1ULL) && v > best) { best = v; bidx = j; }
                }
                used |= 1ULL << bidx;
                t5v[gr * 5 + p] = best; t5i[gr * 5 + p] = bidx;
            }
            bitsS = used;
        }
        __syncthreads();
        if (t < 64) {
            const size_t gr = (size_t)r;
            const float v = pav[t];
            const float m = (float)((bitsS >> t) & 1ULL);
            pre_out[gr * 64 + t]  = v;
            mask_out[gr * 64 + t] = m;
            sl_out[gr * 64 + t]   = m * v;
        }
        __syncthreads();
    }
}

// ---------------- K3: recon via bf16 MFMA, register-built A-fragments ----------------
// Block 256 thr = 4 waves over 32 rows x 256 cols. Wave w: rows (w>>1)*16..+16,
// cols (w&1)*128..+128. Lane builds its OWN A-frag elements (row=lane&15,
// k=(lane>>4)*8+i) from WdhT gathers -- no LDS staging, no inner barriers.
__global__ __launch_bounds__(256)
void k_dec(const float* __restrict__ t5v, const int* __restrict__ t5i,
           const float* __restrict__ WdhT,        // [64][512] fp32
           const float* __restrict__ b_dh,
           const unsigned short* __restrict__ Wdo_frag,
           const float* __restrict__ bias3,
           float* __restrict__ recon)             // global [B][256]
{
    __shared__ float svv[32][5];
    __shared__ int   sii[32][5];
    const int t    = threadIdx.x;
    const int rb   = blockIdx.x * 32;
    const int lane = t & 63;
    const int w    = t >> 6;

    if (t < 160) {
        int rr = t / 5, p = t % 5;
        size_t lr = (size_t)(rb + rr);
        svv[rr][p] = t5v[lr * 5 + p];
        sii[rr][p] = t5i[lr * 5 + p];
    }
    __syncthreads();

    const int rs = (w >> 1) * 16;       // row strip within block
    const int ch = (w & 1) * 128;       // col half
    const int r  = rs + (lane & 15);    // local row this lane builds
    const int ks = (lane >> 4) * 8;     // k sub-slice

    float vv[5]; int ii[5];
    #pragma unroll
    for (int p = 0; p < 5; p++) { vv[p] = svv[r][p]; ii[p] = sii[r][p]; }

    v4f acc[8];
    #pragma unroll
    for (int i = 0; i < 8; i++) acc[i] = (v4f){0.f, 0.f, 0.f, 0.f};

    #pragma unroll 1
    for (int c = 0; c < 4; ++c) {
        #pragma unroll
        for (int kcl = 0; kcl < 4; ++kcl) {
            const int kcg = c * 4 + kcl;
            const int k0  = kcg * 32 + ks;
            float a[8];
            {
                const float4 b0 = *reinterpret_cast<const float4*>(&b_dh[k0]);
                const float4 b1 = *reinterpret_cast<const float4*>(&b_dh[k0 + 4]);
                a[0] = b0.x; a[1] = b0.y; a[2] = b0.z; a[3] = b0.w;
                a[4] = b1.x; a[5] = b1.y; a[6] = b1.z; a[7] = b1.w;
            }
            #pragma unroll
            for (int p = 0; p < 5; p++) {
                const float s = vv[p];
                const float4* wp = reinterpret_cast<const float4*>(&WdhT[(size_t)ii[p] * 512 + k0]);
                const float4 w0 = wp[0];
                const float4 w1 = wp[1];
                a[0] = fmaf(s, w0.x, a[0]); a[1] = fmaf(s, w0.y, a[1]);
                a[2] = fmaf(s, w0.z, a[2]); a[3] = fmaf(s, w0.w, a[3]);
                a[4] = fmaf(s, w1.x, a[4]); a[5] = fmaf(s, w1.y, a[5]);
                a[6] = fmaf(s, w1.z, a[6]); a[7] = fmaf(s, w1.w, a[7]);
            }
            union { unsigned u[4]; v8s v; } af;
            af.u[0] = pack2(fmaxf(a[0], 0.f), fmaxf(a[1], 0.f));
            af.u[1] = pack2(fmaxf(a[2], 0.f), fmaxf(a[3], 0.f));
            af.u[2] = pack2(fmaxf(a[4], 0.f), fmaxf(a[5], 0.f));
            af.u[3] = pack2(fmaxf(a[6], 0.f), fmaxf(a[7], 0.f));
            #pragma unroll
            for (int ntl = 0; ntl < 8; ntl++) {
                const int ntg = (ch >> 4) + ntl;
                const v8s bf = *reinterpret_cast<const v8s*>(
                    Wdo_frag + ((size_t)(ntg * 16 + kcg) * 64 + lane) * 8);
                acc[ntl] = __builtin_amdgcn_mfma_f32_16x16x32_bf16(af.v, bf, acc[ntl], 0, 0, 0);
            }
        }
    }
    // epilogue: D col=lane&15 (Wdo col), row=(lane>>4)*4+j (hd row)
    const int rowbase = rb + rs;
    #pragma unroll
    for (int ntl = 0; ntl < 8; ntl++) {
        const int col = ch + ntl * 16 + (lane & 15);
        const float bz = bias3[col];
        #pragma unroll
        for (int j = 0; j < 4; j++) {
            const size_t row = (size_t)(rowbase + (lane >> 4) * 4 + j);
            recon[row * 256 + col] = acc[ntl][j] + bz;
        }
    }
}

// ---------------- host ----------------
extern "C" void kernel_launch(void* const* d_in, const int* in_sizes, int n_in,
                              void* d_out, int out_size, void* d_ws, size_t ws_size,
                              hipStream_t stream)
{
    const float* x        = (const float*)d_in[0];
    const float* pre_bias = (const float*)d_in[1];
    const float* W_eh     = (const float*)d_in[2];
    const float* b_eh     = (const float*)d_in[3];
    const float* W_eo     = (const float*)d_in[4];
    const float* b_eo     = (const float*)d_in[5];
    const float* lat_b    = (const float*)d_in[6];
    const float* W_dh     = (const float*)d_in[7];
    const float* b_dh     = (const float*)d_in[8];
    const float* W_do     = (const float*)d_in[9];
    const float* b_do     = (const float*)d_in[10];
    const float* dec_b    = (const float*)d_in[11];

    float* out = (float*)d_out;
    float* recon_out = out;
    float* sl_out    = out + (size_t)B_TOT * 256;
    float* pre_out   = sl_out + (size_t)B_TOT * 64;
    float* mask_out  = pre_out + (size_t)B_TOT * 64;
    float* spars_out = mask_out + (size_t)B_TOT * 64;

    char* ws = (char*)d_ws;
    float* WdhT           = (float*)ws;
    float* bias3          = (float*)(ws + 131072);
    unsigned short* WdoF  = (unsigned short*)(ws + 132096);
    unsigned short* WehHi = (unsigned short*)(ws + 394240);
    unsigned short* WehLo = (unsigned short*)(ws + 656384);
    unsigned short* WeoHi = (unsigned short*)(ws + 918528);
    unsigned short* WeoLo = (unsigned short*)(ws + 984064);
    int* fcount           = (int*)(ws + 1049600);
    int* flist            = (int*)(ws + 1049664);
    float* t5v            = (float*)(ws + 1049664 + 524288);
    int*   t5i            = (int*)  (ws + 1049664 + 524288 + (size_t)B_TOT * 20);
    unsigned short* hHi   = (unsigned short*)(ws + 1049664 + 524288 + (size_t)B_TOT * 40);
    unsigned short* hLo   = hHi + (size_t)B_TOT * 512;

    k_prep<<<32, 256, 0, stream>>>(W_dh, b_do, dec_b, pre_bias, W_do, W_eh, W_eo,
                                   WdhT, bias3, WdoF, WehHi, WehLo, WeoHi, WeoLo,
                                   spars_out, fcount);

    k_enc1<<<B_TOT / 64, 512, 0, stream>>>(x, pre_bias, WehHi, WehLo, b_eh, hHi, hLo);

    k_enc2_topk<<<B_TOT / 64, 256, 0, stream>>>(hHi, hLo, WeoHi, WeoLo, b_eo, lat_b,
                                                pre_out, mask_out, sl_out, t5v, t5i,
                                                fcount, flist);

    k_repair<<<256, 256, 0, stream>>>(x, pre_bias, W_eh, b_eh, W_eo, b_eo, lat_b,
                                      fcount, flist, pre_out, mask_out, sl_out,
                                      t5v, t5i);

    k_dec<<<B_TOT / 32, 256, 0, stream>>>(t5v, t5i, WdhT, b_dh, WdoF, bias3, recon_out);
}

// Round 11
// 658.039 us; speedup vs baseline: 1.2146x; 1.2146x over previous
//
#include <hip/hip_runtime.h>
#include <stdint.h>

#define B_TOT 131072
#define GAP_TAU 2.5e-4f

typedef short v8s __attribute__((ext_vector_type(8)));
typedef float v4f __attribute__((ext_vector_type(4)));

__device__ __forceinline__ unsigned short f2bf(float f) {
    union { float f; unsigned u; } v; v.f = f;
    unsigned u = v.u;
    u += 0x7fffu + ((u >> 16) & 1u);      // RNE
    return (unsigned short)(u >> 16);
}
__device__ __forceinline__ float bf2f(unsigned short s) {
    union { unsigned u; float f; } v; v.u = ((unsigned)s) << 16;
    return v.f;
}
__device__ __forceinline__ unsigned pack2(float lo, float hi) {
    return (unsigned)f2bf(lo) | ((unsigned)f2bf(hi) << 16);
}

// ---------------- K0: prep (weights swizzle + fcount zero) ----------------
__global__ void k_prep(const float* __restrict__ W_dh,
                       const float* __restrict__ b_do,
                       const float* __restrict__ dec_b,
                       const float* __restrict__ pre_bias,
                       const float* __restrict__ W_do,
                       const float* __restrict__ W_eh,
                       const float* __restrict__ W_eo,
                       unsigned short* __restrict__ WdhTb,   // bf16 [64][512]
                       float* __restrict__ bias3,
                       unsigned short* __restrict__ Wdo_frag,
                       unsigned short* __restrict__ WehHi,
                       unsigned short* __restrict__ WehLo,
                       unsigned short* __restrict__ WeoHi,
                       unsigned short* __restrict__ WeoLo,
                       float* __restrict__ spars_out,
                       int* __restrict__ fcount)
{
    int t = blockIdx.x * blockDim.x + threadIdx.x;
    int nthr = gridDim.x * blockDim.x;
    for (int i = t; i < 512 * 64; i += nthr) {
        int h = i >> 6, l = i & 63;
        WdhTb[l * 512 + h] = f2bf(W_dh[i]);
    }
    for (int g = t; g < 16384; g += nthr) {     // Wdo B-frag
        int lane = g & 63;
        int q = g >> 6;
        int nt = q >> 4, kc = q & 15;
        int col = nt * 16 + (lane & 15);
        int kbase = kc * 32 + (lane >> 4) * 8;
        const float* src = &W_do[(size_t)col * 512 + kbase];
        unsigned short* dst = &Wdo_frag[(size_t)g * 8];
        #pragma unroll
        for (int i = 0; i < 8; i++) dst[i] = f2bf(src[i]);
    }
    for (int g = t; g < 32 * 8 * 64; g += nthr) {   // W_eh hi/lo A-frag
        int lane = g & 63;
        int rem = g >> 6;
        int kcg = rem & 7, ct = rem >> 3;
        int c = ct * 16 + (lane & 15);
        int k = kcg * 32 + (lane >> 4) * 8;
        const float* src = &W_eh[(size_t)c * 256 + k];
        #pragma unroll
        for (int i = 0; i < 8; i++) {
            unsigned short hi = f2bf(src[i]);
            WehHi[(size_t)g * 8 + i] = hi;
            WehLo[(size_t)g * 8 + i] = f2bf(src[i] - bf2f(hi));
        }
    }
    for (int g = t; g < 4 * 16 * 64; g += nthr) {   // W_eo hi/lo A-frag
        int lane = g & 63;
        int rem = g >> 6;
        int kcg = rem & 15, lt = rem >> 4;
        int l = lt * 16 + (lane & 15);
        int k = kcg * 32 + (lane >> 4) * 8;
        const float* src = &W_eo[(size_t)l * 512 + k];
        #pragma unroll
        for (int i = 0; i < 8; i++) {
            unsigned short hi = f2bf(src[i]);
            WeoHi[(size_t)g * 8 + i] = hi;
            WeoLo[(size_t)g * 8 + i] = f2bf(src[i] - bf2f(hi));
        }
    }
    if (t < 256) bias3[t] = b_do[t] + dec_b[t] + pre_bias[t];
    if (t == 0) { spars_out[0] = 5.0f / 64.0f; *fcount = 0; }
}

// h planes layout (writer-native, fully coalesced stores):
//   element index H(row,k) = ((rowtile*128 + k/4)*16 + row%16)*4 + k%4

// ---------------- K1: h = relu((x-pb) @ W_eh^T + b_eh), split-bf16 MFMA ----------------
__global__ __launch_bounds__(512, 2)
void k_enc1(const float* __restrict__ x,
            const float* __restrict__ pre_bias,
            const unsigned short* __restrict__ WehHi,
            const unsigned short* __restrict__ WehLo,
            const float* __restrict__ b_eh,
            unsigned short* __restrict__ hHi,   // tiled layout
            unsigned short* __restrict__ hLo)
{
    __shared__ __align__(16) unsigned short aH[8 * 4 * 64 * 8];  // 32 KB
    __shared__ __align__(16) unsigned short aL[8 * 4 * 64 * 8];  // 32 KB
    const int t    = threadIdx.x;
    const int lane = t & 63;
    const int w    = t >> 6;        // 0..7
    const int rb   = blockIdx.x * 64;

    #pragma unroll
    for (int i = 0; i < 4; i++) {
        const int f    = t + i * 512;       // 0..2047
        const int srow = f >> 5;            // 0..63
        const int kc   = (f >> 2) & 7;      // 0..7
        const int skq  = f & 3;             // 0..3
        const float* xp = &x[(size_t)(rb + srow) * 256 + kc * 32 + skq * 8];
        const float* pp = &pre_bias[kc * 32 + skq * 8];
        const float4 v0 = *reinterpret_cast<const float4*>(xp);
        const float4 v1 = *reinterpret_cast<const float4*>(xp + 4);
        const float4 p0 = *reinterpret_cast<const float4*>(pp);
        const float4 p1 = *reinterpret_cast<const float4*>(pp + 4);
        float fv[8] = {v0.x - p0.x, v0.y - p0.y, v0.z - p0.z, v0.w - p0.w,
                       v1.x - p1.x, v1.y - p1.y, v1.z - p1.z, v1.w - p1.w};
        unsigned hi2[4], lo2[4];
        #pragma unroll
        for (int q = 0; q < 4; q++) {
            unsigned short h0 = f2bf(fv[q * 2]), h1 = f2bf(fv[q * 2 + 1]);
            hi2[q] = (unsigned)h0 | ((unsigned)h1 << 16);
            lo2[q] = (unsigned)f2bf(fv[q * 2] - bf2f(h0)) | ((unsigned)f2bf(fv[q * 2 + 1] - bf2f(h1)) << 16);
        }
        const int mt = srow >> 4;
        const int ln = skq * 16 + (srow & 15);
        *reinterpret_cast<uint4*>(&aH[((kc * 4 + mt) * 64 + ln) * 8]) = *reinterpret_cast<uint4*>(hi2);
        *reinterpret_cast<uint4*>(&aL[((kc * 4 + mt) * 64 + ln) * 8]) = *reinterpret_cast<uint4*>(lo2);
    }
    __syncthreads();

    v4f acc[4][4];
    #pragma unroll
    for (int i = 0; i < 4; i++)
        #pragma unroll
        for (int j = 0; j < 4; j++) acc[i][j] = (v4f){0.f, 0.f, 0.f, 0.f};

    #pragma unroll 2
    for (int kc = 0; kc < 8; ++kc) {
        v8s wh[4], wl[4];
        #pragma unroll
        for (int ntl = 0; ntl < 4; ntl++) {
            const int ct = w * 4 + ntl;
            const size_t idx = ((size_t)(ct * 8 + kc) * 64 + lane) * 8;
            wh[ntl] = *reinterpret_cast<const v8s*>(&WehHi[idx]);
            wl[ntl] = *reinterpret_cast<const v8s*>(&WehLo[idx]);
        }
        v8s ah[4], al[4];
        #pragma unroll
        for (int mt = 0; mt < 4; mt++) {
            const int off = ((kc * 4 + mt) * 64 + lane) * 8;
            ah[mt] = *reinterpret_cast<const v8s*>(&aH[off]);
            al[mt] = *reinterpret_cast<const v8s*>(&aL[off]);
        }
        #pragma unroll
        for (int mt = 0; mt < 4; mt++) {
            #pragma unroll
            for (int ntl = 0; ntl < 4; ntl++) {
                acc[mt][ntl] = __builtin_amdgcn_mfma_f32_16x16x32_bf16(wh[ntl], ah[mt], acc[mt][ntl], 0, 0, 0);
                acc[mt][ntl] = __builtin_amdgcn_mfma_f32_16x16x32_bf16(wl[ntl], ah[mt], acc[mt][ntl], 0, 0, 0);
                acc[mt][ntl] = __builtin_amdgcn_mfma_f32_16x16x32_bf16(wh[ntl], al[mt], acc[mt][ntl], 0, 0, 0);
            }
        }
    }
    const int rt0 = rb >> 4;
    #pragma unroll
    for (int mt = 0; mt < 4; mt++) {
        #pragma unroll
        for (int ntl = 0; ntl < 4; ntl++) {
            const int c = w * 64 + ntl * 16 + (lane >> 4) * 4;
            const float4 be = *reinterpret_cast<const float4*>(&b_eh[c]);
            float h0 = fmaxf(acc[mt][ntl][0] + be.x, 0.f);
            float h1 = fmaxf(acc[mt][ntl][1] + be.y, 0.f);
            float h2 = fmaxf(acc[mt][ntl][2] + be.z, 0.f);
            float h3 = fmaxf(acc[mt][ntl][3] + be.w, 0.f);
            unsigned short s0 = f2bf(h0), s1 = f2bf(h1), s2 = f2bf(h2), s3 = f2bf(h3);
            uint2 phi = { (unsigned)s0 | ((unsigned)s1 << 16), (unsigned)s2 | ((unsigned)s3 << 16) };
            uint2 plo = { (unsigned)f2bf(h0 - bf2f(s0)) | ((unsigned)f2bf(h1 - bf2f(s1)) << 16),
                          (unsigned)f2bf(h2 - bf2f(s2)) | ((unsigned)f2bf(h3 - bf2f(s3)) << 16) };
            const int cg = w * 16 + ntl * 4 + (lane >> 4);
            const size_t base = ((size_t)((rt0 + mt) * 128 + cg) * 16 + (lane & 15)) * 4;
            *reinterpret_cast<uint2*>(&hHi[base]) = phi;
            *reinterpret_cast<uint2*>(&hLo[base]) = plo;
        }
    }
}

// ---------------- K2: pre_act (split-bf16 MFMA); top-5; gap-flag; outputs ----------------
__global__ __launch_bounds__(256, 4)
void k_enc2_topk(const unsigned short* __restrict__ hHi,   // tiled layout
                 const unsigned short* __restrict__ hLo,
                 const unsigned short* __restrict__ WeoHi,
                 const unsigned short* __restrict__ WeoLo,
                 const float* __restrict__ b_eo,
                 const float* __restrict__ lat_b,
                 float* __restrict__ pre_out,
                 float* __restrict__ mask_out,
                 float* __restrict__ sl_out,
                 float* __restrict__ t5v,          // global [B][5]
                 int*   __restrict__ t5i,
                 int*   __restrict__ fcount,
                 int*   __restrict__ flist)
{
    __shared__ float pa[64][68];
    __shared__ unsigned long long mbits[64];
    const int t    = threadIdx.x;
    const int lane = t & 63;
    const int w    = t >> 6;
    const int rb   = blockIdx.x * 64;
    const int rt   = (rb >> 4) + w;

    v4f acc[4];
    #pragma unroll
    for (int i = 0; i < 4; i++) acc[i] = (v4f){0.f, 0.f, 0.f, 0.f};

    #pragma unroll 2
    for (int kcl = 0; kcl < 16; ++kcl) {
        const int cg = kcl * 8 + (lane >> 4) * 2;
        const size_t b1 = ((size_t)(rt * 128 + cg) * 16 + (lane & 15)) * 4;
        union { uint4 u; v8s v; } hh, hl;
        {
            const uint2 a0 = *reinterpret_cast<const uint2*>(&hHi[b1]);
            const uint2 a1 = *reinterpret_cast<const uint2*>(&hHi[b1 + 64]);
            hh.u = (uint4){a0.x, a0.y, a1.x, a1.y};
            const uint2 c0 = *reinterpret_cast<const uint2*>(&hLo[b1]);
            const uint2 c1 = *reinterpret_cast<const uint2*>(&hLo[b1 + 64]);
            hl.u = (uint4){c0.x, c0.y, c1.x, c1.y};
        }
        #pragma unroll
        for (int lt = 0; lt < 4; lt++) {
            const size_t idx = ((size_t)(lt * 16 + kcl) * 64 + lane) * 8;
            const v8s wh = *reinterpret_cast<const v8s*>(&WeoHi[idx]);
            const v8s wl = *reinterpret_cast<const v8s*>(&WeoLo[idx]);
            acc[lt] = __builtin_amdgcn_mfma_f32_16x16x32_bf16(wh, hh.v, acc[lt], 0, 0, 0);
            acc[lt] = __builtin_amdgcn_mfma_f32_16x16x32_bf16(wl, hh.v, acc[lt], 0, 0, 0);
            acc[lt] = __builtin_amdgcn_mfma_f32_16x16x32_bf16(wh, hl.v, acc[lt], 0, 0, 0);
        }
    }
    #pragma unroll
    for (int lt = 0; lt < 4; lt++) {
        const int l0 = lt * 16 + ((lane >> 4) << 2);
        const float4 be = *reinterpret_cast<const float4*>(&b_eo[l0]);
        const float4 lb = *reinterpret_cast<const float4*>(&lat_b[l0]);
        float4 o;
        o.x = acc[lt][0] + be.x + lb.x;
        o.y = acc[lt][1] + be.y + lb.y;
        o.z = acc[lt][2] + be.z + lb.z;
        o.w = acc[lt][3] + be.w + lb.w;
        *reinterpret_cast<float4*>(&pa[w * 16 + (lane & 15)][l0]) = o;
    }
    __syncthreads();
    if (t < 64) {
        int r = t;
        unsigned long long used = 0ULL;
        float bv[5]; int bi[5];
        #pragma unroll
        for (int p = 0; p < 5; p++) {
            float best = -3.402823466e38f; int bidx = 0;
            for (int j = 0; j < 64; j++) {
                float v = pa[r][j];
                if (!((used >> j) & 1ULL) && v > best) { best = v; bidx = j; }
            }
            used |= 1ULL << bidx;
            bv[p] = best; bi[p] = bidx;
        }
        mbits[r] = used;
        size_t gr = (size_t)(rb + r);
        #pragma unroll
        for (int p = 0; p < 5; p++) { t5v[gr * 5 + p] = bv[p]; t5i[gr * 5 + p] = bi[p]; }
        float v6 = -3.402823466e38f;
        for (int j = 0; j < 64; j++) {
            float v = pa[r][j];
            if (!((used >> j) & 1ULL) && v > v6) v6 = v;
        }
        if (bv[4] - v6 < GAP_TAU) {
            int slot = atomicAdd(fcount, 1);
            flist[slot] = rb + r;
        }
    }
    __syncthreads();
    {
        int row = t >> 2, c0 = (t & 3) * 16;
        size_t gr = (size_t)(rb + row);
        unsigned long long bits = mbits[row];
        #pragma unroll
        for (int g = 0; g < 4; g++) {
            int c = c0 + g * 4;
            float p0 = pa[row][c + 0], p1 = pa[row][c + 1], p2 = pa[row][c + 2], p3 = pa[row][c + 3];
            float m0 = (float)((bits >> (c + 0)) & 1ULL);
            float m1 = (float)((bits >> (c + 1)) & 1ULL);
            float m2 = (float)((bits >> (c + 2)) & 1ULL);
            float m3 = (float)((bits >> (c + 3)) & 1ULL);
            float4 pv = {p0, p1, p2, p3};
            float4 mv = {m0, m1, m2, m3};
            float4 sv = {m0 * p0, m1 * p1, m2 * p2, m3 * p3};
            *reinterpret_cast<float4*>(&pre_out[gr * 64 + c])  = pv;
            *reinterpret_cast<float4*>(&mask_out[gr * 64 + c]) = mv;
            *reinterpret_cast<float4*>(&sl_out[gr * 64 + c])   = sv;
        }
    }
}

// ---------------- K2b: fp32 exact repair of gap-flagged rows ----------------
__global__ __launch_bounds__(256)
void k_repair(const float* __restrict__ x,
              const float* __restrict__ pre_bias,
              const float* __restrict__ W_eh,     // [512][256]
              const float* __restrict__ b_eh,
              const float* __restrict__ W_eo,     // [64][512]
              const float* __restrict__ b_eo,
              const float* __restrict__ lat_b,
              const int* __restrict__ fcount,
              const int* __restrict__ flist,
              float* __restrict__ pre_out,
              float* __restrict__ mask_out,
              float* __restrict__ sl_out,
              float* __restrict__ t5v,
              int*   __restrict__ t5i)
{
    __shared__ float xs[256];
    __shared__ float hs[512];
    __shared__ float part[64][4];
    __shared__ float pav[64];
    __shared__ unsigned long long bitsS;
    const int t = threadIdx.x;
    const int n = *fcount;
    #pragma unroll 1
    for (int it = blockIdx.x; it < n; it += gridDim.x) {
        const int r = flist[it];
        xs[t] = x[(size_t)r * 256 + t] - pre_bias[t];
        __syncthreads();
        #pragma unroll 1
        for (int j = t; j < 512; j += 256) {
            const float* wr = &W_eh[(size_t)j * 256];
            float acc = 0.f;
            #pragma unroll
            for (int k = 0; k < 256; k += 4) {
                const float4 wv = *reinterpret_cast<const float4*>(&wr[k]);
                acc = fmaf(wv.x, xs[k + 0], acc);
                acc = fmaf(wv.y, xs[k + 1], acc);
                acc = fmaf(wv.z, xs[k + 2], acc);
                acc = fmaf(wv.w, xs[k + 3], acc);
            }
            hs[j] = fmaxf(acc + b_eh[j], 0.f);
        }
        __syncthreads();
        {
            const int l = t & 63, q = t >> 6;
            const float* wr = &W_eo[(size_t)l * 512 + q * 128];
            const float* hp = &hs[q * 128];
            float acc = 0.f;
            #pragma unroll
            for (int k = 0; k < 128; k += 4) {
                const float4 wv = *reinterpret_cast<const float4*>(&wr[k]);
                acc = fmaf(wv.x, hp[k + 0], acc);
                acc = fmaf(wv.y, hp[k + 1], acc);
                acc = fmaf(wv.z, hp[k + 2], acc);
                acc = fmaf(wv.w, hp[k + 3], acc);
            }
            part[l][q] = acc;
        }
        __syncthreads();
        if (t < 64)
            pav[t] = ((part[t][0] + part[t][1]) + (part[t][2] + part[t][3])) + b_eo[t] + lat_b[t];
        __syncthreads();
        if (t == 0) {
            unsigned long long used = 0ULL;
            const size_t gr = (size_t)r;
            #pragma unroll
            for (int p = 0; p < 5; p++) {
                float best = -3.402823466e38f; int bidx = 0;
                for (int j = 0; j < 64; j++) {
                    float v = pav[j];
                    if (!((used >> j) & 1ULL) && v > best) { best = v; bidx = j; }
                }
                used |= 1ULL << bidx;
                t5v[gr * 5 + p] = best; t5i[gr * 5 + p] = bidx;
            }
            bitsS = used;
        }
        __syncthreads();
        if (t < 64) {
            const size_t gr = (size_t)r;
            const float v = pav[t];
            const float m = (float)((bitsS >> t) & 1ULL);
            pre_out[gr * 64 + t]  = v;
            mask_out[gr * 64 + t] = m;
            sl_out[gr * 64 + t]   = m * v;
        }
        __syncthreads();
    }
}

// ---------------- K3: recon via bf16 MFMA; W_dh resident in LDS (bf16, swizzled) ----------------
// Block 256 thr = 4 waves over 64 rows x 256 cols. Wave w: row-group g=w>>1 (2 strips of 16),
// col-half ch=w&1 (8 n-tiles). hd A-frags built per-lane from LDS W (no global gathers,
// no k-loop barriers). Swizzle: byte ^= (row&7)<<4, applied on store AND read.
__global__ __launch_bounds__(256)
void k_dec(const float* __restrict__ t5v, const int* __restrict__ t5i,
           const unsigned short* __restrict__ WdhTb,  // bf16 [64][512]
           const float* __restrict__ b_dh,
           const unsigned short* __restrict__ Wdo_frag,
           const float* __restrict__ bias3,
           float* __restrict__ recon)                 // global [B][256]
{
    __shared__ __align__(16) unsigned short Wl[64 * 512];  // 64 KB
    __shared__ float bdh[512];                             // 2 KB
    __shared__ float svv[64][5];
    __shared__ int   sii[64][5];
    const int t    = threadIdx.x;
    const int rb   = blockIdx.x * 64;
    const int lane = t & 63;
    const int w    = t >> 6;

    // ---- stage W_dh^T bf16 into LDS, swizzled; coalesced 16B chunks ----
    #pragma unroll
    for (int i = 0; i < 16; i++) {
        const int chunk = t + i * 256;          // 0..4095
        const int row   = chunk >> 6;
        const int kc16  = chunk & 63;
        const uint4 v = *reinterpret_cast<const uint4*>(&WdhTb[(size_t)chunk * 8]);
        const int dst = row * 1024 + ((kc16 * 16) ^ ((row & 7) << 4));
        *reinterpret_cast<uint4*>((char*)Wl + dst) = v;
    }
    bdh[t] = b_dh[t];
    bdh[t + 256] = b_dh[t + 256];
    for (int i = t; i < 320; i += 256) {
        int rr = i / 5, p = i % 5;
        size_t lr = (size_t)(rb + rr);
        svv[rr][p] = t5v[lr * 5 + p];
        sii[rr][p] = t5i[lr * 5 + p];
    }
    __syncthreads();

    const int g  = w >> 1;              // row-group
    const int ch = w & 1;               // col-half
    const int r0 = g * 32 + (lane & 15);
    const int r1 = r0 + 16;
    const int ks = (lane >> 4) * 8;

    float vv0[5], vv1[5]; int ii0[5], ii1[5];
    #pragma unroll
    for (int p = 0; p < 5; p++) {
        vv0[p] = svv[r0][p]; ii0[p] = sii[r0][p];
        vv1[p] = svv[r1][p]; ii1[p] = sii[r1][p];
    }

    v4f acc[2][8];
    #pragma unroll
    for (int s = 0; s < 2; s++)
        #pragma unroll
        for (int n = 0; n < 8; n++) acc[s][n] = (v4f){0.f, 0.f, 0.f, 0.f};

    #pragma unroll 2
    for (int kcg = 0; kcg < 16; ++kcg) {
        const int k0 = kcg * 32 + ks;
        const float4 bd0 = *reinterpret_cast<const float4*>(&bdh[k0]);
        const float4 bd1 = *reinterpret_cast<const float4*>(&bdh[k0 + 4]);
        union { unsigned u[4]; v8s v; } af0, af1;
        // strip 0 build
        {
            float a[8] = {bd0.x, bd0.y, bd0.z, bd0.w, bd1.x, bd1.y, bd1.z, bd1.w};
            #pragma unroll
            for (int p = 0; p < 5; p++) {
                const int row = ii0[p];
                const int off = row * 1024 + ((k0 * 2) ^ ((row & 7) << 4));
                const v8s wv = *reinterpret_cast<const v8s*>((const char*)Wl + off);
                const float s = vv0[p];
                #pragma unroll
                for (int i = 0; i < 8; i++)
                    a[i] = fmaf(s, bf2f((unsigned short)wv[i]), a[i]);
            }
            af0.u[0] = pack2(fmaxf(a[0], 0.f), fmaxf(a[1], 0.f));
            af0.u[1] = pack2(fmaxf(a[2], 0.f), fmaxf(a[3], 0.f));
            af0.u[2] = pack2(fmaxf(a[4], 0.f), fmaxf(a[5], 0.f));
            af0.u[3] = pack2(fmaxf(a[6], 0.f), fmaxf(a[7], 0.f));
        }
        // strip 1 build
        {
            float a[8] = {bd0.x, bd0.y, bd0.z, bd0.w, bd1.x, bd1.y, bd1.z, bd1.w};
            #pragma unroll
            for (int p = 0; p < 5; p++) {
                const int row = ii1[p];
                const int off = row * 1024 + ((k0 * 2) ^ ((row & 7) << 4));
                const v8s wv = *reinterpret_cast<const v8s*>((const char*)Wl + off);
                const float s = vv1[p];
                #pragma unroll
                for (int i = 0; i < 8; i++)
                    a[i] = fmaf(s, bf2f((unsigned short)wv[i]), a[i]);
            }
            af1.u[0] = pack2(fmaxf(a[0], 0.f), fmaxf(a[1], 0.f));
            af1.u[1] = pack2(fmaxf(a[2], 0.f), fmaxf(a[3], 0.f));
            af1.u[2] = pack2(fmaxf(a[4], 0.f), fmaxf(a[5], 0.f));
            af1.u[3] = pack2(fmaxf(a[6], 0.f), fmaxf(a[7], 0.f));
        }
        #pragma unroll
        for (int ntl = 0; ntl < 8; ntl++) {
            const int ntg = ch * 8 + ntl;
            const v8s bf = *reinterpret_cast<const v8s*>(
                Wdo_frag + ((size_t)(ntg * 16 + kcg) * 64 + lane) * 8);
            acc[0][ntl] = __builtin_amdgcn_mfma_f32_16x16x32_bf16(af0.v, bf, acc[0][ntl], 0, 0, 0);
            acc[1][ntl] = __builtin_amdgcn_mfma_f32_16x16x32_bf16(af1.v, bf, acc[1][ntl], 0, 0, 0);
        }
    }
    // epilogue: D col=lane&15 (Wdo col), row=(lane>>4)*4+j (hd row)
    #pragma unroll
    for (int s = 0; s < 2; s++) {
        const int rowbase = rb + g * 32 + s * 16;
        #pragma unroll
        for (int ntl = 0; ntl < 8; ntl++) {
            const int col = ch * 128 + ntl * 16 + (lane & 15);
            const float bz = bias3[col];
            #pragma unroll
            for (int j = 0; j < 4; j++) {
                const size_t row = (size_t)(rowbase + (lane >> 4) * 4 + j);
                recon[row * 256 + col] = acc[s][ntl][j] + bz;
            }
        }
    }
}

// ---------------- host ----------------
extern "C" void kernel_launch(void* const* d_in, const int* in_sizes, int n_in,
                              void* d_out, int out_size, void* d_ws, size_t ws_size,
                              hipStream_t stream)
{
    const float* x        = (const float*)d_in[0];
    const float* pre_bias = (const float*)d_in[1];
    const float* W_eh     = (const float*)d_in[2];
    const float* b_eh     = (const float*)d_in[3];
    const float* W_eo     = (const float*)d_in[4];
    const float* b_eo     = (const float*)d_in[5];
    const float* lat_b    = (const float*)d_in[6];
    const float* W_dh     = (const float*)d_in[7];
    const float* b_dh     = (const float*)d_in[8];
    const float* W_do     = (const float*)d_in[9];
    const float* b_do     = (const float*)d_in[10];
    const float* dec_b    = (const float*)d_in[11];

    float* out = (float*)d_out;
    float* recon_out = out;
    float* sl_out    = out + (size_t)B_TOT * 256;
    float* pre_out   = sl_out + (size_t)B_TOT * 64;
    float* mask_out  = pre_out + (size_t)B_TOT * 64;
    float* spars_out = mask_out + (size_t)B_TOT * 64;

    char* ws = (char*)d_ws;
    unsigned short* WdhTb = (unsigned short*)ws;            // 64 KB used of 128 KB slot
    float* bias3          = (float*)(ws + 131072);
    unsigned short* WdoF  = (unsigned short*)(ws + 132096);
    unsigned short* WehHi = (unsigned short*)(ws + 394240);
    unsigned short* WehLo = (unsigned short*)(ws + 656384);
    unsigned short* WeoHi = (unsigned short*)(ws + 918528);
    unsigned short* WeoLo = (unsigned short*)(ws + 984064);
    int* fcount           = (int*)(ws + 1049600);
    int* flist            = (int*)(ws + 1049664);
    float* t5v            = (float*)(ws + 1049664 + 524288);
    int*   t5i            = (int*)  (ws + 1049664 + 524288 + (size_t)B_TOT * 20);
    unsigned short* hHi   = (unsigned short*)(ws + 1049664 + 524288 + (size_t)B_TOT * 40);
    unsigned short* hLo   = hHi + (size_t)B_TOT * 512;

    k_prep<<<32, 256, 0, stream>>>(W_dh, b_do, dec_b, pre_bias, W_do, W_eh, W_eo,
                                   WdhTb, bias3, WdoF, WehHi, WehLo, WeoHi, WeoLo,
                                   spars_out, fcount);

    k_enc1<<<B_TOT / 64, 512, 0, stream>>>(x, pre_bias, WehHi, WehLo, b_eh, hHi, hLo);

    k_enc2_topk<<<B_TOT / 64, 256, 0, stream>>>(hHi, hLo, WeoHi, WeoLo, b_eo, lat_b,
                                                pre_out, mask_out, sl_out, t5v, t5i,
                                                fcount, flist);

    k_repair<<<256, 256, 0, stream>>>(x, pre_bias, W_eh, b_eh, W_eo, b_eo, lat_b,
                                      fcount, flist, pre_out, mask_out, sl_out,
                                      t5v, t5i);

    k_dec<<<B_TOT / 64, 256, 0, stream>>>(t5v, t5i, WdhTb, b_dh, WdoF, bias3, recon_out);
}

// Round 12
// 613.240 us; speedup vs baseline: 1.3034x; 1.0731x over previous
//
#include <hip/hip_runtime.h>
#include <stdint.h>

#define B_TOT 131072
#define GAP_TAU 2.5e-4f

typedef short v8s __attribute__((ext_vector_type(8)));
typedef float v4f __attribute__((ext_vector_type(4)));

__device__ __forceinline__ unsigned short f2bf(float f) {
    union { float f; unsigned u; } v; v.f = f;
    unsigned u = v.u;
    u += 0x7fffu + ((u >> 16) & 1u);      // RNE
    return (unsigned short)(u >> 16);
}
__device__ __forceinline__ float bf2f(unsigned short s) {
    union { unsigned u; float f; } v; v.u = ((unsigned)s) << 16;
    return v.f;
}

// ---------------- K0: prep (weights swizzle + fcount zero) ----------------
__global__ void k_prep(const float* __restrict__ W_dh,      // [512][64]
                       const float* __restrict__ b_do,
                       const float* __restrict__ dec_b,
                       const float* __restrict__ pre_bias,
                       const float* __restrict__ W_do,
                       const float* __restrict__ W_eh,
                       const float* __restrict__ W_eo,
                       unsigned short* __restrict__ WdhB,    // hd-GEMM B-frags [32ht][2kc][64][8]
                       float* __restrict__ bias3,
                       unsigned short* __restrict__ Wdo_frag,
                       unsigned short* __restrict__ WehHi,
                       unsigned short* __restrict__ WehLo,
                       unsigned short* __restrict__ WeoHi,
                       unsigned short* __restrict__ WeoLo,
                       float* __restrict__ spars_out,
                       int* __restrict__ fcount)
{
    int t = blockIdx.x * blockDim.x + threadIdx.x;
    int nthr = gridDim.x * blockDim.x;
    // WdhB: frag (ht,kc,lane): W_dh[ht*16+(lane&15)][kc*32+(lane>>4)*8 + i]
    for (int g = t; g < 32 * 2 * 64; g += nthr) {
        int lane = g & 63;
        int rem = g >> 6;
        int kc = rem & 1, ht = rem >> 1;
        int h = ht * 16 + (lane & 15);
        int l = kc * 32 + (lane >> 4) * 8;
        const float* src = &W_dh[(size_t)h * 64 + l];
        unsigned short* dst = &WdhB[(size_t)g * 8];
        #pragma unroll
        for (int i = 0; i < 8; i++) dst[i] = f2bf(src[i]);
    }
    for (int g = t; g < 16384; g += nthr) {     // Wdo B-frag
        int lane = g & 63;
        int q = g >> 6;
        int nt = q >> 4, kc = q & 15;
        int col = nt * 16 + (lane & 15);
        int kbase = kc * 32 + (lane >> 4) * 8;
        const float* src = &W_do[(size_t)col * 512 + kbase];
        unsigned short* dst = &Wdo_frag[(size_t)g * 8];
        #pragma unroll
        for (int i = 0; i < 8; i++) dst[i] = f2bf(src[i]);
    }
    for (int g = t; g < 32 * 8 * 64; g += nthr) {   // W_eh hi/lo A-frag
        int lane = g & 63;
        int rem = g >> 6;
        int kcg = rem & 7, ct = rem >> 3;
        int c = ct * 16 + (lane & 15);
        int k = kcg * 32 + (lane >> 4) * 8;
        const float* src = &W_eh[(size_t)c * 256 + k];
        #pragma unroll
        for (int i = 0; i < 8; i++) {
            unsigned short hi = f2bf(src[i]);
            WehHi[(size_t)g * 8 + i] = hi;
            WehLo[(size_t)g * 8 + i] = f2bf(src[i] - bf2f(hi));
        }
    }
    for (int g = t; g < 4 * 16 * 64; g += nthr) {   // W_eo hi/lo A-frag
        int lane = g & 63;
        int rem = g >> 6;
        int kcg = rem & 15, lt = rem >> 4;
        int l = lt * 16 + (lane & 15);
        int k = kcg * 32 + (lane >> 4) * 8;
        const float* src = &W_eo[(size_t)l * 512 + k];
        #pragma unroll
        for (int i = 0; i < 8; i++) {
            unsigned short hi = f2bf(src[i]);
            WeoHi[(size_t)g * 8 + i] = hi;
            WeoLo[(size_t)g * 8 + i] = f2bf(src[i] - bf2f(hi));
        }
    }
    if (t < 256) bias3[t] = b_do[t] + dec_b[t] + pre_bias[t];
    if (t == 0) { spars_out[0] = 5.0f / 64.0f; *fcount = 0; }
}

// h planes layout (writer-native, fully coalesced stores):
//   element index H(row,k) = ((rowtile*128 + k/4)*16 + row%16)*4 + k%4

// ---------------- K1: h = relu((x-pb) @ W_eh^T + b_eh), split-bf16 MFMA ----------------
__global__ __launch_bounds__(512, 2)
void k_enc1(const float* __restrict__ x,
            const float* __restrict__ pre_bias,
            const unsigned short* __restrict__ WehHi,
            const unsigned short* __restrict__ WehLo,
            const float* __restrict__ b_eh,
            unsigned short* __restrict__ hHi,   // tiled layout
            unsigned short* __restrict__ hLo)
{
    __shared__ __align__(16) unsigned short aH[8 * 4 * 64 * 8];  // 32 KB
    __shared__ __align__(16) unsigned short aL[8 * 4 * 64 * 8];  // 32 KB
    const int t    = threadIdx.x;
    const int lane = t & 63;
    const int w    = t >> 6;        // 0..7
    const int rb   = blockIdx.x * 64;

    #pragma unroll
    for (int i = 0; i < 4; i++) {
        const int f    = t + i * 512;       // 0..2047
        const int srow = f >> 5;            // 0..63
        const int kc   = (f >> 2) & 7;      // 0..7
        const int skq  = f & 3;             // 0..3
        const float* xp = &x[(size_t)(rb + srow) * 256 + kc * 32 + skq * 8];
        const float* pp = &pre_bias[kc * 32 + skq * 8];
        const float4 v0 = *reinterpret_cast<const float4*>(xp);
        const float4 v1 = *reinterpret_cast<const float4*>(xp + 4);
        const float4 p0 = *reinterpret_cast<const float4*>(pp);
        const float4 p1 = *reinterpret_cast<const float4*>(pp + 4);
        float fv[8] = {v0.x - p0.x, v0.y - p0.y, v0.z - p0.z, v0.w - p0.w,
                       v1.x - p1.x, v1.y - p1.y, v1.z - p1.z, v1.w - p1.w};
        unsigned hi2[4], lo2[4];
        #pragma unroll
        for (int q = 0; q < 4; q++) {
            unsigned short h0 = f2bf(fv[q * 2]), h1 = f2bf(fv[q * 2 + 1]);
            hi2[q] = (unsigned)h0 | ((unsigned)h1 << 16);
            lo2[q] = (unsigned)f2bf(fv[q * 2] - bf2f(h0)) | ((unsigned)f2bf(fv[q * 2 + 1] - bf2f(h1)) << 16);
        }
        const int mt = srow >> 4;
        const int ln = skq * 16 + (srow & 15);
        *reinterpret_cast<uint4*>(&aH[((kc * 4 + mt) * 64 + ln) * 8]) = *reinterpret_cast<uint4*>(hi2);
        *reinterpret_cast<uint4*>(&aL[((kc * 4 + mt) * 64 + ln) * 8]) = *reinterpret_cast<uint4*>(lo2);
    }
    __syncthreads();

    v4f acc[4][4];
    #pragma unroll
    for (int i = 0; i < 4; i++)
        #pragma unroll
        for (int j = 0; j < 4; j++) acc[i][j] = (v4f){0.f, 0.f, 0.f, 0.f};

    #pragma unroll 2
    for (int kc = 0; kc < 8; ++kc) {
        v8s wh[4], wl[4];
        #pragma unroll
        for (int ntl = 0; ntl < 4; ntl++) {
            const int ct = w * 4 + ntl;
            const size_t idx = ((size_t)(ct * 8 + kc) * 64 + lane) * 8;
            wh[ntl] = *reinterpret_cast<const v8s*>(&WehHi[idx]);
            wl[ntl] = *reinterpret_cast<const v8s*>(&WehLo[idx]);
        }
        v8s ah[4], al[4];
        #pragma unroll
        for (int mt = 0; mt < 4; mt++) {
            const int off = ((kc * 4 + mt) * 64 + lane) * 8;
            ah[mt] = *reinterpret_cast<const v8s*>(&aH[off]);
            al[mt] = *reinterpret_cast<const v8s*>(&aL[off]);
        }
        #pragma unroll
        for (int mt = 0; mt < 4; mt++) {
            #pragma unroll
            for (int ntl = 0; ntl < 4; ntl++) {
                acc[mt][ntl] = __builtin_amdgcn_mfma_f32_16x16x32_bf16(wh[ntl], ah[mt], acc[mt][ntl], 0, 0, 0);
                acc[mt][ntl] = __builtin_amdgcn_mfma_f32_16x16x32_bf16(wl[ntl], ah[mt], acc[mt][ntl], 0, 0, 0);
                acc[mt][ntl] = __builtin_amdgcn_mfma_f32_16x16x32_bf16(wh[ntl], al[mt], acc[mt][ntl], 0, 0, 0);
            }
        }
    }
    const int rt0 = rb >> 4;
    #pragma unroll
    for (int mt = 0; mt < 4; mt++) {
        #pragma unroll
        for (int ntl = 0; ntl < 4; ntl++) {
            const int c = w * 64 + ntl * 16 + (lane >> 4) * 4;
            const float4 be = *reinterpret_cast<const float4*>(&b_eh[c]);
            float h0 = fmaxf(acc[mt][ntl][0] + be.x, 0.f);
            float h1 = fmaxf(acc[mt][ntl][1] + be.y, 0.f);
            float h2 = fmaxf(acc[mt][ntl][2] + be.z, 0.f);
            float h3 = fmaxf(acc[mt][ntl][3] + be.w, 0.f);
            unsigned short s0 = f2bf(h0), s1 = f2bf(h1), s2 = f2bf(h2), s3 = f2bf(h3);
            uint2 phi = { (unsigned)s0 | ((unsigned)s1 << 16), (unsigned)s2 | ((unsigned)s3 << 16) };
            uint2 plo = { (unsigned)f2bf(h0 - bf2f(s0)) | ((unsigned)f2bf(h1 - bf2f(s1)) << 16),
                          (unsigned)f2bf(h2 - bf2f(s2)) | ((unsigned)f2bf(h3 - bf2f(s3)) << 16) };
            const int cg = w * 16 + ntl * 4 + (lane >> 4);
            const size_t base = ((size_t)((rt0 + mt) * 128 + cg) * 16 + (lane & 15)) * 4;
            *reinterpret_cast<uint2*>(&hHi[base]) = phi;
            *reinterpret_cast<uint2*>(&hLo[base]) = plo;
        }
    }
}

// ---------------- K2: pre_act (split-bf16 MFMA); top-5; gap-flag; outputs ----------------
__global__ __launch_bounds__(256, 4)
void k_enc2_topk(const unsigned short* __restrict__ hHi,   // tiled layout
                 const unsigned short* __restrict__ hLo,
                 const unsigned short* __restrict__ WeoHi,
                 const unsigned short* __restrict__ WeoLo,
                 const float* __restrict__ b_eo,
                 const float* __restrict__ lat_b,
                 float* __restrict__ pre_out,
                 float* __restrict__ mask_out,
                 float* __restrict__ sl_out,
                 int*   __restrict__ fcount,
                 int*   __restrict__ flist)
{
    __shared__ float pa[64][68];
    __shared__ unsigned long long mbits[64];
    const int t    = threadIdx.x;
    const int lane = t & 63;
    const int w    = t >> 6;
    const int rb   = blockIdx.x * 64;
    const int rt   = (rb >> 4) + w;

    v4f acc[4];
    #pragma unroll
    for (int i = 0; i < 4; i++) acc[i] = (v4f){0.f, 0.f, 0.f, 0.f};

    #pragma unroll 2
    for (int kcl = 0; kcl < 16; ++kcl) {
        const int cg = kcl * 8 + (lane >> 4) * 2;
        const size_t b1 = ((size_t)(rt * 128 + cg) * 16 + (lane & 15)) * 4;
        union { uint4 u; v8s v; } hh, hl;
        {
            const uint2 a0 = *reinterpret_cast<const uint2*>(&hHi[b1]);
            const uint2 a1 = *reinterpret_cast<const uint2*>(&hHi[b1 + 64]);
            hh.u = (uint4){a0.x, a0.y, a1.x, a1.y};
            const uint2 c0 = *reinterpret_cast<const uint2*>(&hLo[b1]);
            const uint2 c1 = *reinterpret_cast<const uint2*>(&hLo[b1 + 64]);
            hl.u = (uint4){c0.x, c0.y, c1.x, c1.y};
        }
        #pragma unroll
        for (int lt = 0; lt < 4; lt++) {
            const size_t idx = ((size_t)(lt * 16 + kcl) * 64 + lane) * 8;
            const v8s wh = *reinterpret_cast<const v8s*>(&WeoHi[idx]);
            const v8s wl = *reinterpret_cast<const v8s*>(&WeoLo[idx]);
            acc[lt] = __builtin_amdgcn_mfma_f32_16x16x32_bf16(wh, hh.v, acc[lt], 0, 0, 0);
            acc[lt] = __builtin_amdgcn_mfma_f32_16x16x32_bf16(wl, hh.v, acc[lt], 0, 0, 0);
            acc[lt] = __builtin_amdgcn_mfma_f32_16x16x32_bf16(wh, hl.v, acc[lt], 0, 0, 0);
        }
    }
    #pragma unroll
    for (int lt = 0; lt < 4; lt++) {
        const int l0 = lt * 16 + ((lane >> 4) << 2);
        const float4 be = *reinterpret_cast<const float4*>(&b_eo[l0]);
        const float4 lb = *reinterpret_cast<const float4*>(&lat_b[l0]);
        float4 o;
        o.x = acc[lt][0] + be.x + lb.x;
        o.y = acc[lt][1] + be.y + lb.y;
        o.z = acc[lt][2] + be.z + lb.z;
        o.w = acc[lt][3] + be.w + lb.w;
        *reinterpret_cast<float4*>(&pa[w * 16 + (lane & 15)][l0]) = o;
    }
    __syncthreads();
    if (t < 64) {
        int r = t;
        unsigned long long used = 0ULL;
        float bv[5];
        #pragma unroll
        for (int p = 0; p < 5; p++) {
            float best = -3.402823466e38f; int bidx = 0;
            for (int j = 0; j < 64; j++) {
                float v = pa[r][j];
                if (!((used >> j) & 1ULL) && v > best) { best = v; bidx = j; }
            }
            used |= 1ULL << bidx;
            bv[p] = best;
        }
        mbits[r] = used;
        float v6 = -3.402823466e38f;
        for (int j = 0; j < 64; j++) {
            float v = pa[r][j];
            if (!((used >> j) & 1ULL) && v > v6) v6 = v;
        }
        if (bv[4] - v6 < GAP_TAU) {
            int slot = atomicAdd(fcount, 1);
            flist[slot] = rb + r;
        }
    }
    __syncthreads();
    {
        int row = t >> 2, c0 = (t & 3) * 16;
        size_t gr = (size_t)(rb + row);
        unsigned long long bits = mbits[row];
        #pragma unroll
        for (int g = 0; g < 4; g++) {
            int c = c0 + g * 4;
            float p0 = pa[row][c + 0], p1 = pa[row][c + 1], p2 = pa[row][c + 2], p3 = pa[row][c + 3];
            float m0 = (float)((bits >> (c + 0)) & 1ULL);
            float m1 = (float)((bits >> (c + 1)) & 1ULL);
            float m2 = (float)((bits >> (c + 2)) & 1ULL);
            float m3 = (float)((bits >> (c + 3)) & 1ULL);
            float4 pv = {p0, p1, p2, p3};
            float4 mv = {m0, m1, m2, m3};
            float4 sv = {m0 * p0, m1 * p1, m2 * p2, m3 * p3};
            *reinterpret_cast<float4*>(&pre_out[gr * 64 + c])  = pv;
            *reinterpret_cast<float4*>(&mask_out[gr * 64 + c]) = mv;
            *reinterpret_cast<float4*>(&sl_out[gr * 64 + c])   = sv;
        }
    }
}

// ---------------- K2b: fp32 exact repair of gap-flagged rows ----------------
__global__ __launch_bounds__(256)
void k_repair(const float* __restrict__ x,
              const float* __restrict__ pre_bias,
              const float* __restrict__ W_eh,     // [512][256]
              const float* __restrict__ b_eh,
              const float* __restrict__ W_eo,     // [64][512]
              const float* __restrict__ b_eo,
              const float* __restrict__ lat_b,
              const int* __restrict__ fcount,
              const int* __restrict__ flist,
              float* __restrict__ pre_out,
              float* __restrict__ mask_out,
              float* __restrict__ sl_out)
{
    __shared__ float xs[256];
    __shared__ float hs[512];
    __shared__ float part[64][4];
    __shared__ float pav[64];
    __shared__ unsigned long long bitsS;
    const int t = threadIdx.x;
    const int n = *fcount;
    #pragma unroll 1
    for (int it = blockIdx.x; it < n; it += gridDim.x) {
        const int r = flist[it];
        xs[t] = x[(size_t)r * 256 + t] - pre_bias[t];
        __syncthreads();
        #pragma unroll 1
        for (int j = t; j < 512; j += 256) {
            const float* wr = &W_eh[(size_t)j * 256];
            float acc = 0.f;
            #pragma unroll
            for (int k = 0; k < 256; k += 4) {
                const float4 wv = *reinterpret_cast<const float4*>(&wr[k]);
                acc = fmaf(wv.x, xs[k + 0], acc);
                acc = fmaf(wv.y, xs[k + 1], acc);
                acc = fmaf(wv.z, xs[k + 2], acc);
                acc = fmaf(wv.w, xs[k + 3], acc);
            }
            hs[j] = fmaxf(acc + b_eh[j], 0.f);
        }
        __syncthreads();
        {
            const int l = t & 63, q = t >> 6;
            const float* wr = &W_eo[(size_t)l * 512 + q * 128];
            const float* hp = &hs[q * 128];
            float acc = 0.f;
            #pragma unroll
            for (int k = 0; k < 128; k += 4) {
                const float4 wv = *reinterpret_cast<const float4*>(&wr[k]);
                acc = fmaf(wv.x, hp[k + 0], acc);
                acc = fmaf(wv.y, hp[k + 1], acc);
                acc = fmaf(wv.z, hp[k + 2], acc);
                acc = fmaf(wv.w, hp[k + 3], acc);
            }
            part[l][q] = acc;
        }
        __syncthreads();
        if (t < 64)
            pav[t] = ((part[t][0] + part[t][1]) + (part[t][2] + part[t][3])) + b_eo[t] + lat_b[t];
        __syncthreads();
        if (t == 0) {
            unsigned long long used = 0ULL;
            #pragma unroll
            for (int p = 0; p < 5; p++) {
                float best = -3.402823466e38f; int bidx = 0;
                for (int j = 0; j < 64; j++) {
                    float v = pav[j];
                    if (!((used >> j) & 1ULL) && v > best) { best = v; bidx = j; }
                }
                used |= 1ULL << bidx;
            }
            bitsS = used;
        }
        __syncthreads();
        if (t < 64) {
            const size_t gr = (size_t)r;
            const float v = pav[t];
            const float m = (float)((bitsS >> t) & 1ULL);
            pre_out[gr * 64 + t]  = v;
            mask_out[gr * 64 + t] = m;
            sl_out[gr * 64 + t]   = m * v;
        }
        __syncthreads();
    }
}

// ---------------- K3: recon fully via MFMA (hd-GEMM + main GEMM) ----------------
// Block 256 thr = 4 waves; 64 rows x 256 cols; K(h)=512 in 4 chunks of 128.
// Phase 1 (per chunk): hd = relu(b_dh + sl @ W_dh^T) via MFMA; wave w owns
//   h-tiles {2w,2w+1} x all 4 row-tiles; D relu/bf16-packed into hdA frag LDS.
// Phase 2: main GEMM from hdA; wave w: row-strips g*2..+2 (g=w>>1), col-half ch=w&1.
__global__ __launch_bounds__(256)
void k_dec(const float* __restrict__ sl,              // [B][64] f32 (post-repair)
           const float* __restrict__ b_dh,            // [512]
           const unsigned short* __restrict__ WdhB,   // hd-GEMM B-frags
           const unsigned short* __restrict__ Wdo_frag,
           const float* __restrict__ bias3,
           float* __restrict__ recon)                 // global [B][256]
{
    __shared__ __align__(16) unsigned short slA[2 * 4 * 64 * 8];  // 4 KB
    __shared__ __align__(16) unsigned short hdA[4 * 4 * 64 * 8];  // 16 KB
    const int t    = threadIdx.x;
    const int rb   = blockIdx.x * 64;
    const int lane = t & 63;
    const int w    = t >> 6;

    // ---- stage sl rows as bf16 A-frags ----
    {
        const int row = t >> 2;
        const int seg = (t & 3) * 16;
        const float* sp = &sl[(size_t)(rb + row) * 64 + seg];
        const int mt = row >> 4;
        #pragma unroll
        for (int q = 0; q < 4; q++) {
            const float4 v = *reinterpret_cast<const float4*>(sp + q * 4);
            const float vals[4] = {v.x, v.y, v.z, v.w};
            #pragma unroll
            for (int e = 0; e < 4; e++) {
                const int k  = seg + q * 4 + e;
                const int kc = k >> 5;
                const int lp = ((k & 31) >> 3) * 16 + (row & 15);
                slA[((kc * 4 + mt) * 64 + lp) * 8 + (k & 7)] = f2bf(vals[e]);
            }
        }
    }
    __syncthreads();

    const int g  = w >> 1;      // main-GEMM row-group
    const int ch = w & 1;       // main-GEMM col-half

    v4f accM[2][8];
    #pragma unroll
    for (int s = 0; s < 2; s++)
        #pragma unroll
        for (int n = 0; n < 8; n++) accM[s][n] = (v4f){0.f, 0.f, 0.f, 0.f};

    #pragma unroll 1
    for (int c = 0; c < 4; ++c) {
        // ---- phase 1: hd-GEMM for h-tiles ht = c*8 + {2w, 2w+1} ----
        v4f ah[4][2];
        #pragma unroll
        for (int htl = 0; htl < 2; htl++) {
            const float bd = b_dh[(c * 8 + w * 2 + htl) * 16 + (lane & 15)];
            #pragma unroll
            for (int mt = 0; mt < 4; mt++) ah[mt][htl] = (v4f){bd, bd, bd, bd};
        }
        #pragma unroll
        for (int kc = 0; kc < 2; kc++) {
            v8s sa[4];
            #pragma unroll
            for (int mt = 0; mt < 4; mt++)
                sa[mt] = *reinterpret_cast<const v8s*>(&slA[((kc * 4 + mt) * 64 + lane) * 8]);
            #pragma unroll
            for (int htl = 0; htl < 2; htl++) {
                const int ht = c * 8 + w * 2 + htl;
                const v8s wb = *reinterpret_cast<const v8s*>(&WdhB[((size_t)(ht * 2 + kc) * 64 + lane) * 8]);
                #pragma unroll
                for (int mt = 0; mt < 4; mt++)
                    ah[mt][htl] = __builtin_amdgcn_mfma_f32_16x16x32_bf16(sa[mt], wb, ah[mt][htl], 0, 0, 0);
            }
        }
        // relu + pack into hdA (main-GEMM A-frag layout)
        #pragma unroll
        for (int htl = 0; htl < 2; htl++) {
            const int hbase = (w * 2 + htl) * 16 + (lane & 15);   // h within chunk, 0..127
            const int kcgl  = hbase >> 5;
            const int ii    = hbase & 7;
            const int ls    = ((hbase & 31) >> 3) * 16;
            #pragma unroll
            for (int mt = 0; mt < 4; mt++) {
                #pragma unroll
                for (int j = 0; j < 4; j++) {
                    const int lp = ls + (lane >> 4) * 4 + j;
                    hdA[((kcgl * 4 + mt) * 64 + lp) * 8 + ii] = f2bf(fmaxf(ah[mt][htl][j], 0.f));
                }
            }
        }
        __syncthreads();
        // ---- phase 2: main GEMM over this chunk's 4 kcg ----
        #pragma unroll
        for (int kcgl = 0; kcgl < 4; ++kcgl) {
            const int kcg = c * 4 + kcgl;
            const v8s af0 = *reinterpret_cast<const v8s*>(&hdA[((kcgl * 4 + g * 2 + 0) * 64 + lane) * 8]);
            const v8s af1 = *reinterpret_cast<const v8s*>(&hdA[((kcgl * 4 + g * 2 + 1) * 64 + lane) * 8]);
            #pragma unroll
            for (int ntl = 0; ntl < 8; ntl++) {
                const int ntg = ch * 8 + ntl;
                const v8s bf = *reinterpret_cast<const v8s*>(
                    Wdo_frag + ((size_t)(ntg * 16 + kcg) * 64 + lane) * 8);
                accM[0][ntl] = __builtin_amdgcn_mfma_f32_16x16x32_bf16(af0, bf, accM[0][ntl], 0, 0, 0);
                accM[1][ntl] = __builtin_amdgcn_mfma_f32_16x16x32_bf16(af1, bf, accM[1][ntl], 0, 0, 0);
            }
        }
        __syncthreads();
    }
    // ---- epilogue: D col=lane&15 (Wdo col), row=(lane>>4)*4+j ----
    #pragma unroll
    for (int s = 0; s < 2; s++) {
        const int rowbase = rb + (g * 2 + s) * 16;
        #pragma unroll
        for (int ntl = 0; ntl < 8; ntl++) {
            const int col = ch * 128 + ntl * 16 + (lane & 15);
            const float bz = bias3[col];
            #pragma unroll
            for (int j = 0; j < 4; j++) {
                const size_t row = (size_t)(rowbase + (lane >> 4) * 4 + j);
                recon[row * 256 + col] = accM[s][ntl][j] + bz;
            }
        }
    }
}

// ---------------- host ----------------
extern "C" void kernel_launch(void* const* d_in, const int* in_sizes, int n_in,
                              void* d_out, int out_size, void* d_ws, size_t ws_size,
                              hipStream_t stream)
{
    const float* x        = (const float*)d_in[0];
    const float* pre_bias = (const float*)d_in[1];
    const float* W_eh     = (const float*)d_in[2];
    const float* b_eh     = (const float*)d_in[3];
    const float* W_eo     = (const float*)d_in[4];
    const float* b_eo     = (const float*)d_in[5];
    const float* lat_b    = (const float*)d_in[6];
    const float* W_dh     = (const float*)d_in[7];
    const float* b_dh     = (const float*)d_in[8];
    const float* W_do     = (const float*)d_in[9];
    const float* b_do     = (const float*)d_in[10];
    const float* dec_b    = (const float*)d_in[11];

    float* out = (float*)d_out;
    float* recon_out = out;
    float* sl_out    = out + (size_t)B_TOT * 256;
    float* pre_out   = sl_out + (size_t)B_TOT * 64;
    float* mask_out  = pre_out + (size_t)B_TOT * 64;
    float* spars_out = mask_out + (size_t)B_TOT * 64;

    char* ws = (char*)d_ws;
    unsigned short* WdhB  = (unsigned short*)ws;            // 64 KB (of 128 KB slot)
    float* bias3          = (float*)(ws + 131072);
    unsigned short* WdoF  = (unsigned short*)(ws + 132096);
    unsigned short* WehHi = (unsigned short*)(ws + 394240);
    unsigned short* WehLo = (unsigned short*)(ws + 656384);
    unsigned short* WeoHi = (unsigned short*)(ws + 918528);
    unsigned short* WeoLo = (unsigned short*)(ws + 984064);
    int* fcount           = (int*)(ws + 1049600);
    int* flist            = (int*)(ws + 1049664);
    unsigned short* hHi   = (unsigned short*)(ws + 1049664 + 524288);
    unsigned short* hLo   = hHi + (size_t)B_TOT * 512;

    k_prep<<<32, 256, 0, stream>>>(W_dh, b_do, dec_b, pre_bias, W_do, W_eh, W_eo,
                                   WdhB, bias3, WdoF, WehHi, WehLo, WeoHi, WeoLo,
                                   spars_out, fcount);

    k_enc1<<<B_TOT / 64, 512, 0, stream>>>(x, pre_bias, WehHi, WehLo, b_eh, hHi, hLo);

    k_enc2_topk<<<B_TOT / 64, 256, 0, stream>>>(hHi, hLo, WeoHi, WeoLo, b_eo, lat_b,
                                                pre_out, mask_out, sl_out,
                                                fcount, flist);

    k_repair<<<256, 256, 0, stream>>>(x, pre_bias, W_eh, b_eh, W_eo, b_eo, lat_b,
                                      fcount, flist, pre_out, mask_out, sl_out);

    k_dec<<<B_TOT / 64, 256, 0, stream>>>(sl_out, b_dh, WdhB, WdoF, bias3, recon_out);
}

// Round 13
// 538.080 us; speedup vs baseline: 1.4854x; 1.1397x over previous
//
#include <hip/hip_runtime.h>
#include <stdint.h>

#define B_TOT 131072
#define GAP_TAU 2.5e-4f

typedef short v8s __attribute__((ext_vector_type(8)));
typedef float v4f __attribute__((ext_vector_type(4)));

__device__ __forceinline__ unsigned short f2bf(float f) {
    union { float f; unsigned u; } v; v.f = f;
    unsigned u = v.u;
    u += 0x7fffu + ((u >> 16) & 1u);      // RNE
    return (unsigned short)(u >> 16);
}
__device__ __forceinline__ float bf2f(unsigned short s) {
    union { unsigned u; float f; } v; v.u = ((unsigned)s) << 16;
    return v.f;
}
__device__ __forceinline__ unsigned pack2(float lo, float hi) {
    return (unsigned)f2bf(lo) | ((unsigned)f2bf(hi) << 16);
}

// ---------------- K0: prep (weights swizzle + fcount zero) ----------------
__global__ void k_prep(const float* __restrict__ W_dh,      // [512][64]
                       const float* __restrict__ b_do,
                       const float* __restrict__ dec_b,
                       const float* __restrict__ pre_bias,
                       const float* __restrict__ W_do,
                       const float* __restrict__ W_eh,
                       const float* __restrict__ W_eo,
                       unsigned short* __restrict__ WdhB,    // hd-GEMM W-frags [32ht][2kc][64][8]
                       float* __restrict__ bias3,
                       unsigned short* __restrict__ Wdo_frag,
                       unsigned short* __restrict__ WehHi,
                       unsigned short* __restrict__ WehLo,
                       unsigned short* __restrict__ WeoHi,
                       unsigned short* __restrict__ WeoLo,
                       float* __restrict__ spars_out,
                       int* __restrict__ fcount)
{
    int t = blockIdx.x * blockDim.x + threadIdx.x;
    int nthr = gridDim.x * blockDim.x;
    // WdhB: frag (ht,kc,lane): W_dh[ht*16+(lane&15)][kc*32+(lane>>4)*8 + i]
    for (int g = t; g < 32 * 2 * 64; g += nthr) {
        int lane = g & 63;
        int rem = g >> 6;
        int kc = rem & 1, ht = rem >> 1;
        int h = ht * 16 + (lane & 15);
        int l = kc * 32 + (lane >> 4) * 8;
        const float* src = &W_dh[(size_t)h * 64 + l];
        unsigned short* dst = &WdhB[(size_t)g * 8];
        #pragma unroll
        for (int i = 0; i < 8; i++) dst[i] = f2bf(src[i]);
    }
    for (int g = t; g < 16384; g += nthr) {     // Wdo B-frag
        int lane = g & 63;
        int q = g >> 6;
        int nt = q >> 4, kc = q & 15;
        int col = nt * 16 + (lane & 15);
        int kbase = kc * 32 + (lane >> 4) * 8;
        const float* src = &W_do[(size_t)col * 512 + kbase];
        unsigned short* dst = &Wdo_frag[(size_t)g * 8];
        #pragma unroll
        for (int i = 0; i < 8; i++) dst[i] = f2bf(src[i]);
    }
    for (int g = t; g < 32 * 8 * 64; g += nthr) {   // W_eh hi/lo A-frag
        int lane = g & 63;
        int rem = g >> 6;
        int kcg = rem & 7, ct = rem >> 3;
        int c = ct * 16 + (lane & 15);
        int k = kcg * 32 + (lane >> 4) * 8;
        const float* src = &W_eh[(size_t)c * 256 + k];
        #pragma unroll
        for (int i = 0; i < 8; i++) {
            unsigned short hi = f2bf(src[i]);
            WehHi[(size_t)g * 8 + i] = hi;
            WehLo[(size_t)g * 8 + i] = f2bf(src[i] - bf2f(hi));
        }
    }
    for (int g = t; g < 4 * 16 * 64; g += nthr) {   // W_eo hi/lo A-frag
        int lane = g & 63;
        int rem = g >> 6;
        int kcg = rem & 15, lt = rem >> 4;
        int l = lt * 16 + (lane & 15);
        int k = kcg * 32 + (lane >> 4) * 8;
        const float* src = &W_eo[(size_t)l * 512 + k];
        #pragma unroll
        for (int i = 0; i < 8; i++) {
            unsigned short hi = f2bf(src[i]);
            WeoHi[(size_t)g * 8 + i] = hi;
            WeoLo[(size_t)g * 8 + i] = f2bf(src[i] - bf2f(hi));
        }
    }
    if (t < 256) bias3[t] = b_do[t] + dec_b[t] + pre_bias[t];
    if (t == 0) { spars_out[0] = 5.0f / 64.0f; *fcount = 0; }
}

// h planes OCTET layout: element H(row,k) = ((rowtile*64 + k/8)*16 + row%16)*8 + k%8
// (writer: uint2 stores, 512B contiguous per wave-instr; reader: one uint4 per frag, 1KB/instr)

// ---------------- K1: h = relu((x-pb) @ W_eh^T + b_eh), split-bf16 MFMA ----------------
__global__ __launch_bounds__(512, 2)
void k_enc1(const float* __restrict__ x,
            const float* __restrict__ pre_bias,
            const unsigned short* __restrict__ WehHi,
            const unsigned short* __restrict__ WehLo,
            const float* __restrict__ b_eh,
            unsigned short* __restrict__ hHi,   // octet layout
            unsigned short* __restrict__ hLo)
{
    __shared__ __align__(16) unsigned short aH[8 * 4 * 64 * 8];  // 32 KB
    __shared__ __align__(16) unsigned short aL[8 * 4 * 64 * 8];  // 32 KB
    const int t    = threadIdx.x;
    const int lane = t & 63;
    const int w    = t >> 6;        // 0..7
    const int rb   = blockIdx.x * 64;

    #pragma unroll
    for (int i = 0; i < 4; i++) {
        const int f    = t + i * 512;       // 0..2047
        const int srow = f >> 5;            // 0..63
        const int kc   = (f >> 2) & 7;      // 0..7
        const int skq  = f & 3;             // 0..3
        const float* xp = &x[(size_t)(rb + srow) * 256 + kc * 32 + skq * 8];
        const float* pp = &pre_bias[kc * 32 + skq * 8];
        const float4 v0 = *reinterpret_cast<const float4*>(xp);
        const float4 v1 = *reinterpret_cast<const float4*>(xp + 4);
        const float4 p0 = *reinterpret_cast<const float4*>(pp);
        const float4 p1 = *reinterpret_cast<const float4*>(pp + 4);
        float fv[8] = {v0.x - p0.x, v0.y - p0.y, v0.z - p0.z, v0.w - p0.w,
                       v1.x - p1.x, v1.y - p1.y, v1.z - p1.z, v1.w - p1.w};
        unsigned hi2[4], lo2[4];
        #pragma unroll
        for (int q = 0; q < 4; q++) {
            unsigned short h0 = f2bf(fv[q * 2]), h1 = f2bf(fv[q * 2 + 1]);
            hi2[q] = (unsigned)h0 | ((unsigned)h1 << 16);
            lo2[q] = (unsigned)f2bf(fv[q * 2] - bf2f(h0)) | ((unsigned)f2bf(fv[q * 2 + 1] - bf2f(h1)) << 16);
        }
        const int mt = srow >> 4;
        const int ln = skq * 16 + (srow & 15);
        *reinterpret_cast<uint4*>(&aH[((kc * 4 + mt) * 64 + ln) * 8]) = *reinterpret_cast<uint4*>(hi2);
        *reinterpret_cast<uint4*>(&aL[((kc * 4 + mt) * 64 + ln) * 8]) = *reinterpret_cast<uint4*>(lo2);
    }
    __syncthreads();

    v4f acc[4][4];
    #pragma unroll
    for (int i = 0; i < 4; i++)
        #pragma unroll
        for (int j = 0; j < 4; j++) acc[i][j] = (v4f){0.f, 0.f, 0.f, 0.f};

    #pragma unroll 2
    for (int kc = 0; kc < 8; ++kc) {
        v8s wh[4], wl[4];
        #pragma unroll
        for (int ntl = 0; ntl < 4; ntl++) {
            const int ct = w * 4 + ntl;
            const size_t idx = ((size_t)(ct * 8 + kc) * 64 + lane) * 8;
            wh[ntl] = *reinterpret_cast<const v8s*>(&WehHi[idx]);
            wl[ntl] = *reinterpret_cast<const v8s*>(&WehLo[idx]);
        }
        v8s ah[4], al[4];
        #pragma unroll
        for (int mt = 0; mt < 4; mt++) {
            const int off = ((kc * 4 + mt) * 64 + lane) * 8;
            ah[mt] = *reinterpret_cast<const v8s*>(&aH[off]);
            al[mt] = *reinterpret_cast<const v8s*>(&aL[off]);
        }
        #pragma unroll
        for (int mt = 0; mt < 4; mt++) {
            #pragma unroll
            for (int ntl = 0; ntl < 4; ntl++) {
                acc[mt][ntl] = __builtin_amdgcn_mfma_f32_16x16x32_bf16(wh[ntl], ah[mt], acc[mt][ntl], 0, 0, 0);
                acc[mt][ntl] = __builtin_amdgcn_mfma_f32_16x16x32_bf16(wl[ntl], ah[mt], acc[mt][ntl], 0, 0, 0);
                acc[mt][ntl] = __builtin_amdgcn_mfma_f32_16x16x32_bf16(wh[ntl], al[mt], acc[mt][ntl], 0, 0, 0);
            }
        }
    }
    const int rt0 = rb >> 4;
    const int q   = lane >> 4;
    #pragma unroll
    for (int mt = 0; mt < 4; mt++) {
        #pragma unroll
        for (int ntl = 0; ntl < 4; ntl++) {
            const int c = w * 64 + ntl * 16 + q * 4;
            const float4 be = *reinterpret_cast<const float4*>(&b_eh[c]);
            float h0 = fmaxf(acc[mt][ntl][0] + be.x, 0.f);
            float h1 = fmaxf(acc[mt][ntl][1] + be.y, 0.f);
            float h2 = fmaxf(acc[mt][ntl][2] + be.z, 0.f);
            float h3 = fmaxf(acc[mt][ntl][3] + be.w, 0.f);
            unsigned short s0 = f2bf(h0), s1 = f2bf(h1), s2 = f2bf(h2), s3 = f2bf(h3);
            uint2 phi = { (unsigned)s0 | ((unsigned)s1 << 16), (unsigned)s2 | ((unsigned)s3 << 16) };
            uint2 plo = { (unsigned)f2bf(h0 - bf2f(s0)) | ((unsigned)f2bf(h1 - bf2f(s1)) << 16),
                          (unsigned)f2bf(h2 - bf2f(s2)) | ((unsigned)f2bf(h3 - bf2f(s3)) << 16) };
            const int oct = w * 8 + ntl * 2 + (q >> 1);
            const size_t base = (((size_t)(rt0 + mt) * 64 + oct) * 16 + (lane & 15)) * 8 + (q & 1) * 4;
            *reinterpret_cast<uint2*>(&hHi[base]) = phi;
            *reinterpret_cast<uint2*>(&hLo[base]) = plo;
        }
    }
}

// ---------------- K2: pre_act (split-bf16 MFMA); top-5; gap-flag; outputs ----------------
__global__ __launch_bounds__(256, 3)
void k_enc2_topk(const unsigned short* __restrict__ hHi,   // octet layout
                 const unsigned short* __restrict__ hLo,
                 const unsigned short* __restrict__ WeoHi,
                 const unsigned short* __restrict__ WeoLo,
                 const float* __restrict__ b_eo,
                 const float* __restrict__ lat_b,
                 float* __restrict__ pre_out,
                 float* __restrict__ mask_out,
                 float* __restrict__ sl_out,
                 int*   __restrict__ fcount,
                 int*   __restrict__ flist)
{
    __shared__ float pa[64][68];
    __shared__ unsigned long long mbits[64];
    const int t    = threadIdx.x;
    const int lane = t & 63;
    const int w    = t >> 6;
    const int rb   = blockIdx.x * 64;
    const int rt   = (rb >> 4) + w;

    v4f acc[4];
    #pragma unroll
    for (int i = 0; i < 4; i++) acc[i] = (v4f){0.f, 0.f, 0.f, 0.f};

    #pragma unroll 4
    for (int kcl = 0; kcl < 16; ++kcl) {
        const size_t base = ((size_t)(rt * 64 + kcl * 4 + (lane >> 4)) * 16 + (lane & 15)) * 8;
        const v8s hh = *reinterpret_cast<const v8s*>(&hHi[base]);
        const v8s hl = *reinterpret_cast<const v8s*>(&hLo[base]);
        #pragma unroll
        for (int lt = 0; lt < 4; lt++) {
            const size_t idx = ((size_t)(lt * 16 + kcl) * 64 + lane) * 8;
            const v8s wh = *reinterpret_cast<const v8s*>(&WeoHi[idx]);
            const v8s wl = *reinterpret_cast<const v8s*>(&WeoLo[idx]);
            acc[lt] = __builtin_amdgcn_mfma_f32_16x16x32_bf16(wh, hh, acc[lt], 0, 0, 0);
            acc[lt] = __builtin_amdgcn_mfma_f32_16x16x32_bf16(wl, hh, acc[lt], 0, 0, 0);
            acc[lt] = __builtin_amdgcn_mfma_f32_16x16x32_bf16(wh, hl, acc[lt], 0, 0, 0);
        }
    }
    #pragma unroll
    for (int lt = 0; lt < 4; lt++) {
        const int l0 = lt * 16 + ((lane >> 4) << 2);
        const float4 be = *reinterpret_cast<const float4*>(&b_eo[l0]);
        const float4 lb = *reinterpret_cast<const float4*>(&lat_b[l0]);
        float4 o;
        o.x = acc[lt][0] + be.x + lb.x;
        o.y = acc[lt][1] + be.y + lb.y;
        o.z = acc[lt][2] + be.z + lb.z;
        o.w = acc[lt][3] + be.w + lb.w;
        *reinterpret_cast<float4*>(&pa[w * 16 + (lane & 15)][l0]) = o;
    }
    __syncthreads();
    if (t < 64) {
        int r = t;
        unsigned long long used = 0ULL;
        float bv[5];
        #pragma unroll
        for (int p = 0; p < 5; p++) {
            float best = -3.402823466e38f; int bidx = 0;
            for (int j = 0; j < 64; j++) {
                float v = pa[r][j];
                if (!((used >> j) & 1ULL) && v > best) { best = v; bidx = j; }
            }
            used |= 1ULL << bidx;
            bv[p] = best;
        }
        mbits[r] = used;
        float v6 = -3.402823466e38f;
        for (int j = 0; j < 64; j++) {
            float v = pa[r][j];
            if (!((used >> j) & 1ULL) && v > v6) v6 = v;
        }
        if (bv[4] - v6 < GAP_TAU) {
            int slot = atomicAdd(fcount, 1);
            flist[slot] = rb + r;
        }
    }
    __syncthreads();
    {
        int row = t >> 2, c0 = (t & 3) * 16;
        size_t gr = (size_t)(rb + row);
        unsigned long long bits = mbits[row];
        #pragma unroll
        for (int g = 0; g < 4; g++) {
            int c = c0 + g * 4;
            float p0 = pa[row][c + 0], p1 = pa[row][c + 1], p2 = pa[row][c + 2], p3 = pa[row][c + 3];
            float m0 = (float)((bits >> (c + 0)) & 1ULL);
            float m1 = (float)((bits >> (c + 1)) & 1ULL);
            float m2 = (float)((bits >> (c + 2)) & 1ULL);
            float m3 = (float)((bits >> (c + 3)) & 1ULL);
            float4 pv = {p0, p1, p2, p3};
            float4 mv = {m0, m1, m2, m3};
            float4 sv = {m0 * p0, m1 * p1, m2 * p2, m3 * p3};
            *reinterpret_cast<float4*>(&pre_out[gr * 64 + c])  = pv;
            *reinterpret_cast<float4*>(&mask_out[gr * 64 + c]) = mv;
            *reinterpret_cast<float4*>(&sl_out[gr * 64 + c])   = sv;
        }
    }
}

// ---------------- K2b: fp32 exact repair of gap-flagged rows ----------------
__global__ __launch_bounds__(256)
void k_repair(const float* __restrict__ x,
              const float* __restrict__ pre_bias,
              const float* __restrict__ W_eh,     // [512][256]
              const float* __restrict__ b_eh,
              const float* __restrict__ W_eo,     // [64][512]
              const float* __restrict__ b_eo,
              const float* __restrict__ lat_b,
              const int* __restrict__ fcount,
              const int* __restrict__ flist,
              float* __restrict__ pre_out,
              float* __restrict__ mask_out,
              float* __restrict__ sl_out)
{
    __shared__ float xs[256];
    __shared__ float hs[512];
    __shared__ float part[64][4];
    __shared__ float pav[64];
    __shared__ unsigned long long bitsS;
    const int t = threadIdx.x;
    const int n = *fcount;
    #pragma unroll 1
    for (int it = blockIdx.x; it < n; it += gridDim.x) {
        const int r = flist[it];
        xs[t] = x[(size_t)r * 256 + t] - pre_bias[t];
        __syncthreads();
        #pragma unroll 1
        for (int j = t; j < 512; j += 256) {
            const float* wr = &W_eh[(size_t)j * 256];
            float acc = 0.f;
            #pragma unroll
            for (int k = 0; k < 256; k += 4) {
                const float4 wv = *reinterpret_cast<const float4*>(&wr[k]);
                acc = fmaf(wv.x, xs[k + 0], acc);
                acc = fmaf(wv.y, xs[k + 1], acc);
                acc = fmaf(wv.z, xs[k + 2], acc);
                acc = fmaf(wv.w, xs[k + 3], acc);
            }
            hs[j] = fmaxf(acc + b_eh[j], 0.f);
        }
        __syncthreads();
        {
            const int l = t & 63, q = t >> 6;
            const float* wr = &W_eo[(size_t)l * 512 + q * 128];
            const float* hp = &hs[q * 128];
            float acc = 0.f;
            #pragma unroll
            for (int k = 0; k < 128; k += 4) {
                const float4 wv = *reinterpret_cast<const float4*>(&wr[k]);
                acc = fmaf(wv.x, hp[k + 0], acc);
                acc = fmaf(wv.y, hp[k + 1], acc);
                acc = fmaf(wv.z, hp[k + 2], acc);
                acc = fmaf(wv.w, hp[k + 3], acc);
            }
            part[l][q] = acc;
        }
        __syncthreads();
        if (t < 64)
            pav[t] = ((part[t][0] + part[t][1]) + (part[t][2] + part[t][3])) + b_eo[t] + lat_b[t];
        __syncthreads();
        if (t == 0) {
            unsigned long long used = 0ULL;
            #pragma unroll
            for (int p = 0; p < 5; p++) {
                float best = -3.402823466e38f; int bidx = 0;
                for (int j = 0; j < 64; j++) {
                    float v = pav[j];
                    if (!((used >> j) & 1ULL) && v > best) { best = v; bidx = j; }
                }
                used |= 1ULL << bidx;
            }
            bitsS = used;
        }
        __syncthreads();
        if (t < 64) {
            const size_t gr = (size_t)r;
            const float v = pav[t];
            const float m = (float)((bitsS >> t) & 1ULL);
            pre_out[gr * 64 + t]  = v;
            mask_out[gr * 64 + t] = m;
            sl_out[gr * 64 + t]   = m * v;
        }
        __syncthreads();
    }
}

// ---------------- K3 phase 1: hd-tile GEMM (swapped operands -> A-frag-native D) ----------------
// mfma(Wdh_frag, sl_frag): D rows = h (first operand), D cols = batch (second).
// Lane holds 4 CONSECUTIVE h for one batch row -> uint2 write straight into A-frag layout.
__device__ __forceinline__ void hd_phase1(unsigned short* __restrict__ buf,
                                          const unsigned short* __restrict__ slA,
                                          const unsigned short* __restrict__ WdhB,
                                          const float* __restrict__ b_dh,
                                          int c, int w, int lane)
{
    v4f ah[2][4];
    #pragma unroll
    for (int htl = 0; htl < 2; htl++) {
        const int h0 = (c * 8 + w * 2 + htl) * 16 + ((lane >> 4) << 2);
        const float4 bd = *reinterpret_cast<const float4*>(&b_dh[h0]);
        #pragma unroll
        for (int mt = 0; mt < 4; mt++) ah[htl][mt] = (v4f){bd.x, bd.y, bd.z, bd.w};
    }
    #pragma unroll
    for (int kc = 0; kc < 2; kc++) {
        v8s sa[4];
        #pragma unroll
        for (int mt = 0; mt < 4; mt++)
            sa[mt] = *reinterpret_cast<const v8s*>(&slA[((kc * 4 + mt) * 64 + lane) * 8]);
        #pragma unroll
        for (int htl = 0; htl < 2; htl++) {
            const int ht = c * 8 + w * 2 + htl;
            const v8s wb = *reinterpret_cast<const v8s*>(&WdhB[((size_t)(ht * 2 + kc) * 64 + lane) * 8]);
            #pragma unroll
            for (int mt = 0; mt < 4; mt++)
                ah[htl][mt] = __builtin_amdgcn_mfma_f32_16x16x32_bf16(wb, sa[mt], ah[htl][mt], 0, 0, 0);
        }
    }
    #pragma unroll
    for (int htl = 0; htl < 2; htl++) {
        const int hbase = (w * 2 + htl) * 16 + ((lane >> 4) << 2);   // h within 128-chunk
        const int kcgl  = hbase >> 5;
        const int lp    = (((hbase & 31) >> 3) << 4) + (lane & 15);
        const int ii    = hbase & 7;                                 // 0 or 4
        #pragma unroll
        for (int mt = 0; mt < 4; mt++) {
            uint2 o;
            o.x = pack2(fmaxf(ah[htl][mt][0], 0.f), fmaxf(ah[htl][mt][1], 0.f));
            o.y = pack2(fmaxf(ah[htl][mt][2], 0.f), fmaxf(ah[htl][mt][3], 0.f));
            *reinterpret_cast<uint2*>(&buf[((kcgl * 4 + mt) * 64 + lp) * 8 + ii]) = o;
        }
    }
}

// ---------------- K3: recon fully via MFMA, double-buffered hd, 1 barrier/chunk ----------------
__global__ __launch_bounds__(256)
void k_dec(const float* __restrict__ sl,              // [B][64] f32 (post-repair)
           const float* __restrict__ b_dh,            // [512]
           const unsigned short* __restrict__ WdhB,
           const unsigned short* __restrict__ Wdo_frag,
           const float* __restrict__ bias3,
           float* __restrict__ recon)                 // global [B][256]
{
    __shared__ __align__(16) unsigned short slA[2 * 4 * 64 * 8];      // 4 KB
    __shared__ __align__(16) unsigned short hdA[2][4 * 4 * 64 * 8];   // 2 x 16 KB
    const int t    = threadIdx.x;
    const int rb   = blockIdx.x * 64;
    const int lane = t & 63;
    const int w    = t >> 6;

    // ---- stage sl rows as bf16 frags ----
    {
        const int row = t >> 2;
        const int seg = (t & 3) * 16;
        const float* sp = &sl[(size_t)(rb + row) * 64 + seg];
        const int mt = row >> 4;
        #pragma unroll
        for (int q = 0; q < 4; q++) {
            const float4 v = *reinterpret_cast<const float4*>(sp + q * 4);
            const float vals[4] = {v.x, v.y, v.z, v.w};
            #pragma unroll
            for (int e = 0; e < 4; e++) {
                const int k  = seg + q * 4 + e;
                const int kc = k >> 5;
                const int lp = ((k & 31) >> 3) * 16 + (row & 15);
                slA[((kc * 4 + mt) * 64 + lp) * 8 + (k & 7)] = f2bf(vals[e]);
            }
        }
    }
    __syncthreads();

    const int g  = w >> 1;      // main-GEMM row-group
    const int ch = w & 1;       // main-GEMM col-half

    v4f accM[2][8];
    #pragma unroll
    for (int s = 0; s < 2; s++)
        #pragma unroll
        for (int n = 0; n < 8; n++) accM[s][n] = (v4f){0.f, 0.f, 0.f, 0.f};

    hd_phase1(hdA[0], slA, WdhB, b_dh, 0, w, lane);
    __syncthreads();

    #pragma unroll 1
    for (int c = 0; c < 4; ++c) {
        if (c < 3)
            hd_phase1(hdA[(c + 1) & 1], slA, WdhB, b_dh, c + 1, w, lane);
        const unsigned short* buf = hdA[c & 1];
        #pragma unroll
        for (int kcgl = 0; kcgl < 4; ++kcgl) {
            const int kcg = c * 4 + kcgl;
            const v8s af0 = *reinterpret_cast<const v8s*>(&buf[((kcgl * 4 + g * 2 + 0) * 64 + lane) * 8]);
            const v8s af1 = *reinterpret_cast<const v8s*>(&buf[((kcgl * 4 + g * 2 + 1) * 64 + lane) * 8]);
            #pragma unroll
            for (int ntl = 0; ntl < 8; ntl++) {
                const int ntg = ch * 8 + ntl;
                const v8s bf = *reinterpret_cast<const v8s*>(
                    Wdo_frag + ((size_t)(ntg * 16 + kcg) * 64 + lane) * 8);
                accM[0][ntl] = __builtin_amdgcn_mfma_f32_16x16x32_bf16(af0, bf, accM[0][ntl], 0, 0, 0);
                accM[1][ntl] = __builtin_amdgcn_mfma_f32_16x16x32_bf16(af1, bf, accM[1][ntl], 0, 0, 0);
            }
        }
        __syncthreads();
    }
    // ---- epilogue: D col=lane&15 (Wdo col), row=(lane>>4)*4+j ----
    #pragma unroll
    for (int s = 0; s < 2; s++) {
        const int rowbase = rb + (g * 2 + s) * 16;
        #pragma unroll
        for (int ntl = 0; ntl < 8; ntl++) {
            const int col = ch * 128 + ntl * 16 + (lane & 15);
            const float bz = bias3[col];
            #pragma unroll
            for (int j = 0; j < 4; j++) {
                const size_t row = (size_t)(rowbase + (lane >> 4) * 4 + j);
                recon[row * 256 + col] = accM[s][ntl][j] + bz;
            }
        }
    }
}

// ---------------- host ----------------
extern "C" void kernel_launch(void* const* d_in, const int* in_sizes, int n_in,
                              void* d_out, int out_size, void* d_ws, size_t ws_size,
                              hipStream_t stream)
{
    const float* x        = (const float*)d_in[0];
    const float* pre_bias = (const float*)d_in[1];
    const float* W_eh     = (const float*)d_in[2];
    const float* b_eh     = (const float*)d_in[3];
    const float* W_eo     = (const float*)d_in[4];
    const float* b_eo     = (const float*)d_in[5];
    const float* lat_b    = (const float*)d_in[6];
    const float* W_dh     = (const float*)d_in[7];
    const float* b_dh     = (const float*)d_in[8];
    const float* W_do     = (const float*)d_in[9];
    const float* b_do     = (const float*)d_in[10];
    const float* dec_b    = (const float*)d_in[11];

    float* out = (float*)d_out;
    float* recon_out = out;
    float* sl_out    = out + (size_t)B_TOT * 256;
    float* pre_out   = sl_out + (size_t)B_TOT * 64;
    float* mask_out  = pre_out + (size_t)B_TOT * 64;
    float* spars_out = mask_out + (size_t)B_TOT * 64;

    char* ws = (char*)d_ws;
    unsigned short* WdhB  = (unsigned short*)ws;            // 64 KB (of 128 KB slot)
    float* bias3          = (float*)(ws + 131072);
    unsigned short* WdoF  = (unsigned short*)(ws + 132096);
    unsigned short* WehHi = (unsigned short*)(ws + 394240);
    unsigned short* WehLo = (unsigned short*)(ws + 656384);
    unsigned short* WeoHi = (unsigned short*)(ws + 918528);
    unsigned short* WeoLo = (unsigned short*)(ws + 984064);
    int* fcount           = (int*)(ws + 1049600);
    int* flist            = (int*)(ws + 1049664);
    unsigned short* hHi   = (unsigned short*)(ws + 1049664 + 524288);
    unsigned short* hLo   = hHi + (size_t)B_TOT * 512;

    k_prep<<<32, 256, 0, stream>>>(W_dh, b_do, dec_b, pre_bias, W_do, W_eh, W_eo,
                                   WdhB, bias3, WdoF, WehHi, WehLo, WeoHi, WeoLo,
                                   spars_out, fcount);

    k_enc1<<<B_TOT / 64, 512, 0, stream>>>(x, pre_bias, WehHi, WehLo, b_eh, hHi, hLo);

    k_enc2_topk<<<B_TOT / 64, 256, 0, stream>>>(hHi, hLo, WeoHi, WeoLo, b_eo, lat_b,
                                                pre_out, mask_out, sl_out,
                                                fcount, flist);

    k_repair<<<256, 256, 0, stream>>>(x, pre_bias, W_eh, b_eh, W_eo, b_eo, lat_b,
                                      fcount, flist, pre_out, mask_out, sl_out);

    k_dec<<<B_TOT / 64, 256, 0, stream>>>(sl_out, b_dh, WdhB, WdoF, bias3, recon_out);
}

// Round 14
// 493.106 us; speedup vs baseline: 1.6209x; 1.0912x over previous
//
#include <hip/hip_runtime.h>
#include <stdint.h>

#define B_TOT 131072
#define GAP_TAU 2.5e-4f

typedef short v8s __attribute__((ext_vector_type(8)));
typedef float v4f __attribute__((ext_vector_type(4)));

__device__ __forceinline__ unsigned short f2bf(float f) {
    union { float f; unsigned u; } v; v.f = f;
    unsigned u = v.u;
    u += 0x7fffu + ((u >> 16) & 1u);      // RNE
    return (unsigned short)(u >> 16);
}
__device__ __forceinline__ float bf2f(unsigned short s) {
    union { unsigned u; float f; } v; v.u = ((unsigned)s) << 16;
    return v.f;
}
__device__ __forceinline__ unsigned pack2(float lo, float hi) {
    return (unsigned)f2bf(lo) | ((unsigned)f2bf(hi) << 16);
}

// ---------------- K0: prep (weights swizzle + fcount zero) ----------------
__global__ void k_prep(const float* __restrict__ W_dh,      // [512][64]
                       const float* __restrict__ b_do,
                       const float* __restrict__ dec_b,
                       const float* __restrict__ pre_bias,
                       const float* __restrict__ W_do,
                       const float* __restrict__ W_eh,
                       const float* __restrict__ W_eo,
                       unsigned short* __restrict__ WdhB,    // hd-GEMM W-frags [32ht][2kc][64][8]
                       float* __restrict__ bias3,
                       unsigned short* __restrict__ Wdo_frag,
                       unsigned short* __restrict__ WehHi,
                       unsigned short* __restrict__ WehLo,
                       unsigned short* __restrict__ WeoHi,
                       unsigned short* __restrict__ WeoLo,
                       float* __restrict__ spars_out,
                       int* __restrict__ fcount)
{
    int t = blockIdx.x * blockDim.x + threadIdx.x;
    int nthr = gridDim.x * blockDim.x;
    // WdhB: frag (ht,kc,lane): W_dh[ht*16+(lane&15)][kc*32+(lane>>4)*8 + i]
    for (int g = t; g < 32 * 2 * 64; g += nthr) {
        int lane = g & 63;
        int rem = g >> 6;
        int kc = rem & 1, ht = rem >> 1;
        int h = ht * 16 + (lane & 15);
        int l = kc * 32 + (lane >> 4) * 8;
        const float* src = &W_dh[(size_t)h * 64 + l];
        unsigned short* dst = &WdhB[(size_t)g * 8];
        #pragma unroll
        for (int i = 0; i < 8; i++) dst[i] = f2bf(src[i]);
    }
    for (int g = t; g < 16384; g += nthr) {     // Wdo B-frag
        int lane = g & 63;
        int q = g >> 6;
        int nt = q >> 4, kc = q & 15;
        int col = nt * 16 + (lane & 15);
        int kbase = kc * 32 + (lane >> 4) * 8;
        const float* src = &W_do[(size_t)col * 512 + kbase];
        unsigned short* dst = &Wdo_frag[(size_t)g * 8];
        #pragma unroll
        for (int i = 0; i < 8; i++) dst[i] = f2bf(src[i]);
    }
    for (int g = t; g < 32 * 8 * 64; g += nthr) {   // W_eh hi/lo A-frag
        int lane = g & 63;
        int rem = g >> 6;
        int kcg = rem & 7, ct = rem >> 3;
        int c = ct * 16 + (lane & 15);
        int k = kcg * 32 + (lane >> 4) * 8;
        const float* src = &W_eh[(size_t)c * 256 + k];
        #pragma unroll
        for (int i = 0; i < 8; i++) {
            unsigned short hi = f2bf(src[i]);
            WehHi[(size_t)g * 8 + i] = hi;
            WehLo[(size_t)g * 8 + i] = f2bf(src[i] - bf2f(hi));
        }
    }
    for (int g = t; g < 4 * 16 * 64; g += nthr) {   // W_eo hi/lo A-frag
        int lane = g & 63;
        int rem = g >> 6;
        int kcg = rem & 15, lt = rem >> 4;
        int l = lt * 16 + (lane & 15);
        int k = kcg * 32 + (lane >> 4) * 8;
        const float* src = &W_eo[(size_t)l * 512 + k];
        #pragma unroll
        for (int i = 0; i < 8; i++) {
            unsigned short hi = f2bf(src[i]);
            WeoHi[(size_t)g * 8 + i] = hi;
            WeoLo[(size_t)g * 8 + i] = f2bf(src[i] - bf2f(hi));
        }
    }
    if (t < 256) bias3[t] = b_do[t] + dec_b[t] + pre_bias[t];
    if (t == 0) { spars_out[0] = 5.0f / 64.0f; *fcount = 0; }
}

// h planes OCTET layout: element H(row,k) = ((rowtile*64 + k/8)*16 + row%16)*8 + k%8

// ---------------- K1: h = relu((x-pb) @ W_eh^T + b_eh), split-bf16 MFMA ----------------
__global__ __launch_bounds__(512, 2)
void k_enc1(const float* __restrict__ x,
            const float* __restrict__ pre_bias,
            const unsigned short* __restrict__ WehHi,
            const unsigned short* __restrict__ WehLo,
            const float* __restrict__ b_eh,
            unsigned short* __restrict__ hHi,   // octet layout
            unsigned short* __restrict__ hLo)
{
    __shared__ __align__(16) unsigned short aH[8 * 4 * 64 * 8];  // 32 KB
    __shared__ __align__(16) unsigned short aL[8 * 4 * 64 * 8];  // 32 KB
    const int t    = threadIdx.x;
    const int lane = t & 63;
    const int w    = t >> 6;        // 0..7
    const int rb   = blockIdx.x * 64;

    #pragma unroll
    for (int i = 0; i < 4; i++) {
        const int f    = t + i * 512;       // 0..2047
        const int srow = f >> 5;            // 0..63
        const int kc   = (f >> 2) & 7;      // 0..7
        const int skq  = f & 3;             // 0..3
        const float* xp = &x[(size_t)(rb + srow) * 256 + kc * 32 + skq * 8];
        const float* pp = &pre_bias[kc * 32 + skq * 8];
        const float4 v0 = *reinterpret_cast<const float4*>(xp);
        const float4 v1 = *reinterpret_cast<const float4*>(xp + 4);
        const float4 p0 = *reinterpret_cast<const float4*>(pp);
        const float4 p1 = *reinterpret_cast<const float4*>(pp + 4);
        float fv[8] = {v0.x - p0.x, v0.y - p0.y, v0.z - p0.z, v0.w - p0.w,
                       v1.x - p1.x, v1.y - p1.y, v1.z - p1.z, v1.w - p1.w};
        unsigned hi2[4], lo2[4];
        #pragma unroll
        for (int q = 0; q < 4; q++) {
            unsigned short h0 = f2bf(fv[q * 2]), h1 = f2bf(fv[q * 2 + 1]);
            hi2[q] = (unsigned)h0 | ((unsigned)h1 << 16);
            lo2[q] = (unsigned)f2bf(fv[q * 2] - bf2f(h0)) | ((unsigned)f2bf(fv[q * 2 + 1] - bf2f(h1)) << 16);
        }
        const int mt = srow >> 4;
        const int ln = skq * 16 + (srow & 15);
        *reinterpret_cast<uint4*>(&aH[((kc * 4 + mt) * 64 + ln) * 8]) = *reinterpret_cast<uint4*>(hi2);
        *reinterpret_cast<uint4*>(&aL[((kc * 4 + mt) * 64 + ln) * 8]) = *reinterpret_cast<uint4*>(lo2);
    }
    __syncthreads();

    v4f acc[4][4];
    #pragma unroll
    for (int i = 0; i < 4; i++)
        #pragma unroll
        for (int j = 0; j < 4; j++) acc[i][j] = (v4f){0.f, 0.f, 0.f, 0.f};

    #pragma unroll 2
    for (int kc = 0; kc < 8; ++kc) {
        v8s wh[4], wl[4];
        #pragma unroll
        for (int ntl = 0; ntl < 4; ntl++) {
            const int ct = w * 4 + ntl;
            const size_t idx = ((size_t)(ct * 8 + kc) * 64 + lane) * 8;
            wh[ntl] = *reinterpret_cast<const v8s*>(&WehHi[idx]);
            wl[ntl] = *reinterpret_cast<const v8s*>(&WehLo[idx]);
        }
        v8s ah[4], al[4];
        #pragma unroll
        for (int mt = 0; mt < 4; mt++) {
            const int off = ((kc * 4 + mt) * 64 + lane) * 8;
            ah[mt] = *reinterpret_cast<const v8s*>(&aH[off]);
            al[mt] = *reinterpret_cast<const v8s*>(&aL[off]);
        }
        #pragma unroll
        for (int mt = 0; mt < 4; mt++) {
            #pragma unroll
            for (int ntl = 0; ntl < 4; ntl++) {
                acc[mt][ntl] = __builtin_amdgcn_mfma_f32_16x16x32_bf16(wh[ntl], ah[mt], acc[mt][ntl], 0, 0, 0);
                acc[mt][ntl] = __builtin_amdgcn_mfma_f32_16x16x32_bf16(wl[ntl], ah[mt], acc[mt][ntl], 0, 0, 0);
                acc[mt][ntl] = __builtin_amdgcn_mfma_f32_16x16x32_bf16(wh[ntl], al[mt], acc[mt][ntl], 0, 0, 0);
            }
        }
    }
    const int rt0 = rb >> 4;
    const int q   = lane >> 4;
    #pragma unroll
    for (int mt = 0; mt < 4; mt++) {
        #pragma unroll
        for (int ntl = 0; ntl < 4; ntl++) {
            const int c = w * 64 + ntl * 16 + q * 4;
            const float4 be = *reinterpret_cast<const float4*>(&b_eh[c]);
            float h0 = fmaxf(acc[mt][ntl][0] + be.x, 0.f);
            float h1 = fmaxf(acc[mt][ntl][1] + be.y, 0.f);
            float h2 = fmaxf(acc[mt][ntl][2] + be.z, 0.f);
            float h3 = fmaxf(acc[mt][ntl][3] + be.w, 0.f);
            unsigned short s0 = f2bf(h0), s1 = f2bf(h1), s2 = f2bf(h2), s3 = f2bf(h3);
            uint2 phi = { (unsigned)s0 | ((unsigned)s1 << 16), (unsigned)s2 | ((unsigned)s3 << 16) };
            uint2 plo = { (unsigned)f2bf(h0 - bf2f(s0)) | ((unsigned)f2bf(h1 - bf2f(s1)) << 16),
                          (unsigned)f2bf(h2 - bf2f(s2)) | ((unsigned)f2bf(h3 - bf2f(s3)) << 16) };
            const int oct = w * 8 + ntl * 2 + (q >> 1);
            const size_t base = (((size_t)(rt0 + mt) * 64 + oct) * 16 + (lane & 15)) * 8 + (q & 1) * 4;
            *reinterpret_cast<uint2*>(&hHi[base]) = phi;
            *reinterpret_cast<uint2*>(&hLo[base]) = plo;
        }
    }
}

// ---------------- K2: pre_act (split-bf16 MFMA); top-5; gap-flag; outputs ----------------
// 128 rows/block; wave w owns row-tiles {2w, 2w+1} (32 rows); W frags shared across both.
__global__ __launch_bounds__(256, 4)
void k_enc2_topk(const unsigned short* __restrict__ hHi,   // octet layout
                 const unsigned short* __restrict__ hLo,
                 const unsigned short* __restrict__ WeoHi,
                 const unsigned short* __restrict__ WeoLo,
                 const float* __restrict__ b_eo,
                 const float* __restrict__ lat_b,
                 float* __restrict__ pre_out,
                 float* __restrict__ mask_out,
                 float* __restrict__ sl_out,
                 int*   __restrict__ fcount,
                 int*   __restrict__ flist)
{
    __shared__ float pa[128][68];
    __shared__ unsigned long long mbits[128];
    const int t    = threadIdx.x;
    const int lane = t & 63;
    const int w    = t >> 6;
    const int rb   = blockIdx.x * 128;
    const int rtA  = (rb >> 4) + w * 2;
    const int rtB  = rtA + 1;

    v4f acc[2][4];
    #pragma unroll
    for (int s = 0; s < 2; s++)
        #pragma unroll
        for (int i = 0; i < 4; i++) acc[s][i] = (v4f){0.f, 0.f, 0.f, 0.f};

    #pragma unroll 2
    for (int kcl = 0; kcl < 16; ++kcl) {
        const size_t baseA = ((size_t)(rtA * 64 + kcl * 4 + (lane >> 4)) * 16 + (lane & 15)) * 8;
        const size_t baseB = ((size_t)(rtB * 64 + kcl * 4 + (lane >> 4)) * 16 + (lane & 15)) * 8;
        const v8s hhA = *reinterpret_cast<const v8s*>(&hHi[baseA]);
        const v8s hlA = *reinterpret_cast<const v8s*>(&hLo[baseA]);
        const v8s hhB = *reinterpret_cast<const v8s*>(&hHi[baseB]);
        const v8s hlB = *reinterpret_cast<const v8s*>(&hLo[baseB]);
        #pragma unroll
        for (int lt = 0; lt < 4; lt++) {
            const size_t idx = ((size_t)(lt * 16 + kcl) * 64 + lane) * 8;
            const v8s wh = *reinterpret_cast<const v8s*>(&WeoHi[idx]);
            const v8s wl = *reinterpret_cast<const v8s*>(&WeoLo[idx]);
            acc[0][lt] = __builtin_amdgcn_mfma_f32_16x16x32_bf16(wh, hhA, acc[0][lt], 0, 0, 0);
            acc[0][lt] = __builtin_amdgcn_mfma_f32_16x16x32_bf16(wl, hhA, acc[0][lt], 0, 0, 0);
            acc[0][lt] = __builtin_amdgcn_mfma_f32_16x16x32_bf16(wh, hlA, acc[0][lt], 0, 0, 0);
            acc[1][lt] = __builtin_amdgcn_mfma_f32_16x16x32_bf16(wh, hhB, acc[1][lt], 0, 0, 0);
            acc[1][lt] = __builtin_amdgcn_mfma_f32_16x16x32_bf16(wl, hhB, acc[1][lt], 0, 0, 0);
            acc[1][lt] = __builtin_amdgcn_mfma_f32_16x16x32_bf16(wh, hlB, acc[1][lt], 0, 0, 0);
        }
    }
    #pragma unroll
    for (int s = 0; s < 2; s++) {
        const int row = w * 32 + s * 16 + (lane & 15);
        #pragma unroll
        for (int lt = 0; lt < 4; lt++) {
            const int l0 = lt * 16 + ((lane >> 4) << 2);
            const float4 be = *reinterpret_cast<const float4*>(&b_eo[l0]);
            const float4 lb = *reinterpret_cast<const float4*>(&lat_b[l0]);
            float4 o;
            o.x = acc[s][lt][0] + be.x + lb.x;
            o.y = acc[s][lt][1] + be.y + lb.y;
            o.z = acc[s][lt][2] + be.z + lb.z;
            o.w = acc[s][lt][3] + be.w + lb.w;
            *reinterpret_cast<float4*>(&pa[row][l0]) = o;
        }
    }
    __syncthreads();
    if (t < 128) {
        int r = t;
        unsigned long long used = 0ULL;
        float bv[5];
        #pragma unroll
        for (int p = 0; p < 5; p++) {
            float best = -3.402823466e38f; int bidx = 0;
            for (int j = 0; j < 64; j++) {
                float v = pa[r][j];
                if (!((used >> j) & 1ULL) && v > best) { best = v; bidx = j; }
            }
            used |= 1ULL << bidx;
            bv[p] = best;
        }
        mbits[r] = used;
        float v6 = -3.402823466e38f;
        for (int j = 0; j < 64; j++) {
            float v = pa[r][j];
            if (!((used >> j) & 1ULL) && v > v6) v6 = v;
        }
        if (bv[4] - v6 < GAP_TAU) {
            int slot = atomicAdd(fcount, 1);
            flist[slot] = rb + r;
        }
    }
    __syncthreads();
    // fully-coalesced output writes: 16 lanes x float4 = 4 consecutive rows per wave-instr
    {
        const int c = (t & 15) * 4;
        #pragma unroll
        for (int pass = 0; pass < 8; pass++) {
            const int row = pass * 16 + (t >> 4);
            const size_t gr = (size_t)(rb + row);
            const unsigned long long bits = mbits[row];
            const float p0 = pa[row][c + 0], p1 = pa[row][c + 1];
            const float p2 = pa[row][c + 2], p3 = pa[row][c + 3];
            const float m0 = (float)((bits >> (c + 0)) & 1ULL);
            const float m1 = (float)((bits >> (c + 1)) & 1ULL);
            const float m2 = (float)((bits >> (c + 2)) & 1ULL);
            const float m3 = (float)((bits >> (c + 3)) & 1ULL);
            float4 pv = {p0, p1, p2, p3};
            float4 mv = {m0, m1, m2, m3};
            float4 sv = {m0 * p0, m1 * p1, m2 * p2, m3 * p3};
            *reinterpret_cast<float4*>(&pre_out[gr * 64 + c])  = pv;
            *reinterpret_cast<float4*>(&mask_out[gr * 64 + c]) = mv;
            *reinterpret_cast<float4*>(&sl_out[gr * 64 + c])   = sv;
        }
    }
}

// ---------------- K2b: fp32 exact repair of gap-flagged rows ----------------
__global__ __launch_bounds__(256)
void k_repair(const float* __restrict__ x,
              const float* __restrict__ pre_bias,
              const float* __restrict__ W_eh,     // [512][256]
              const float* __restrict__ b_eh,
              const float* __restrict__ W_eo,     // [64][512]
              const float* __restrict__ b_eo,
              const float* __restrict__ lat_b,
              const int* __restrict__ fcount,
              const int* __restrict__ flist,
              float* __restrict__ pre_out,
              float* __restrict__ mask_out,
              float* __restrict__ sl_out)
{
    __shared__ float xs[256];
    __shared__ float hs[512];
    __shared__ float part[64][4];
    __shared__ float pav[64];
    __shared__ unsigned long long bitsS;
    const int t = threadIdx.x;
    const int n = *fcount;
    #pragma unroll 1
    for (int it = blockIdx.x; it < n; it += gridDim.x) {
        const int r = flist[it];
        xs[t] = x[(size_t)r * 256 + t] - pre_bias[t];
        __syncthreads();
        #pragma unroll 1
        for (int j = t; j < 512; j += 256) {
            const float* wr = &W_eh[(size_t)j * 256];
            float acc = 0.f;
            #pragma unroll
            for (int k = 0; k < 256; k += 4) {
                const float4 wv = *reinterpret_cast<const float4*>(&wr[k]);
                acc = fmaf(wv.x, xs[k + 0], acc);
                acc = fmaf(wv.y, xs[k + 1], acc);
                acc = fmaf(wv.z, xs[k + 2], acc);
                acc = fmaf(wv.w, xs[k + 3], acc);
            }
            hs[j] = fmaxf(acc + b_eh[j], 0.f);
        }
        __syncthreads();
        {
            const int l = t & 63, q = t >> 6;
            const float* wr = &W_eo[(size_t)l * 512 + q * 128];
            const float* hp = &hs[q * 128];
            float acc = 0.f;
            #pragma unroll
            for (int k = 0; k < 128; k += 4) {
                const float4 wv = *reinterpret_cast<const float4*>(&wr[k]);
                acc = fmaf(wv.x, hp[k + 0], acc);
                acc = fmaf(wv.y, hp[k + 1], acc);
                acc = fmaf(wv.z, hp[k + 2], acc);
                acc = fmaf(wv.w, hp[k + 3], acc);
            }
            part[l][q] = acc;
        }
        __syncthreads();
        if (t < 64)
            pav[t] = ((part[t][0] + part[t][1]) + (part[t][2] + part[t][3])) + b_eo[t] + lat_b[t];
        __syncthreads();
        if (t == 0) {
            unsigned long long used = 0ULL;
            #pragma unroll
            for (int p = 0; p < 5; p++) {
                float best = -3.402823466e38f; int bidx = 0;
                for (int j = 0; j < 64; j++) {
                    float v = pav[j];
                    if (!((used >> j) & 1ULL) && v > best) { best = v; bidx = j; }
                }
                used |= 1ULL << bidx;
            }
            bitsS = used;
        }
        __syncthreads();
        if (t < 64) {
            const size_t gr = (size_t)r;
            const float v = pav[t];
            const float m = (float)((bitsS >> t) & 1ULL);
            pre_out[gr * 64 + t]  = v;
            mask_out[gr * 64 + t] = m;
            sl_out[gr * 64 + t]   = m * v;
        }
        __syncthreads();
    }
}

// ---------------- K3 phase 1: hd-tile GEMM (swapped operands -> A-frag-native D) ----------------
__device__ __forceinline__ void hd_phase1(unsigned short* __restrict__ buf,
                                          const unsigned short* __restrict__ slA,
                                          const unsigned short* __restrict__ WdhB,
                                          const float* __restrict__ b_dh,
                                          int c, int w, int lane)
{
    v4f ah[2][4];
    #pragma unroll
    for (int htl = 0; htl < 2; htl++) {
        const int h0 = (c * 8 + w * 2 + htl) * 16 + ((lane >> 4) << 2);
        const float4 bd = *reinterpret_cast<const float4*>(&b_dh[h0]);
        #pragma unroll
        for (int mt = 0; mt < 4; mt++) ah[htl][mt] = (v4f){bd.x, bd.y, bd.z, bd.w};
    }
    #pragma unroll
    for (int kc = 0; kc < 2; kc++) {
        v8s sa[4];
        #pragma unroll
        for (int mt = 0; mt < 4; mt++)
            sa[mt] = *reinterpret_cast<const v8s*>(&slA[((kc * 4 + mt) * 64 + lane) * 8]);
        #pragma unroll
        for (int htl = 0; htl < 2; htl++) {
            const int ht = c * 8 + w * 2 + htl;
            const v8s wb = *reinterpret_cast<const v8s*>(&WdhB[((size_t)(ht * 2 + kc) * 64 + lane) * 8]);
            #pragma unroll
            for (int mt = 0; mt < 4; mt++)
                ah[htl][mt] = __builtin_amdgcn_mfma_f32_16x16x32_bf16(wb, sa[mt], ah[htl][mt], 0, 0, 0);
        }
    }
    #pragma unroll
    for (int htl = 0; htl < 2; htl++) {
        const int hbase = (w * 2 + htl) * 16 + ((lane >> 4) << 2);   // h within 128-chunk
        const int kcgl  = hbase >> 5;
        const int lp    = (((hbase & 31) >> 3) << 4) + (lane & 15);
        const int ii    = hbase & 7;                                 // 0 or 4
        #pragma unroll
        for (int mt = 0; mt < 4; mt++) {
            uint2 o;
            o.x = pack2(fmaxf(ah[htl][mt][0], 0.f), fmaxf(ah[htl][mt][1], 0.f));
            o.y = pack2(fmaxf(ah[htl][mt][2], 0.f), fmaxf(ah[htl][mt][3], 0.f));
            *reinterpret_cast<uint2*>(&buf[((kcgl * 4 + mt) * 64 + lp) * 8 + ii]) = o;
        }
    }
}

// ---------------- K3: recon fully via MFMA, double-buffered hd, 1 barrier/chunk ----------------
__global__ __launch_bounds__(256)
void k_dec(const float* __restrict__ sl,              // [B][64] f32 (post-repair)
           const float* __restrict__ b_dh,            // [512]
           const unsigned short* __restrict__ WdhB,
           const unsigned short* __restrict__ Wdo_frag,
           const float* __restrict__ bias3,
           float* __restrict__ recon)                 // global [B][256]
{
    __shared__ __align__(16) unsigned short slA[2 * 4 * 64 * 8];      // 4 KB
    __shared__ __align__(16) unsigned short hdA[2][4 * 4 * 64 * 8];   // 2 x 16 KB
    const int t    = threadIdx.x;
    const int rb   = blockIdx.x * 64;
    const int lane = t & 63;
    const int w    = t >> 6;

    // ---- stage sl rows as bf16 frags ----
    {
        const int row = t >> 2;
        const int seg = (t & 3) * 16;
        const float* sp = &sl[(size_t)(rb + row) * 64 + seg];
        const int mt = row >> 4;
        #pragma unroll
        for (int q = 0; q < 4; q++) {
            const float4 v = *reinterpret_cast<const float4*>(sp + q * 4);
            const float vals[4] = {v.x, v.y, v.z, v.w};
            #pragma unroll
            for (int e = 0; e < 4; e++) {
                const int k  = seg + q * 4 + e;
                const int kc = k >> 5;
                const int lp = ((k & 31) >> 3) * 16 + (row & 15);
                slA[((kc * 4 + mt) * 64 + lp) * 8 + (k & 7)] = f2bf(vals[e]);
            }
        }
    }
    __syncthreads();

    const int g  = w >> 1;      // main-GEMM row-group
    const int ch = w & 1;       // main-GEMM col-half

    v4f accM[2][8];
    #pragma unroll
    for (int s = 0; s < 2; s++)
        #pragma unroll
        for (int n = 0; n < 8; n++) accM[s][n] = (v4f){0.f, 0.f, 0.f, 0.f};

    hd_phase1(hdA[0], slA, WdhB, b_dh, 0, w, lane);
    __syncthreads();

    #pragma unroll 1
    for (int c = 0; c < 4; ++c) {
        if (c < 3)
            hd_phase1(hdA[(c + 1) & 1], slA, WdhB, b_dh, c + 1, w, lane);
        const unsigned short* buf = hdA[c & 1];
        #pragma unroll
        for (int kcgl = 0; kcgl < 4; ++kcgl) {
            const int kcg = c * 4 + kcgl;
            const v8s af0 = *reinterpret_cast<const v8s*>(&buf[((kcgl * 4 + g * 2 + 0) * 64 + lane) * 8]);
            const v8s af1 = *reinterpret_cast<const v8s*>(&buf[((kcgl * 4 + g * 2 + 1) * 64 + lane) * 8]);
            #pragma unroll
            for (int ntl = 0; ntl < 8; ntl++) {
                const int ntg = ch * 8 + ntl;
                const v8s bf = *reinterpret_cast<const v8s*>(
                    Wdo_frag + ((size_t)(ntg * 16 + kcg) * 64 + lane) * 8);
                accM[0][ntl] = __builtin_amdgcn_mfma_f32_16x16x32_bf16(af0, bf, accM[0][ntl], 0, 0, 0);
                accM[1][ntl] = __builtin_amdgcn_mfma_f32_16x16x32_bf16(af1, bf, accM[1][ntl], 0, 0, 0);
            }
        }
        __syncthreads();
    }
    // ---- epilogue: D col=lane&15 (Wdo col), row=(lane>>4)*4+j ----
    #pragma unroll
    for (int s = 0; s < 2; s++) {
        const int rowbase = rb + (g * 2 + s) * 16;
        #pragma unroll
        for (int ntl = 0; ntl < 8; ntl++) {
            const int col = ch * 128 + ntl * 16 + (lane & 15);
            const float bz = bias3[col];
            #pragma unroll
            for (int j = 0; j < 4; j++) {
                const size_t row = (size_t)(rowbase + (lane >> 4) * 4 + j);
                recon[row * 256 + col] = accM[s][ntl][j] + bz;
            }
        }
    }
}

// ---------------- host ----------------
extern "C" void kernel_launch(void* const* d_in, const int* in_sizes, int n_in,
                              void* d_out, int out_size, void* d_ws, size_t ws_size,
                              hipStream_t stream)
{
    const float* x        = (const float*)d_in[0];
    const float* pre_bias = (const float*)d_in[1];
    const float* W_eh     = (const float*)d_in[2];
    const float* b_eh     = (const float*)d_in[3];
    const float* W_eo     = (const float*)d_in[4];
    const float* b_eo     = (const float*)d_in[5];
    const float* lat_b    = (const float*)d_in[6];
    const float* W_dh     = (const float*)d_in[7];
    const float* b_dh     = (const float*)d_in[8];
    const float* W_do     = (const float*)d_in[9];
    const float* b_do     = (const float*)d_in[10];
    const float* dec_b    = (const float*)d_in[11];

    float* out = (float*)d_out;
    float* recon_out = out;
    float* sl_out    = out + (size_t)B_TOT * 256;
    float* pre_out   = sl_out + (size_t)B_TOT * 64;
    float* mask_out  = pre_out + (size_t)B_TOT * 64;
    float* spars_out = mask_out + (size_t)B_TOT * 64;

    char* ws = (char*)d_ws;
    unsigned short* WdhB  = (unsigned short*)ws;            // 64 KB (of 128 KB slot)
    float* bias3          = (float*)(ws + 131072);
    unsigned short* WdoF  = (unsigned short*)(ws + 132096);
    unsigned short* WehHi = (unsigned short*)(ws + 394240);
    unsigned short* WehLo = (unsigned short*)(ws + 656384);
    unsigned short* WeoHi = (unsigned short*)(ws + 918528);
    unsigned short* WeoLo = (unsigned short*)(ws + 984064);
    int* fcount           = (int*)(ws + 1049600);
    int* flist            = (int*)(ws + 1049664);
    unsigned short* hHi   = (unsigned short*)(ws + 1049664 + 524288);
    unsigned short* hLo   = hHi + (size_t)B_TOT * 512;

    k_prep<<<32, 256, 0, stream>>>(W_dh, b_do, dec_b, pre_bias, W_do, W_eh, W_eo,
                                   WdhB, bias3, WdoF, WehHi, WehLo, WeoHi, WeoLo,
                                   spars_out, fcount);

    k_enc1<<<B_TOT / 64, 512, 0, stream>>>(x, pre_bias, WehHi, WehLo, b_eh, hHi, hLo);

    k_enc2_topk<<<B_TOT / 128, 256, 0, stream>>>(hHi, hLo, WeoHi, WeoLo, b_eo, lat_b,
                                                 pre_out, mask_out, sl_out,
                                                 fcount, flist);

    k_repair<<<256, 256, 0, stream>>>(x, pre_bias, W_eh, b_eh, W_eo, b_eo, lat_b,
                                      fcount, flist, pre_out, mask_out, sl_out);

    k_dec<<<B_TOT / 64, 256, 0, stream>>>(sl_out, b_dh, WdhB, WdoF, bias3, recon_out);
}

// Round 15
// 491.058 us; speedup vs baseline: 1.6277x; 1.0042x over previous
//
#include <hip/hip_runtime.h>
#include <stdint.h>

#define B_TOT 131072
#define GAP_TAU 2.5e-4f

typedef short v8s __attribute__((ext_vector_type(8)));
typedef float v4f __attribute__((ext_vector_type(4)));

__device__ __forceinline__ unsigned short f2bf(float f) {
    union { float f; unsigned u; } v; v.f = f;
    unsigned u = v.u;
    u += 0x7fffu + ((u >> 16) & 1u);      // RNE
    return (unsigned short)(u >> 16);
}
__device__ __forceinline__ float bf2f(unsigned short s) {
    union { unsigned u; float f; } v; v.u = ((unsigned)s) << 16;
    return v.f;
}
__device__ __forceinline__ unsigned pack2(float lo, float hi) {
    return (unsigned)f2bf(lo) | ((unsigned)f2bf(hi) << 16);
}

// ---------------- K0: prep (weights swizzle + fcount zero) ----------------
__global__ void k_prep(const float* __restrict__ W_dh,      // [512][64]
                       const float* __restrict__ b_do,
                       const float* __restrict__ dec_b,
                       const float* __restrict__ pre_bias,
                       const float* __restrict__ W_do,
                       const float* __restrict__ W_eh,
                       const float* __restrict__ W_eo,
                       unsigned short* __restrict__ WdhB,    // hd-GEMM W-frags [32ht][2kc][64][8]
                       float* __restrict__ bias3,
                       unsigned short* __restrict__ Wdo_frag,
                       unsigned short* __restrict__ WehHi,
                       unsigned short* __restrict__ WehLo,
                       unsigned short* __restrict__ WeoHi,
                       unsigned short* __restrict__ WeoLo,
                       float* __restrict__ spars_out,
                       int* __restrict__ fcount)
{
    int t = blockIdx.x * blockDim.x + threadIdx.x;
    int nthr = gridDim.x * blockDim.x;
    // WdhB: frag (ht,kc,lane): W_dh[ht*16+(lane&15)][kc*32+(lane>>4)*8 + i]
    for (int g = t; g < 32 * 2 * 64; g += nthr) {
        int lane = g & 63;
        int rem = g >> 6;
        int kc = rem & 1, ht = rem >> 1;
        int h = ht * 16 + (lane & 15);
        int l = kc * 32 + (lane >> 4) * 8;
        const float* src = &W_dh[(size_t)h * 64 + l];
        unsigned short* dst = &WdhB[(size_t)g * 8];
        #pragma unroll
        for (int i = 0; i < 8; i++) dst[i] = f2bf(src[i]);
    }
    for (int g = t; g < 16384; g += nthr) {     // Wdo B-frag
        int lane = g & 63;
        int q = g >> 6;
        int nt = q >> 4, kc = q & 15;
        int col = nt * 16 + (lane & 15);
        int kbase = kc * 32 + (lane >> 4) * 8;
        const float* src = &W_do[(size_t)col * 512 + kbase];
        unsigned short* dst = &Wdo_frag[(size_t)g * 8];
        #pragma unroll
        for (int i = 0; i < 8; i++) dst[i] = f2bf(src[i]);
    }
    for (int g = t; g < 32 * 8 * 64; g += nthr) {   // W_eh hi/lo A-frag
        int lane = g & 63;
        int rem = g >> 6;
        int kcg = rem & 7, ct = rem >> 3;
        int c = ct * 16 + (lane & 15);
        int k = kcg * 32 + (lane >> 4) * 8;
        const float* src = &W_eh[(size_t)c * 256 + k];
        #pragma unroll
        for (int i = 0; i < 8; i++) {
            unsigned short hi = f2bf(src[i]);
            WehHi[(size_t)g * 8 + i] = hi;
            WehLo[(size_t)g * 8 + i] = f2bf(src[i] - bf2f(hi));
        }
    }
    for (int g = t; g < 4 * 16 * 64; g += nthr) {   // W_eo hi/lo A-frag
        int lane = g & 63;
        int rem = g >> 6;
        int kcg = rem & 15, lt = rem >> 4;
        int l = lt * 16 + (lane & 15);
        int k = kcg * 32 + (lane >> 4) * 8;
        const float* src = &W_eo[(size_t)l * 512 + k];
        #pragma unroll
        for (int i = 0; i < 8; i++) {
            unsigned short hi = f2bf(src[i]);
            WeoHi[(size_t)g * 8 + i] = hi;
            WeoLo[(size_t)g * 8 + i] = f2bf(src[i] - bf2f(hi));
        }
    }
    if (t < 256) bias3[t] = b_do[t] + dec_b[t] + pre_bias[t];
    if (t == 0) { spars_out[0] = 5.0f / 64.0f; *fcount = 0; }
}

// h planes OCTET layout: element H(row,k) = ((rowtile*64 + k/8)*16 + row%16)*8 + k%8

// ---------------- K1: h = relu((x-pb) @ W_eh^T + b_eh), split-bf16 MFMA ----------------
// x-stage layout: unit (row, kc, skq) holds bf16 of x[row][kc*32+skq*8 .. +8] at byte
//   row*512 + ((kc*64 + skq*16) ^ ((row&7)<<4))   (conflict-free write AND read)
__global__ __launch_bounds__(512, 2)
void k_enc1(const float* __restrict__ x,
            const float* __restrict__ pre_bias,
            const unsigned short* __restrict__ WehHi,
            const unsigned short* __restrict__ WehLo,
            const float* __restrict__ b_eh,
            unsigned short* __restrict__ hHi,   // octet layout
            unsigned short* __restrict__ hLo)
{
    __shared__ __align__(16) unsigned short aH[64 * 256];  // 32 KB, swizzled rows
    __shared__ __align__(16) unsigned short aL[64 * 256];  // 32 KB
    const int t    = threadIdx.x;
    const int lane = t & 63;
    const int w    = t >> 6;        // 0..7
    const int rb   = blockIdx.x * 64;

    #pragma unroll
    for (int i = 0; i < 4; i++) {
        const int f    = t + i * 512;       // 0..2047
        const int srow = f >> 5;            // 0..63
        const int kc   = (f >> 2) & 7;      // 0..7
        const int skq  = f & 3;             // 0..3
        const float* xp = &x[(size_t)(rb + srow) * 256 + kc * 32 + skq * 8];
        const float* pp = &pre_bias[kc * 32 + skq * 8];
        const float4 v0 = *reinterpret_cast<const float4*>(xp);
        const float4 v1 = *reinterpret_cast<const float4*>(xp + 4);
        const float4 p0 = *reinterpret_cast<const float4*>(pp);
        const float4 p1 = *reinterpret_cast<const float4*>(pp + 4);
        float fv[8] = {v0.x - p0.x, v0.y - p0.y, v0.z - p0.z, v0.w - p0.w,
                       v1.x - p1.x, v1.y - p1.y, v1.z - p1.z, v1.w - p1.w};
        unsigned hi2[4], lo2[4];
        #pragma unroll
        for (int q = 0; q < 4; q++) {
            unsigned short h0 = f2bf(fv[q * 2]), h1 = f2bf(fv[q * 2 + 1]);
            hi2[q] = (unsigned)h0 | ((unsigned)h1 << 16);
            lo2[q] = (unsigned)f2bf(fv[q * 2] - bf2f(h0)) | ((unsigned)f2bf(fv[q * 2 + 1] - bf2f(h1)) << 16);
        }
        const int off = srow * 512 + ((kc * 64 + skq * 16) ^ ((srow & 7) << 4));
        *reinterpret_cast<uint4*>((char*)aH + off) = *reinterpret_cast<uint4*>(hi2);
        *reinterpret_cast<uint4*>((char*)aL + off) = *reinterpret_cast<uint4*>(lo2);
    }
    __syncthreads();

    v4f acc[4][4];
    #pragma unroll
    for (int i = 0; i < 4; i++)
        #pragma unroll
        for (int j = 0; j < 4; j++) acc[i][j] = (v4f){0.f, 0.f, 0.f, 0.f};

    #pragma unroll 2
    for (int kc = 0; kc < 8; ++kc) {
        v8s wh[4], wl[4];
        #pragma unroll
        for (int ntl = 0; ntl < 4; ntl++) {
            const int ct = w * 4 + ntl;
            const size_t idx = ((size_t)(ct * 8 + kc) * 64 + lane) * 8;
            wh[ntl] = *reinterpret_cast<const v8s*>(&WehHi[idx]);
            wl[ntl] = *reinterpret_cast<const v8s*>(&WehLo[idx]);
        }
        v8s ah[4], al[4];
        #pragma unroll
        for (int mt = 0; mt < 4; mt++) {
            const int row = mt * 16 + (lane & 15);
            const int off = row * 512 + ((kc * 64 + (lane >> 4) * 16) ^ ((row & 7) << 4));
            ah[mt] = *reinterpret_cast<const v8s*>((const char*)aH + off);
            al[mt] = *reinterpret_cast<const v8s*>((const char*)aL + off);
        }
        #pragma unroll
        for (int mt = 0; mt < 4; mt++) {
            #pragma unroll
            for (int ntl = 0; ntl < 4; ntl++) {
                acc[mt][ntl] = __builtin_amdgcn_mfma_f32_16x16x32_bf16(wh[ntl], ah[mt], acc[mt][ntl], 0, 0, 0);
                acc[mt][ntl] = __builtin_amdgcn_mfma_f32_16x16x32_bf16(wl[ntl], ah[mt], acc[mt][ntl], 0, 0, 0);
                acc[mt][ntl] = __builtin_amdgcn_mfma_f32_16x16x32_bf16(wh[ntl], al[mt], acc[mt][ntl], 0, 0, 0);
            }
        }
    }
    const int rt0 = rb >> 4;
    const int q   = lane >> 4;
    #pragma unroll
    for (int mt = 0; mt < 4; mt++) {
        #pragma unroll
        for (int ntl = 0; ntl < 4; ntl++) {
            const int c = w * 64 + ntl * 16 + q * 4;
            const float4 be = *reinterpret_cast<const float4*>(&b_eh[c]);
            float h0 = fmaxf(acc[mt][ntl][0] + be.x, 0.f);
            float h1 = fmaxf(acc[mt][ntl][1] + be.y, 0.f);
            float h2 = fmaxf(acc[mt][ntl][2] + be.z, 0.f);
            float h3 = fmaxf(acc[mt][ntl][3] + be.w, 0.f);
            unsigned short s0 = f2bf(h0), s1 = f2bf(h1), s2 = f2bf(h2), s3 = f2bf(h3);
            uint2 phi = { (unsigned)s0 | ((unsigned)s1 << 16), (unsigned)s2 | ((unsigned)s3 << 16) };
            uint2 plo = { (unsigned)f2bf(h0 - bf2f(s0)) | ((unsigned)f2bf(h1 - bf2f(s1)) << 16),
                          (unsigned)f2bf(h2 - bf2f(s2)) | ((unsigned)f2bf(h3 - bf2f(s3)) << 16) };
            const int oct = w * 8 + ntl * 2 + (q >> 1);
            const size_t base = (((size_t)(rt0 + mt) * 64 + oct) * 16 + (lane & 15)) * 8 + (q & 1) * 4;
            *reinterpret_cast<uint2*>(&hHi[base]) = phi;
            *reinterpret_cast<uint2*>(&hLo[base]) = plo;
        }
    }
}

// ---------------- K2: pre_act (split-bf16 MFMA); top-5; gap-flag; outputs ----------------
// 128 rows/block; wave w owns row-tiles {2w, 2w+1} (32 rows); W frags shared across both.
__global__ __launch_bounds__(256, 4)
void k_enc2_topk(const unsigned short* __restrict__ hHi,   // octet layout
                 const unsigned short* __restrict__ hLo,
                 const unsigned short* __restrict__ WeoHi,
                 const unsigned short* __restrict__ WeoLo,
                 const float* __restrict__ b_eo,
                 const float* __restrict__ lat_b,
                 float* __restrict__ pre_out,
                 float* __restrict__ mask_out,
                 float* __restrict__ sl_out,
                 int*   __restrict__ fcount,
                 int*   __restrict__ flist)
{
    __shared__ float pa[128][68];
    __shared__ unsigned long long mbits[128];
    const int t    = threadIdx.x;
    const int lane = t & 63;
    const int w    = t >> 6;
    const int rb   = blockIdx.x * 128;
    const int rtA  = (rb >> 4) + w * 2;
    const int rtB  = rtA + 1;

    v4f acc[2][4];
    #pragma unroll
    for (int s = 0; s < 2; s++)
        #pragma unroll
        for (int i = 0; i < 4; i++) acc[s][i] = (v4f){0.f, 0.f, 0.f, 0.f};

    #pragma unroll 2
    for (int kcl = 0; kcl < 16; ++kcl) {
        const size_t baseA = ((size_t)(rtA * 64 + kcl * 4 + (lane >> 4)) * 16 + (lane & 15)) * 8;
        const size_t baseB = ((size_t)(rtB * 64 + kcl * 4 + (lane >> 4)) * 16 + (lane & 15)) * 8;
        const v8s hhA = *reinterpret_cast<const v8s*>(&hHi[baseA]);
        const v8s hlA = *reinterpret_cast<const v8s*>(&hLo[baseA]);
        const v8s hhB = *reinterpret_cast<const v8s*>(&hHi[baseB]);
        const v8s hlB = *reinterpret_cast<const v8s*>(&hLo[baseB]);
        #pragma unroll
        for (int lt = 0; lt < 4; lt++) {
            const size_t idx = ((size_t)(lt * 16 + kcl) * 64 + lane) * 8;
            const v8s wh = *reinterpret_cast<const v8s*>(&WeoHi[idx]);
            const v8s wl = *reinterpret_cast<const v8s*>(&WeoLo[idx]);
            acc[0][lt] = __builtin_amdgcn_mfma_f32_16x16x32_bf16(wh, hhA, acc[0][lt], 0, 0, 0);
            acc[0][lt] = __builtin_amdgcn_mfma_f32_16x16x32_bf16(wl, hhA, acc[0][lt], 0, 0, 0);
            acc[0][lt] = __builtin_amdgcn_mfma_f32_16x16x32_bf16(wh, hlA, acc[0][lt], 0, 0, 0);
            acc[1][lt] = __builtin_amdgcn_mfma_f32_16x16x32_bf16(wh, hhB, acc[1][lt], 0, 0, 0);
            acc[1][lt] = __builtin_amdgcn_mfma_f32_16x16x32_bf16(wl, hhB, acc[1][lt], 0, 0, 0);
            acc[1][lt] = __builtin_amdgcn_mfma_f32_16x16x32_bf16(wh, hlB, acc[1][lt], 0, 0, 0);
        }
    }
    #pragma unroll
    for (int s = 0; s < 2; s++) {
        const int row = w * 32 + s * 16 + (lane & 15);
        #pragma unroll
        for (int lt = 0; lt < 4; lt++) {
            const int l0 = lt * 16 + ((lane >> 4) << 2);
            const float4 be = *reinterpret_cast<const float4*>(&b_eo[l0]);
            const float4 lb = *reinterpret_cast<const float4*>(&lat_b[l0]);
            float4 o;
            o.x = acc[s][lt][0] + be.x + lb.x;
            o.y = acc[s][lt][1] + be.y + lb.y;
            o.z = acc[s][lt][2] + be.z + lb.z;
            o.w = acc[s][lt][3] + be.w + lb.w;
            *reinterpret_cast<float4*>(&pa[row][l0]) = o;
        }
    }
    __syncthreads();
    if (t < 128) {
        int r = t;
        unsigned long long used = 0ULL;
        float bv[5];
        #pragma unroll
        for (int p = 0; p < 5; p++) {
            float best = -3.402823466e38f; int bidx = 0;
            for (int j = 0; j < 64; j++) {
                float v = pa[r][j];
                if (!((used >> j) & 1ULL) && v > best) { best = v; bidx = j; }
            }
            used |= 1ULL << bidx;
            bv[p] = best;
        }
        mbits[r] = used;
        float v6 = -3.402823466e38f;
        for (int j = 0; j < 64; j++) {
            float v = pa[r][j];
            if (!((used >> j) & 1ULL) && v > v6) v6 = v;
        }
        if (bv[4] - v6 < GAP_TAU) {
            int slot = atomicAdd(fcount, 1);
            flist[slot] = rb + r;
        }
    }
    __syncthreads();
    // fully-coalesced output writes: 16 lanes x float4 = 4 consecutive rows per wave-instr
    {
        const int c = (t & 15) * 4;
        #pragma unroll
        for (int pass = 0; pass < 8; pass++) {
            const int row = pass * 16 + (t >> 4);
            const size_t gr = (size_t)(rb + row);
            const unsigned long long bits = mbits[row];
            const float p0 = pa[row][c + 0], p1 = pa[row][c + 1];
            const float p2 = pa[row][c + 2], p3 = pa[row][c + 3];
            const float m0 = (float)((bits >> (c + 0)) & 1ULL);
            const float m1 = (float)((bits >> (c + 1)) & 1ULL);
            const float m2 = (float)((bits >> (c + 2)) & 1ULL);
            const float m3 = (float)((bits >> (c + 3)) & 1ULL);
            float4 pv = {p0, p1, p2, p3};
            float4 mv = {m0, m1, m2, m3};
            float4 sv = {m0 * p0, m1 * p1, m2 * p2, m3 * p3};
            *reinterpret_cast<float4*>(&pre_out[gr * 64 + c])  = pv;
            *reinterpret_cast<float4*>(&mask_out[gr * 64 + c]) = mv;
            *reinterpret_cast<float4*>(&sl_out[gr * 64 + c])   = sv;
        }
    }
}

// ---------------- K2b: fp32 exact repair of gap-flagged rows ----------------
__global__ __launch_bounds__(256)
void k_repair(const float* __restrict__ x,
              const float* __restrict__ pre_bias,
              const float* __restrict__ W_eh,     // [512][256]
              const float* __restrict__ b_eh,
              const float* __restrict__ W_eo,     // [64][512]
              const float* __restrict__ b_eo,
              const float* __restrict__ lat_b,
              const int* __restrict__ fcount,
              const int* __restrict__ flist,
              float* __restrict__ pre_out,
              float* __restrict__ mask_out,
              float* __restrict__ sl_out)
{
    __shared__ float xs[256];
    __shared__ float hs[512];
    __shared__ float part[64][4];
    __shared__ float pav[64];
    __shared__ unsigned long long bitsS;
    const int t = threadIdx.x;
    const int n = *fcount;
    #pragma unroll 1
    for (int it = blockIdx.x; it < n; it += gridDim.x) {
        const int r = flist[it];
        xs[t] = x[(size_t)r * 256 + t] - pre_bias[t];
        __syncthreads();
        #pragma unroll 1
        for (int j = t; j < 512; j += 256) {
            const float* wr = &W_eh[(size_t)j * 256];
            float acc = 0.f;
            #pragma unroll
            for (int k = 0; k < 256; k += 4) {
                const float4 wv = *reinterpret_cast<const float4*>(&wr[k]);
                acc = fmaf(wv.x, xs[k + 0], acc);
                acc = fmaf(wv.y, xs[k + 1], acc);
                acc = fmaf(wv.z, xs[k + 2], acc);
                acc = fmaf(wv.w, xs[k + 3], acc);
            }
            hs[j] = fmaxf(acc + b_eh[j], 0.f);
        }
        __syncthreads();
        {
            const int l = t & 63, q = t >> 6;
            const float* wr = &W_eo[(size_t)l * 512 + q * 128];
            const float* hp = &hs[q * 128];
            float acc = 0.f;
            #pragma unroll
            for (int k = 0; k < 128; k += 4) {
                const float4 wv = *reinterpret_cast<const float4*>(&wr[k]);
                acc = fmaf(wv.x, hp[k + 0], acc);
                acc = fmaf(wv.y, hp[k + 1], acc);
                acc = fmaf(wv.z, hp[k + 2], acc);
                acc = fmaf(wv.w, hp[k + 3], acc);
            }
            part[l][q] = acc;
        }
        __syncthreads();
        if (t < 64)
            pav[t] = ((part[t][0] + part[t][1]) + (part[t][2] + part[t][3])) + b_eo[t] + lat_b[t];
        __syncthreads();
        if (t == 0) {
            unsigned long long used = 0ULL;
            #pragma unroll
            for (int p = 0; p < 5; p++) {
                float best = -3.402823466e38f; int bidx = 0;
                for (int j = 0; j < 64; j++) {
                    float v = pav[j];
                    if (!((used >> j) & 1ULL) && v > best) { best = v; bidx = j; }
                }
                used |= 1ULL << bidx;
            }
            bitsS = used;
        }
        __syncthreads();
        if (t < 64) {
            const size_t gr = (size_t)r;
            const float v = pav[t];
            const float m = (float)((bitsS >> t) & 1ULL);
            pre_out[gr * 64 + t]  = v;
            mask_out[gr * 64 + t] = m;
            sl_out[gr * 64 + t]   = m * v;
        }
        __syncthreads();
    }
}

// ---------------- K3 phase 1: hd-tile GEMM (swapped operands -> A-frag-native D) ----------------
__device__ __forceinline__ void hd_phase1(unsigned short* __restrict__ buf,
                                          const unsigned short* __restrict__ slA,
                                          const unsigned short* __restrict__ WdhB,
                                          const float* __restrict__ b_dh,
                                          int c, int w, int lane)
{
    v4f ah[2][4];
    #pragma unroll
    for (int htl = 0; htl < 2; htl++) {
        const int h0 = (c * 8 + w * 2 + htl) * 16 + ((lane >> 4) << 2);
        const float4 bd = *reinterpret_cast<const float4*>(&b_dh[h0]);
        #pragma unroll
        for (int mt = 0; mt < 4; mt++) ah[htl][mt] = (v4f){bd.x, bd.y, bd.z, bd.w};
    }
    #pragma unroll
    for (int kc = 0; kc < 2; kc++) {
        v8s sa[4];
        #pragma unroll
        for (int mt = 0; mt < 4; mt++)
            sa[mt] = *reinterpret_cast<const v8s*>(&slA[((kc * 4 + mt) * 64 + lane) * 8]);
        #pragma unroll
        for (int htl = 0; htl < 2; htl++) {
            const int ht = c * 8 + w * 2 + htl;
            const v8s wb = *reinterpret_cast<const v8s*>(&WdhB[((size_t)(ht * 2 + kc) * 64 + lane) * 8]);
            #pragma unroll
            for (int mt = 0; mt < 4; mt++)
                ah[htl][mt] = __builtin_amdgcn_mfma_f32_16x16x32_bf16(wb, sa[mt], ah[htl][mt], 0, 0, 0);
        }
    }
    #pragma unroll
    for (int htl = 0; htl < 2; htl++) {
        const int hbase = (w * 2 + htl) * 16 + ((lane >> 4) << 2);   // h within 128-chunk
        const int kcgl  = hbase >> 5;
        const int lp    = (((hbase & 31) >> 3) << 4) + (lane & 15);
        const int ii    = hbase & 7;                                 // 0 or 4
        #pragma unroll
        for (int mt = 0; mt < 4; mt++) {
            uint2 o;
            o.x = pack2(fmaxf(ah[htl][mt][0], 0.f), fmaxf(ah[htl][mt][1], 0.f));
            o.y = pack2(fmaxf(ah[htl][mt][2], 0.f), fmaxf(ah[htl][mt][3], 0.f));
            *reinterpret_cast<uint2*>(&buf[((kcgl * 4 + mt) * 64 + lp) * 8 + ii]) = o;
        }
    }
}

// ---------------- K3: recon fully via MFMA, double-buffered hd, 1 barrier/chunk ----------------
__global__ __launch_bounds__(256)
void k_dec(const float* __restrict__ sl,              // [B][64] f32 (post-repair)
           const float* __restrict__ b_dh,            // [512]
           const unsigned short* __restrict__ WdhB,
           const unsigned short* __restrict__ Wdo_frag,
           const float* __restrict__ bias3,
           float* __restrict__ recon)                 // global [B][256]
{
    __shared__ __align__(16) unsigned short slA[2 * 4 * 64 * 8];      // 4 KB
    __shared__ __align__(16) unsigned short hdA[2][4 * 4 * 64 * 8];   // 2 x 16 KB
    const int t    = threadIdx.x;
    const int rb   = blockIdx.x * 64;
    const int lane = t & 63;
    const int w    = t >> 6;

    // ---- stage sl rows as bf16 frags ----
    {
        const int row = t >> 2;
        const int seg = (t & 3) * 16;
        const float* sp = &sl[(size_t)(rb + row) * 64 + seg];
        const int mt = row >> 4;
        #pragma unroll
        for (int q = 0; q < 4; q++) {
            const float4 v = *reinterpret_cast<const float4*>(sp + q * 4);
            const float vals[4] = {v.x, v.y, v.z, v.w};
            #pragma unroll
            for (int e = 0; e < 4; e++) {
                const int k  = seg + q * 4 + e;
                const int kc = k >> 5;
                const int lp = ((k & 31) >> 3) * 16 + (row & 15);
                slA[((kc * 4 + mt) * 64 + lp) * 8 + (k & 7)] = f2bf(vals[e]);
            }
        }
    }
    __syncthreads();

    const int g  = w >> 1;      // main-GEMM row-group
    const int ch = w & 1;       // main-GEMM col-half

    v4f accM[2][8];
    #pragma unroll
    for (int s = 0; s < 2; s++)
        #pragma unroll
        for (int n = 0; n < 8; n++) accM[s][n] = (v4f){0.f, 0.f, 0.f, 0.f};

    hd_phase1(hdA[0], slA, WdhB, b_dh, 0, w, lane);
    __syncthreads();

    #pragma unroll 1
    for (int c = 0; c < 4; ++c) {
        if (c < 3)
            hd_phase1(hdA[(c + 1) & 1], slA, WdhB, b_dh, c + 1, w, lane);
        const unsigned short* buf = hdA[c & 1];
        #pragma unroll
        for (int kcgl = 0; kcgl < 4; ++kcgl) {
            const int kcg = c * 4 + kcgl;
            const v8s af0 = *reinterpret_cast<const v8s*>(&buf[((kcgl * 4 + g * 2 + 0) * 64 + lane) * 8]);
            const v8s af1 = *reinterpret_cast<const v8s*>(&buf[((kcgl * 4 + g * 2 + 1) * 64 + lane) * 8]);
            #pragma unroll
            for (int ntl = 0; ntl < 8; ntl++) {
                const int ntg = ch * 8 + ntl;
                const v8s bf = *reinterpret_cast<const v8s*>(
                    Wdo_frag + ((size_t)(ntg * 16 + kcg) * 64 + lane) * 8);
                accM[0][ntl] = __builtin_amdgcn_mfma_f32_16x16x32_bf16(af0, bf, accM[0][ntl], 0, 0, 0);
                accM[1][ntl] = __builtin_amdgcn_mfma_f32_16x16x32_bf16(af1, bf, accM[1][ntl], 0, 0, 0);
            }
        }
        __syncthreads();
    }
    // ---- epilogue: D col=lane&15 (Wdo col), row=(lane>>4)*4+j ----
    #pragma unroll
    for (int s = 0; s < 2; s++) {
        const int rowbase = rb + (g * 2 + s) * 16;
        #pragma unroll
        for (int ntl = 0; ntl < 8; ntl++) {
            const int col = ch * 128 + ntl * 16 + (lane & 15);
            const float bz = bias3[col];
            #pragma unroll
            for (int j = 0; j < 4; j++) {
                const size_t row = (size_t)(rowbase + (lane >> 4) * 4 + j);
                recon[row * 256 + col] = accM[s][ntl][j] + bz;
            }
        }
    }
}

// ---------------- host ----------------
extern "C" void kernel_launch(void* const* d_in, const int* in_sizes, int n_in,
                              void* d_out, int out_size, void* d_ws, size_t ws_size,
                              hipStream_t stream)
{
    const float* x        = (const float*)d_in[0];
    const float* pre_bias = (const float*)d_in[1];
    const float* W_eh     = (const float*)d_in[2];
    const float* b_eh     = (const float*)d_in[3];
    const float* W_eo     = (const float*)d_in[4];
    const float* b_eo     = (const float*)d_in[5];
    const float* lat_b    = (const float*)d_in[6];
    const float* W_dh     = (const float*)d_in[7];
    const float* b_dh     = (const float*)d_in[8];
    const float* W_do     = (const float*)d_in[9];
    const float* b_do     = (const float*)d_in[10];
    const float* dec_b    = (const float*)d_in[11];

    float* out = (float*)d_out;
    float* recon_out = out;
    float* sl_out    = out + (size_t)B_TOT * 256;
    float* pre_out   = sl_out + (size_t)B_TOT * 64;
    float* mask_out  = pre_out + (size_t)B_TOT * 64;
    float* spars_out = mask_out + (size_t)B_TOT * 64;

    char* ws = (char*)d_ws;
    unsigned short* WdhB  = (unsigned short*)ws;            // 64 KB (of 128 KB slot)
    float* bias3          = (float*)(ws + 131072);
    unsigned short* WdoF  = (unsigned short*)(ws + 132096);
    unsigned short* WehHi = (unsigned short*)(ws + 394240);
    unsigned short* WehLo = (unsigned short*)(ws + 656384);
    unsigned short* WeoHi = (unsigned short*)(ws + 918528);
    unsigned short* WeoLo = (unsigned short*)(ws + 984064);
    int* fcount           = (int*)(ws + 1049600);
    int* flist            = (int*)(ws + 1049664);
    unsigned short* hHi   = (unsigned short*)(ws + 1049664 + 524288);
    unsigned short* hLo   = hHi + (size_t)B_TOT * 512;

    k_prep<<<32, 256, 0, stream>>>(W_dh, b_do, dec_b, pre_bias, W_do, W_eh, W_eo,
                                   WdhB, bias3, WdoF, WehHi, WehLo, WeoHi, WeoLo,
                                   spars_out, fcount);

    k_enc1<<<B_TOT / 64, 512, 0, stream>>>(x, pre_bias, WehHi, WehLo, b_eh, hHi, hLo);

    k_enc2_topk<<<B_TOT / 128, 256, 0, stream>>>(hHi, hLo, WeoHi, WeoLo, b_eo, lat_b,
                                                 pre_out, mask_out, sl_out,
                                                 fcount, flist);

    k_repair<<<256, 256, 0, stream>>>(x, pre_bias, W_eh, b_eh, W_eo, b_eo, lat_b,
                                      fcount, flist, pre_out, mask_out, sl_out);

    k_dec<<<B_TOT / 64, 256, 0, stream>>>(sl_out, b_dh, WdhB, WdoF, bias3, recon_out);
}

// Round 16
// 476.205 us; speedup vs baseline: 1.6784x; 1.0312x over previous
//
#include <hip/hip_runtime.h>
#include <stdint.h>

#define B_TOT 131072
#define GAP_TAU 2.5e-4f

typedef short v8s __attribute__((ext_vector_type(8)));
typedef float v4f __attribute__((ext_vector_type(4)));

__device__ __forceinline__ unsigned short f2bf(float f) {
    union { float f; unsigned u; } v; v.f = f;
    unsigned u = v.u;
    u += 0x7fffu + ((u >> 16) & 1u);      // RNE
    return (unsigned short)(u >> 16);
}
__device__ __forceinline__ float bf2f(unsigned short s) {
    union { unsigned u; float f; } v; v.u = ((unsigned)s) << 16;
    return v.f;
}
__device__ __forceinline__ unsigned pack2(float lo, float hi) {
    return (unsigned)f2bf(lo) | ((unsigned)f2bf(hi) << 16);
}

// ---------------- K0: prep (weights swizzle + fcount zero) ----------------
__global__ void k_prep(const float* __restrict__ W_dh,      // [512][64]
                       const float* __restrict__ b_do,
                       const float* __restrict__ dec_b,
                       const float* __restrict__ pre_bias,
                       const float* __restrict__ W_do,
                       const float* __restrict__ W_eh,
                       const float* __restrict__ W_eo,
                       unsigned short* __restrict__ WdhB,    // hd-GEMM W-frags [32ht][2kc][64][8]
                       float* __restrict__ bias3,
                       unsigned short* __restrict__ Wdo_frag,
                       unsigned short* __restrict__ WehHi,
                       unsigned short* __restrict__ WehLo,
                       unsigned short* __restrict__ WeoHi,
                       unsigned short* __restrict__ WeoLo,
                       float* __restrict__ spars_out,
                       int* __restrict__ fcount)
{
    int t = blockIdx.x * blockDim.x + threadIdx.x;
    int nthr = gridDim.x * blockDim.x;
    // WdhB: frag (ht,kc,lane): W_dh[ht*16+(lane&15)][kc*32+(lane>>4)*8 + i]
    for (int g = t; g < 32 * 2 * 64; g += nthr) {
        int lane = g & 63;
        int rem = g >> 6;
        int kc = rem & 1, ht = rem >> 1;
        int h = ht * 16 + (lane & 15);
        int l = kc * 32 + (lane >> 4) * 8;
        const float* src = &W_dh[(size_t)h * 64 + l];
        unsigned short* dst = &WdhB[(size_t)g * 8];
        #pragma unroll
        for (int i = 0; i < 8; i++) dst[i] = f2bf(src[i]);
    }
    for (int g = t; g < 16384; g += nthr) {     // Wdo B-frag
        int lane = g & 63;
        int q = g >> 6;
        int nt = q >> 4, kc = q & 15;
        int col = nt * 16 + (lane & 15);
        int kbase = kc * 32 + (lane >> 4) * 8;
        const float* src = &W_do[(size_t)col * 512 + kbase];
        unsigned short* dst = &Wdo_frag[(size_t)g * 8];
        #pragma unroll
        for (int i = 0; i < 8; i++) dst[i] = f2bf(src[i]);
    }
    for (int g = t; g < 32 * 8 * 64; g += nthr) {   // W_eh hi/lo A-frag
        int lane = g & 63;
        int rem = g >> 6;
        int kcg = rem & 7, ct = rem >> 3;
        int c = ct * 16 + (lane & 15);
        int k = kcg * 32 + (lane >> 4) * 8;
        const float* src = &W_eh[(size_t)c * 256 + k];
        #pragma unroll
        for (int i = 0; i < 8; i++) {
            unsigned short hi = f2bf(src[i]);
            WehHi[(size_t)g * 8 + i] = hi;
            WehLo[(size_t)g * 8 + i] = f2bf(src[i] - bf2f(hi));
        }
    }
    for (int g = t; g < 4 * 16 * 64; g += nthr) {   // W_eo hi/lo A-frag
        int lane = g & 63;
        int rem = g >> 6;
        int kcg = rem & 15, lt = rem >> 4;
        int l = lt * 16 + (lane & 15);
        int k = kcg * 32 + (lane >> 4) * 8;
        const float* src = &W_eo[(size_t)l * 512 + k];
        #pragma unroll
        for (int i = 0; i < 8; i++) {
            unsigned short hi = f2bf(src[i]);
            WeoHi[(size_t)g * 8 + i] = hi;
            WeoLo[(size_t)g * 8 + i] = f2bf(src[i] - bf2f(hi));
        }
    }
    if (t < 256) bias3[t] = b_do[t] + dec_b[t] + pre_bias[t];
    if (t == 0) { spars_out[0] = 5.0f / 64.0f; *fcount = 0; }
}

// h planes OCTET layout: element H(row,k) = ((rowtile*64 + k/8)*16 + row%16)*8 + k%8

// ---------------- K1: h = relu((x-pb) @ W_eh^T + b_eh), split-bf16 MFMA ----------------
// 2-pass column split: live accums halved (32 v4f regs) so 2 blocks/CU stay resident.
// Per-output accumulation order bit-identical to prior rounds.
__global__ __launch_bounds__(512, 4)
void k_enc1(const float* __restrict__ x,
            const float* __restrict__ pre_bias,
            const unsigned short* __restrict__ WehHi,
            const unsigned short* __restrict__ WehLo,
            const float* __restrict__ b_eh,
            unsigned short* __restrict__ hHi,   // octet layout
            unsigned short* __restrict__ hLo)
{
    __shared__ __align__(16) unsigned short aH[64 * 256];  // 32 KB, swizzled rows
    __shared__ __align__(16) unsigned short aL[64 * 256];  // 32 KB
    const int t    = threadIdx.x;
    const int lane = t & 63;
    const int w    = t >> 6;        // 0..7
    const int rb   = blockIdx.x * 64;

    #pragma unroll
    for (int i = 0; i < 4; i++) {
        const int f    = t + i * 512;       // 0..2047
        const int srow = f >> 5;            // 0..63
        const int kc   = (f >> 2) & 7;      // 0..7
        const int skq  = f & 3;             // 0..3
        const float* xp = &x[(size_t)(rb + srow) * 256 + kc * 32 + skq * 8];
        const float* pp = &pre_bias[kc * 32 + skq * 8];
        const float4 v0 = *reinterpret_cast<const float4*>(xp);
        const float4 v1 = *reinterpret_cast<const float4*>(xp + 4);
        const float4 p0 = *reinterpret_cast<const float4*>(pp);
        const float4 p1 = *reinterpret_cast<const float4*>(pp + 4);
        float fv[8] = {v0.x - p0.x, v0.y - p0.y, v0.z - p0.z, v0.w - p0.w,
                       v1.x - p1.x, v1.y - p1.y, v1.z - p1.z, v1.w - p1.w};
        unsigned hi2[4], lo2[4];
        #pragma unroll
        for (int q = 0; q < 4; q++) {
            unsigned short h0 = f2bf(fv[q * 2]), h1 = f2bf(fv[q * 2 + 1]);
            hi2[q] = (unsigned)h0 | ((unsigned)h1 << 16);
            lo2[q] = (unsigned)f2bf(fv[q * 2] - bf2f(h0)) | ((unsigned)f2bf(fv[q * 2 + 1] - bf2f(h1)) << 16);
        }
        const int off = srow * 512 + ((kc * 64 + skq * 16) ^ ((srow & 7) << 4));
        *reinterpret_cast<uint4*>((char*)aH + off) = *reinterpret_cast<uint4*>(hi2);
        *reinterpret_cast<uint4*>((char*)aL + off) = *reinterpret_cast<uint4*>(lo2);
    }
    __syncthreads();

    const int rt0 = rb >> 4;
    const int q   = lane >> 4;

    #pragma unroll 1
    for (int pass = 0; pass < 2; ++pass) {
        const int ct0 = w * 4 + pass * 2;

        v4f acc[4][2];
        #pragma unroll
        for (int i = 0; i < 4; i++)
            #pragma unroll
            for (int j = 0; j < 2; j++) acc[i][j] = (v4f){0.f, 0.f, 0.f, 0.f};

        #pragma unroll 2
        for (int kc = 0; kc < 8; ++kc) {
            v8s wh[2], wl[2];
            #pragma unroll
            for (int ntl = 0; ntl < 2; ntl++) {
                const size_t idx = ((size_t)((ct0 + ntl) * 8 + kc) * 64 + lane) * 8;
                wh[ntl] = *reinterpret_cast<const v8s*>(&WehHi[idx]);
                wl[ntl] = *reinterpret_cast<const v8s*>(&WehLo[idx]);
            }
            v8s ah[4], al[4];
            #pragma unroll
            for (int mt = 0; mt < 4; mt++) {
                const int row = mt * 16 + (lane & 15);
                const int off = row * 512 + ((kc * 64 + (lane >> 4) * 16) ^ ((row & 7) << 4));
                ah[mt] = *reinterpret_cast<const v8s*>((const char*)aH + off);
                al[mt] = *reinterpret_cast<const v8s*>((const char*)aL + off);
            }
            #pragma unroll
            for (int mt = 0; mt < 4; mt++) {
                #pragma unroll
                for (int ntl = 0; ntl < 2; ntl++) {
                    acc[mt][ntl] = __builtin_amdgcn_mfma_f32_16x16x32_bf16(wh[ntl], ah[mt], acc[mt][ntl], 0, 0, 0);
                    acc[mt][ntl] = __builtin_amdgcn_mfma_f32_16x16x32_bf16(wl[ntl], ah[mt], acc[mt][ntl], 0, 0, 0);
                    acc[mt][ntl] = __builtin_amdgcn_mfma_f32_16x16x32_bf16(wh[ntl], al[mt], acc[mt][ntl], 0, 0, 0);
                }
            }
        }
        // epilogue for this pass's 2 col-tiles
        #pragma unroll
        for (int mt = 0; mt < 4; mt++) {
            #pragma unroll
            for (int ntl = 0; ntl < 2; ntl++) {
                const int ct = ct0 + ntl;
                const int c  = ct * 16 + q * 4;
                const float4 be = *reinterpret_cast<const float4*>(&b_eh[c]);
                float h0 = fmaxf(acc[mt][ntl][0] + be.x, 0.f);
                float h1 = fmaxf(acc[mt][ntl][1] + be.y, 0.f);
                float h2 = fmaxf(acc[mt][ntl][2] + be.z, 0.f);
                float h3 = fmaxf(acc[mt][ntl][3] + be.w, 0.f);
                unsigned short s0 = f2bf(h0), s1 = f2bf(h1), s2 = f2bf(h2), s3 = f2bf(h3);
                uint2 phi = { (unsigned)s0 | ((unsigned)s1 << 16), (unsigned)s2 | ((unsigned)s3 << 16) };
                uint2 plo = { (unsigned)f2bf(h0 - bf2f(s0)) | ((unsigned)f2bf(h1 - bf2f(s1)) << 16),
                              (unsigned)f2bf(h2 - bf2f(s2)) | ((unsigned)f2bf(h3 - bf2f(s3)) << 16) };
                const int oct = ct * 2 + (q >> 1);
                const size_t base = (((size_t)(rt0 + mt) * 64 + oct) * 16 + (lane & 15)) * 8 + (q & 1) * 4;
                *reinterpret_cast<uint2*>(&hHi[base]) = phi;
                *reinterpret_cast<uint2*>(&hLo[base]) = plo;
            }
        }
    }
}

// ---------------- K2: pre_act (split-bf16 MFMA); top-5; gap-flag; outputs ----------------
// 128 rows/block; wave w owns row-tiles {2w, 2w+1} (32 rows); W frags shared across both.
__global__ __launch_bounds__(256, 4)
void k_enc2_topk(const unsigned short* __restrict__ hHi,   // octet layout
                 const unsigned short* __restrict__ hLo,
                 const unsigned short* __restrict__ WeoHi,
                 const unsigned short* __restrict__ WeoLo,
                 const float* __restrict__ b_eo,
                 const float* __restrict__ lat_b,
                 float* __restrict__ pre_out,
                 float* __restrict__ mask_out,
                 float* __restrict__ sl_out,
                 int*   __restrict__ fcount,
                 int*   __restrict__ flist)
{
    __shared__ float pa[128][68];
    __shared__ unsigned long long mbits[128];
    const int t    = threadIdx.x;
    const int lane = t & 63;
    const int w    = t >> 6;
    const int rb   = blockIdx.x * 128;
    const int rtA  = (rb >> 4) + w * 2;
    const int rtB  = rtA + 1;

    v4f acc[2][4];
    #pragma unroll
    for (int s = 0; s < 2; s++)
        #pragma unroll
        for (int i = 0; i < 4; i++) acc[s][i] = (v4f){0.f, 0.f, 0.f, 0.f};

    #pragma unroll 2
    for (int kcl = 0; kcl < 16; ++kcl) {
        const size_t baseA = ((size_t)(rtA * 64 + kcl * 4 + (lane >> 4)) * 16 + (lane & 15)) * 8;
        const size_t baseB = ((size_t)(rtB * 64 + kcl * 4 + (lane >> 4)) * 16 + (lane & 15)) * 8;
        const v8s hhA = *reinterpret_cast<const v8s*>(&hHi[baseA]);
        const v8s hlA = *reinterpret_cast<const v8s*>(&hLo[baseA]);
        const v8s hhB = *reinterpret_cast<const v8s*>(&hHi[baseB]);
        const v8s hlB = *reinterpret_cast<const v8s*>(&hLo[baseB]);
        #pragma unroll
        for (int lt = 0; lt < 4; lt++) {
            const size_t idx = ((size_t)(lt * 16 + kcl) * 64 + lane) * 8;
            const v8s wh = *reinterpret_cast<const v8s*>(&WeoHi[idx]);
            const v8s wl = *reinterpret_cast<const v8s*>(&WeoLo[idx]);
            acc[0][lt] = __builtin_amdgcn_mfma_f32_16x16x32_bf16(wh, hhA, acc[0][lt], 0, 0, 0);
            acc[0][lt] = __builtin_amdgcn_mfma_f32_16x16x32_bf16(wl, hhA, acc[0][lt], 0, 0, 0);
            acc[0][lt] = __builtin_amdgcn_mfma_f32_16x16x32_bf16(wh, hlA, acc[0][lt], 0, 0, 0);
            acc[1][lt] = __builtin_amdgcn_mfma_f32_16x16x32_bf16(wh, hhB, acc[1][lt], 0, 0, 0);
            acc[1][lt] = __builtin_amdgcn_mfma_f32_16x16x32_bf16(wl, hhB, acc[1][lt], 0, 0, 0);
            acc[1][lt] = __builtin_amdgcn_mfma_f32_16x16x32_bf16(wh, hlB, acc[1][lt], 0, 0, 0);
        }
    }
    #pragma unroll
    for (int s = 0; s < 2; s++) {
        const int row = w * 32 + s * 16 + (lane & 15);
        #pragma unroll
        for (int lt = 0; lt < 4; lt++) {
            const int l0 = lt * 16 + ((lane >> 4) << 2);
            const float4 be = *reinterpret_cast<const float4*>(&b_eo[l0]);
            const float4 lb = *reinterpret_cast<const float4*>(&lat_b[l0]);
            float4 o;
            o.x = acc[s][lt][0] + be.x + lb.x;
            o.y = acc[s][lt][1] + be.y + lb.y;
            o.z = acc[s][lt][2] + be.z + lb.z;
            o.w = acc[s][lt][3] + be.w + lb.w;
            *reinterpret_cast<float4*>(&pa[row][l0]) = o;
        }
    }
    __syncthreads();
    if (t < 128) {
        int r = t;
        unsigned long long used = 0ULL;
        float bv[5];
        #pragma unroll
        for (int p = 0; p < 5; p++) {
            float best = -3.402823466e38f; int bidx = 0;
            for (int j = 0; j < 64; j++) {
                float v = pa[r][j];
                if (!((used >> j) & 1ULL) && v > best) { best = v; bidx = j; }
            }
            used |= 1ULL << bidx;
            bv[p] = best;
        }
        mbits[r] = used;
        float v6 = -3.402823466e38f;
        for (int j = 0; j < 64; j++) {
            float v = pa[r][j];
            if (!((used >> j) & 1ULL) && v > v6) v6 = v;
        }
        if (bv[4] - v6 < GAP_TAU) {
            int slot = atomicAdd(fcount, 1);
            flist[slot] = rb + r;
        }
    }
    __syncthreads();
    // fully-coalesced output writes: 16 lanes x float4 = 4 consecutive rows per wave-instr
    {
        const int c = (t & 15) * 4;
        #pragma unroll
        for (int pass = 0; pass < 8; pass++) {
            const int row = pass * 16 + (t >> 4);
            const size_t gr = (size_t)(rb + row);
            const unsigned long long bits = mbits[row];
            const float p0 = pa[row][c + 0], p1 = pa[row][c + 1];
            const float p2 = pa[row][c + 2], p3 = pa[row][c + 3];
            const float m0 = (float)((bits >> (c + 0)) & 1ULL);
            const float m1 = (float)((bits >> (c + 1)) & 1ULL);
            const float m2 = (float)((bits >> (c + 2)) & 1ULL);
            const float m3 = (float)((bits >> (c + 3)) & 1ULL);
            float4 pv = {p0, p1, p2, p3};
            float4 mv = {m0, m1, m2, m3};
            float4 sv = {m0 * p0, m1 * p1, m2 * p2, m3 * p3};
            *reinterpret_cast<float4*>(&pre_out[gr * 64 + c])  = pv;
            *reinterpret_cast<float4*>(&mask_out[gr * 64 + c]) = mv;
            *reinterpret_cast<float4*>(&sl_out[gr * 64 + c])   = sv;
        }
    }
}

// ---------------- K2b: fp32 exact repair of gap-flagged rows ----------------
__global__ __launch_bounds__(256)
void k_repair(const float* __restrict__ x,
              const float* __restrict__ pre_bias,
              const float* __restrict__ W_eh,     // [512][256]
              const float* __restrict__ b_eh,
              const float* __restrict__ W_eo,     // [64][512]
              const float* __restrict__ b_eo,
              const float* __restrict__ lat_b,
              const int* __restrict__ fcount,
              const int* __restrict__ flist,
              float* __restrict__ pre_out,
              float* __restrict__ mask_out,
              float* __restrict__ sl_out)
{
    __shared__ float xs[256];
    __shared__ float hs[512];
    __shared__ float part[64][4];
    __shared__ float pav[64];
    __shared__ unsigned long long bitsS;
    const int t = threadIdx.x;
    const int n = *fcount;
    #pragma unroll 1
    for (int it = blockIdx.x; it < n; it += gridDim.x) {
        const int r = flist[it];
        xs[t] = x[(size_t)r * 256 + t] - pre_bias[t];
        __syncthreads();
        #pragma unroll 1
        for (int j = t; j < 512; j += 256) {
            const float* wr = &W_eh[(size_t)j * 256];
            float acc = 0.f;
            #pragma unroll
            for (int k = 0; k < 256; k += 4) {
                const float4 wv = *reinterpret_cast<const float4*>(&wr[k]);
                acc = fmaf(wv.x, xs[k + 0], acc);
                acc = fmaf(wv.y, xs[k + 1], acc);
                acc = fmaf(wv.z, xs[k + 2], acc);
                acc = fmaf(wv.w, xs[k + 3], acc);
            }
            hs[j] = fmaxf(acc + b_eh[j], 0.f);
        }
        __syncthreads();
        {
            const int l = t & 63, q = t >> 6;
            const float* wr = &W_eo[(size_t)l * 512 + q * 128];
            const float* hp = &hs[q * 128];
            float acc = 0.f;
            #pragma unroll
            for (int k = 0; k < 128; k += 4) {
                const float4 wv = *reinterpret_cast<const float4*>(&wr[k]);
                acc = fmaf(wv.x, hp[k + 0], acc);
                acc = fmaf(wv.y, hp[k + 1], acc);
                acc = fmaf(wv.z, hp[k + 2], acc);
                acc = fmaf(wv.w, hp[k + 3], acc);
            }
            part[l][q] = acc;
        }
        __syncthreads();
        if (t < 64)
            pav[t] = ((part[t][0] + part[t][1]) + (part[t][2] + part[t][3])) + b_eo[t] + lat_b[t];
        __syncthreads();
        if (t == 0) {
            unsigned long long used = 0ULL;
            #pragma unroll
            for (int p = 0; p < 5; p++) {
                float best = -3.402823466e38f; int bidx = 0;
                for (int j = 0; j < 64; j++) {
                    float v = pav[j];
                    if (!((used >> j) & 1ULL) && v > best) { best = v; bidx = j; }
                }
                used |= 1ULL << bidx;
            }
            bitsS = used;
        }
        __syncthreads();
        if (t < 64) {
            const size_t gr = (size_t)r;
            const float v = pav[t];
            const float m = (float)((bitsS >> t) & 1ULL);
            pre_out[gr * 64 + t]  = v;
            mask_out[gr * 64 + t] = m;
            sl_out[gr * 64 + t]   = m * v;
        }
        __syncthreads();
    }
}

// ---------------- K3 phase 1: hd-tile GEMM (swapped operands -> A-frag-native D) ----------------
__device__ __forceinline__ void hd_phase1(unsigned short* __restrict__ buf,
                                          const unsigned short* __restrict__ slA,
                                          const unsigned short* __restrict__ WdhB,
                                          const float* __restrict__ b_dh,
                                          int c, int w, int lane)
{
    v4f ah[2][4];
    #pragma unroll
    for (int htl = 0; htl < 2; htl++) {
        const int h0 = (c * 8 + w * 2 + htl) * 16 + ((lane >> 4) << 2);
        const float4 bd = *reinterpret_cast<const float4*>(&b_dh[h0]);
        #pragma unroll
        for (int mt = 0; mt < 4; mt++) ah[htl][mt] = (v4f){bd.x, bd.y, bd.z, bd.w};
    }
    #pragma unroll
    for (int kc = 0; kc < 2; kc++) {
        v8s sa[4];
        #pragma unroll
        for (int mt = 0; mt < 4; mt++)
            sa[mt] = *reinterpret_cast<const v8s*>(&slA[((kc * 4 + mt) * 64 + lane) * 8]);
        #pragma unroll
        for (int htl = 0; htl < 2; htl++) {
            const int ht = c * 8 + w * 2 + htl;
            const v8s wb = *reinterpret_cast<const v8s*>(&WdhB[((size_t)(ht * 2 + kc) * 64 + lane) * 8]);
            #pragma unroll
            for (int mt = 0; mt < 4; mt++)
                ah[htl][mt] = __builtin_amdgcn_mfma_f32_16x16x32_bf16(wb, sa[mt], ah[htl][mt], 0, 0, 0);
        }
    }
    #pragma unroll
    for (int htl = 0; htl < 2; htl++) {
        const int hbase = (w * 2 + htl) * 16 + ((lane >> 4) << 2);   // h within 128-chunk
        const int kcgl  = hbase >> 5;
        const int lp    = (((hbase & 31) >> 3) << 4) + (lane & 15);
        const int ii    = hbase & 7;                                 // 0 or 4
        #pragma unroll
        for (int mt = 0; mt < 4; mt++) {
            uint2 o;
            o.x = pack2(fmaxf(ah[htl][mt][0], 0.f), fmaxf(ah[htl][mt][1], 0.f));
            o.y = pack2(fmaxf(ah[htl][mt][2], 0.f), fmaxf(ah[htl][mt][3], 0.f));
            *reinterpret_cast<uint2*>(&buf[((kcgl * 4 + mt) * 64 + lp) * 8 + ii]) = o;
        }
    }
}

// ---------------- K3: recon fully via MFMA, double-buffered hd, 1 barrier/chunk ----------------
__global__ __launch_bounds__(256)
void k_dec(const float* __restrict__ sl,              // [B][64] f32 (post-repair)
           const float* __restrict__ b_dh,            // [512]
           const unsigned short* __restrict__ WdhB,
           const unsigned short* __restrict__ Wdo_frag,
           const float* __restrict__ bias3,
           float* __restrict__ recon)                 // global [B][256]
{
    __shared__ __align__(16) unsigned short slA[2 * 4 * 64 * 8];      // 4 KB
    __shared__ __align__(16) unsigned short hdA[2][4 * 4 * 64 * 8];   // 2 x 16 KB
    const int t    = threadIdx.x;
    const int rb   = blockIdx.x * 64;
    const int lane = t & 63;
    const int w    = t >> 6;

    // ---- stage sl rows as bf16 frags ----
    {
        const int row = t >> 2;
        const int seg = (t & 3) * 16;
        const float* sp = &sl[(size_t)(rb + row) * 64 + seg];
        const int mt = row >> 4;
        #pragma unroll
        for (int q = 0; q < 4; q++) {
            const float4 v = *reinterpret_cast<const float4*>(sp + q * 4);
            const float vals[4] = {v.x, v.y, v.z, v.w};
            #pragma unroll
            for (int e = 0; e < 4; e++) {
                const int k  = seg + q * 4 + e;
                const int kc = k >> 5;
                const int lp = ((k & 31) >> 3) * 16 + (row & 15);
                slA[((kc * 4 + mt) * 64 + lp) * 8 + (k & 7)] = f2bf(vals[e]);
            }
        }
    }
    __syncthreads();

    const int g  = w >> 1;      // main-GEMM row-group
    const int ch = w & 1;       // main-GEMM col-half

    v4f accM[2][8];
    #pragma unroll
    for (int s = 0; s < 2; s++)
        #pragma unroll
        for (int n = 0; n < 8; n++) accM[s][n] = (v4f){0.f, 0.f, 0.f, 0.f};

    hd_phase1(hdA[0], slA, WdhB, b_dh, 0, w, lane);
    __syncthreads();

    #pragma unroll 1
    for (int c = 0; c < 4; ++c) {
        if (c < 3)
            hd_phase1(hdA[(c + 1) & 1], slA, WdhB, b_dh, c + 1, w, lane);
        const unsigned short* buf = hdA[c & 1];
        #pragma unroll
        for (int kcgl = 0; kcgl < 4; ++kcgl) {
            const int kcg = c * 4 + kcgl;
            const v8s af0 = *reinterpret_cast<const v8s*>(&buf[((kcgl * 4 + g * 2 + 0) * 64 + lane) * 8]);
            const v8s af1 = *reinterpret_cast<const v8s*>(&buf[((kcgl * 4 + g * 2 + 1) * 64 + lane) * 8]);
            #pragma unroll
            for (int ntl = 0; ntl < 8; ntl++) {
                const int ntg = ch * 8 + ntl;
                const v8s bf = *reinterpret_cast<const v8s*>(
                    Wdo_frag + ((size_t)(ntg * 16 + kcg) * 64 + lane) * 8);
                accM[0][ntl] = __builtin_amdgcn_mfma_f32_16x16x32_bf16(af0, bf, accM[0][ntl], 0, 0, 0);
                accM[1][ntl] = __builtin_amdgcn_mfma_f32_16x16x32_bf16(af1, bf, accM[1][ntl], 0, 0, 0);
            }
        }
        __syncthreads();
    }
    // ---- epilogue: D col=lane&15 (Wdo col), row=(lane>>4)*4+j ----
    #pragma unroll
    for (int s = 0; s < 2; s++) {
        const int rowbase = rb + (g * 2 + s) * 16;
        #pragma unroll
        for (int ntl = 0; ntl < 8; ntl++) {
            const int col = ch * 128 + ntl * 16 + (lane & 15);
            const float bz = bias3[col];
            #pragma unroll
            for (int j = 0; j < 4; j++) {
                const size_t row = (size_t)(rowbase + (lane >> 4) * 4 + j);
                recon[row * 256 + col] = accM[s][ntl][j] + bz;
            }
        }
    }
}

// ---------------- host ----------------
extern "C" void kernel_launch(void* const* d_in, const int* in_sizes, int n_in,
                              void* d_out, int out_size, void* d_ws, size_t ws_size,
                              hipStream_t stream)
{
    const float* x        = (const float*)d_in[0];
    const float* pre_bias = (const float*)d_in[1];
    const float* W_eh     = (const float*)d_in[2];
    const float* b_eh     = (const float*)d_in[3];
    const float* W_eo     = (const float*)d_in[4];
    const float* b_eo     = (const float*)d_in[5];
    const float* lat_b    = (const float*)d_in[6];
    const float* W_dh     = (const float*)d_in[7];
    const float* b_dh     = (const float*)d_in[8];
    const float* W_do     = (const float*)d_in[9];
    const float* b_do     = (const float*)d_in[10];
    const float* dec_b    = (const float*)d_in[11];

    float* out = (float*)d_out;
    float* recon_out = out;
    float* sl_out    = out + (size_t)B_TOT * 256;
    float* pre_out   = sl_out + (size_t)B_TOT * 64;
    float* mask_out  = pre_out + (size_t)B_TOT * 64;
    float* spars_out = mask_out + (size_t)B_TOT * 64;

    char* ws = (char*)d_ws;
    unsigned short* WdhB  = (unsigned short*)ws;            // 64 KB (of 128 KB slot)
    float* bias3          = (float*)(ws + 131072);
    unsigned short* WdoF  = (unsigned short*)(ws + 132096);
    unsigned short* WehHi = (unsigned short*)(ws + 394240);
    unsigned short* WehLo = (unsigned short*)(ws + 656384);
    unsigned short* WeoHi = (unsigned short*)(ws + 918528);
    unsigned short* WeoLo = (unsigned short*)(ws + 984064);
    int* fcount           = (int*)(ws + 1049600);
    int* flist            = (int*)(ws + 1049664);
    unsigned short* hHi   = (unsigned short*)(ws + 1049664 + 524288);
    unsigned short* hLo   = hHi + (size_t)B_TOT * 512;

    k_prep<<<32, 256, 0, stream>>>(W_dh, b_do, dec_b, pre_bias, W_do, W_eh, W_eo,
                                   WdhB, bias3, WdoF, WehHi, WehLo, WeoHi, WeoLo,
                                   spars_out, fcount);

    k_enc1<<<B_TOT / 64, 512, 0, stream>>>(x, pre_bias, WehHi, WehLo, b_eh, hHi, hLo);

    k_enc2_topk<<<B_TOT / 128, 256, 0, stream>>>(hHi, hLo, WeoHi, WeoLo, b_eo, lat_b,
                                                 pre_out, mask_out, sl_out,
                                                 fcount, flist);

    k_repair<<<256, 256, 0, stream>>>(x, pre_bias, W_eh, b_eh, W_eo, b_eo, lat_b,
                                      fcount, flist, pre_out, mask_out, sl_out);

    k_dec<<<B_TOT / 64, 256, 0, stream>>>(sl_out, b_dh, WdhB, WdoF, bias3, recon_out);
}

// Round 17
// 407.120 us; speedup vs baseline: 1.9633x; 1.1697x over previous
//
#include <hip/hip_runtime.h>
#include <stdint.h>

#define B_TOT 131072
#define GAP_TAU 2.5e-4f

typedef short v8s __attribute__((ext_vector_type(8)));
typedef float v4f __attribute__((ext_vector_type(4)));

__device__ __forceinline__ unsigned short f2bf(float f) {
    union { float f; unsigned u; } v; v.f = f;
    unsigned u = v.u;
    u += 0x7fffu + ((u >> 16) & 1u);      // RNE
    return (unsigned short)(u >> 16);
}
__device__ __forceinline__ float bf2f(unsigned short s) {
    union { unsigned u; float f; } v; v.u = ((unsigned)s) << 16;
    return v.f;
}
__device__ __forceinline__ unsigned pack2(float lo, float hi) {
    return (unsigned)f2bf(lo) | ((unsigned)f2bf(hi) << 16);
}

// ---------------- K0: prep (weights swizzle + transposes + fcount zero) ----------------
__global__ void k_prep(const float* __restrict__ W_dh,      // [512][64]
                       const float* __restrict__ b_do,
                       const float* __restrict__ dec_b,
                       const float* __restrict__ pre_bias,
                       const float* __restrict__ W_do,
                       const float* __restrict__ W_eh,
                       const float* __restrict__ W_eo,
                       unsigned short* __restrict__ WdhB,    // hd-GEMM W-frags [32ht][2kc][64][8]
                       float* __restrict__ bias3,
                       unsigned short* __restrict__ Wdo_frag,
                       unsigned short* __restrict__ WehHi,
                       unsigned short* __restrict__ WehLo,
                       unsigned short* __restrict__ WeoHi,
                       unsigned short* __restrict__ WeoLo,
                       float* __restrict__ WehT,             // fp32 [256][512]
                       float* __restrict__ WeoT,             // fp32 [512][64]
                       float* __restrict__ spars_out,
                       int* __restrict__ fcount)
{
    int t = blockIdx.x * blockDim.x + threadIdx.x;
    int nthr = gridDim.x * blockDim.x;
    // WdhB: frag (ht,kc,lane): W_dh[ht*16+(lane&15)][kc*32+(lane>>4)*8 + i]
    for (int g = t; g < 32 * 2 * 64; g += nthr) {
        int lane = g & 63;
        int rem = g >> 6;
        int kc = rem & 1, ht = rem >> 1;
        int h = ht * 16 + (lane & 15);
        int l = kc * 32 + (lane >> 4) * 8;
        const float* src = &W_dh[(size_t)h * 64 + l];
        unsigned short* dst = &WdhB[(size_t)g * 8];
        #pragma unroll
        for (int i = 0; i < 8; i++) dst[i] = f2bf(src[i]);
    }
    for (int g = t; g < 16384; g += nthr) {     // Wdo B-frag
        int lane = g & 63;
        int q = g >> 6;
        int nt = q >> 4, kc = q & 15;
        int col = nt * 16 + (lane & 15);
        int kbase = kc * 32 + (lane >> 4) * 8;
        const float* src = &W_do[(size_t)col * 512 + kbase];
        unsigned short* dst = &Wdo_frag[(size_t)g * 8];
        #pragma unroll
        for (int i = 0; i < 8; i++) dst[i] = f2bf(src[i]);
    }
    for (int g = t; g < 32 * 8 * 64; g += nthr) {   // W_eh hi/lo A-frag
        int lane = g & 63;
        int rem = g >> 6;
        int kcg = rem & 7, ct = rem >> 3;
        int c = ct * 16 + (lane & 15);
        int k = kcg * 32 + (lane >> 4) * 8;
        const float* src = &W_eh[(size_t)c * 256 + k];
        #pragma unroll
        for (int i = 0; i < 8; i++) {
            unsigned short hi = f2bf(src[i]);
            WehHi[(size_t)g * 8 + i] = hi;
            WehLo[(size_t)g * 8 + i] = f2bf(src[i] - bf2f(hi));
        }
    }
    for (int g = t; g < 4 * 16 * 64; g += nthr) {   // W_eo hi/lo A-frag
        int lane = g & 63;
        int rem = g >> 6;
        int kcg = rem & 15, lt = rem >> 4;
        int l = lt * 16 + (lane & 15);
        int k = kcg * 32 + (lane >> 4) * 8;
        const float* src = &W_eo[(size_t)l * 512 + k];
        #pragma unroll
        for (int i = 0; i < 8; i++) {
            unsigned short hi = f2bf(src[i]);
            WeoHi[(size_t)g * 8 + i] = hi;
            WeoLo[(size_t)g * 8 + i] = f2bf(src[i] - bf2f(hi));
        }
    }
    // fp32 transposes for repair (coalesced-read layouts)
    for (int i = t; i < 256 * 512; i += nthr) {     // WehT[k][j] = W_eh[j][k]
        int k = i >> 9, j = i & 511;
        WehT[i] = W_eh[(size_t)j * 256 + k];
    }
    for (int i = t; i < 512 * 64; i += nthr) {      // WeoT[k][l] = W_eo[l][k]
        int k = i >> 6, l = i & 63;
        WeoT[i] = W_eo[(size_t)l * 512 + k];
    }
    if (t < 256) bias3[t] = b_do[t] + dec_b[t] + pre_bias[t];
    if (t == 0) { spars_out[0] = 5.0f / 64.0f; *fcount = 0; }
}

// h planes OCTET layout: element H(row,k) = ((rowtile*64 + k/8)*16 + row%16)*8 + k%8

// ---------------- K1: h = relu((x-pb) @ W_eh^T + b_eh), split-bf16 MFMA ----------------
// 2-pass column split (register diet for 2 blocks/CU); accumulation order bit-identical.
__global__ __launch_bounds__(512, 4)
void k_enc1(const float* __restrict__ x,
            const float* __restrict__ pre_bias,
            const unsigned short* __restrict__ WehHi,
            const unsigned short* __restrict__ WehLo,
            const float* __restrict__ b_eh,
            unsigned short* __restrict__ hHi,   // octet layout
            unsigned short* __restrict__ hLo)
{
    __shared__ __align__(16) unsigned short aH[64 * 256];  // 32 KB, swizzled rows
    __shared__ __align__(16) unsigned short aL[64 * 256];  // 32 KB
    const int t    = threadIdx.x;
    const int lane = t & 63;
    const int w    = t >> 6;        // 0..7
    const int rb   = blockIdx.x * 64;

    #pragma unroll
    for (int i = 0; i < 4; i++) {
        const int f    = t + i * 512;       // 0..2047
        const int srow = f >> 5;            // 0..63
        const int kc   = (f >> 2) & 7;      // 0..7
        const int skq  = f & 3;             // 0..3
        const float* xp = &x[(size_t)(rb + srow) * 256 + kc * 32 + skq * 8];
        const float* pp = &pre_bias[kc * 32 + skq * 8];
        const float4 v0 = *reinterpret_cast<const float4*>(xp);
        const float4 v1 = *reinterpret_cast<const float4*>(xp + 4);
        const float4 p0 = *reinterpret_cast<const float4*>(pp);
        const float4 p1 = *reinterpret_cast<const float4*>(pp + 4);
        float fv[8] = {v0.x - p0.x, v0.y - p0.y, v0.z - p0.z, v0.w - p0.w,
                       v1.x - p1.x, v1.y - p1.y, v1.z - p1.z, v1.w - p1.w};
        unsigned hi2[4], lo2[4];
        #pragma unroll
        for (int q = 0; q < 4; q++) {
            unsigned short h0 = f2bf(fv[q * 2]), h1 = f2bf(fv[q * 2 + 1]);
            hi2[q] = (unsigned)h0 | ((unsigned)h1 << 16);
            lo2[q] = (unsigned)f2bf(fv[q * 2] - bf2f(h0)) | ((unsigned)f2bf(fv[q * 2 + 1] - bf2f(h1)) << 16);
        }
        const int off = srow * 512 + ((kc * 64 + skq * 16) ^ ((srow & 7) << 4));
        *reinterpret_cast<uint4*>((char*)aH + off) = *reinterpret_cast<uint4*>(hi2);
        *reinterpret_cast<uint4*>((char*)aL + off) = *reinterpret_cast<uint4*>(lo2);
    }
    __syncthreads();

    const int rt0 = rb >> 4;
    const int q   = lane >> 4;

    #pragma unroll 1
    for (int pass = 0; pass < 2; ++pass) {
        const int ct0 = w * 4 + pass * 2;

        v4f acc[4][2];
        #pragma unroll
        for (int i = 0; i < 4; i++)
            #pragma unroll
            for (int j = 0; j < 2; j++) acc[i][j] = (v4f){0.f, 0.f, 0.f, 0.f};

        #pragma unroll 2
        for (int kc = 0; kc < 8; ++kc) {
            v8s wh[2], wl[2];
            #pragma unroll
            for (int ntl = 0; ntl < 2; ntl++) {
                const size_t idx = ((size_t)((ct0 + ntl) * 8 + kc) * 64 + lane) * 8;
                wh[ntl] = *reinterpret_cast<const v8s*>(&WehHi[idx]);
                wl[ntl] = *reinterpret_cast<const v8s*>(&WehLo[idx]);
            }
            v8s ah[4], al[4];
            #pragma unroll
            for (int mt = 0; mt < 4; mt++) {
                const int row = mt * 16 + (lane & 15);
                const int off = row * 512 + ((kc * 64 + (lane >> 4) * 16) ^ ((row & 7) << 4));
                ah[mt] = *reinterpret_cast<const v8s*>((const char*)aH + off);
                al[mt] = *reinterpret_cast<const v8s*>((const char*)aL + off);
            }
            #pragma unroll
            for (int mt = 0; mt < 4; mt++) {
                #pragma unroll
                for (int ntl = 0; ntl < 2; ntl++) {
                    acc[mt][ntl] = __builtin_amdgcn_mfma_f32_16x16x32_bf16(wh[ntl], ah[mt], acc[mt][ntl], 0, 0, 0);
                    acc[mt][ntl] = __builtin_amdgcn_mfma_f32_16x16x32_bf16(wl[ntl], ah[mt], acc[mt][ntl], 0, 0, 0);
                    acc[mt][ntl] = __builtin_amdgcn_mfma_f32_16x16x32_bf16(wh[ntl], al[mt], acc[mt][ntl], 0, 0, 0);
                }
            }
        }
        // epilogue for this pass's 2 col-tiles
        #pragma unroll
        for (int mt = 0; mt < 4; mt++) {
            #pragma unroll
            for (int ntl = 0; ntl < 2; ntl++) {
                const int ct = ct0 + ntl;
                const int c  = ct * 16 + q * 4;
                const float4 be = *reinterpret_cast<const float4*>(&b_eh[c]);
                float h0 = fmaxf(acc[mt][ntl][0] + be.x, 0.f);
                float h1 = fmaxf(acc[mt][ntl][1] + be.y, 0.f);
                float h2 = fmaxf(acc[mt][ntl][2] + be.z, 0.f);
                float h3 = fmaxf(acc[mt][ntl][3] + be.w, 0.f);
                unsigned short s0 = f2bf(h0), s1 = f2bf(h1), s2 = f2bf(h2), s3 = f2bf(h3);
                uint2 phi = { (unsigned)s0 | ((unsigned)s1 << 16), (unsigned)s2 | ((unsigned)s3 << 16) };
                uint2 plo = { (unsigned)f2bf(h0 - bf2f(s0)) | ((unsigned)f2bf(h1 - bf2f(s1)) << 16),
                              (unsigned)f2bf(h2 - bf2f(s2)) | ((unsigned)f2bf(h3 - bf2f(s3)) << 16) };
                const int oct = ct * 2 + (q >> 1);
                const size_t base = (((size_t)(rt0 + mt) * 64 + oct) * 16 + (lane & 15)) * 8 + (q & 1) * 4;
                *reinterpret_cast<uint2*>(&hHi[base]) = phi;
                *reinterpret_cast<uint2*>(&hLo[base]) = plo;
            }
        }
    }
}

// ---------------- K2: pre_act (split-bf16 MFMA); top-5; gap-flag; outputs ----------------
// 128 rows/block; wave w owns row-tiles {2w, 2w+1} (32 rows); W frags shared across both.
__global__ __launch_bounds__(256, 4)
void k_enc2_topk(const unsigned short* __restrict__ hHi,   // octet layout
                 const unsigned short* __restrict__ hLo,
                 const unsigned short* __restrict__ WeoHi,
                 const unsigned short* __restrict__ WeoLo,
                 const float* __restrict__ b_eo,
                 const float* __restrict__ lat_b,
                 float* __restrict__ pre_out,
                 float* __restrict__ mask_out,
                 float* __restrict__ sl_out,
                 int*   __restrict__ fcount,
                 int*   __restrict__ flist)
{
    __shared__ float pa[128][68];
    __shared__ unsigned long long mbits[128];
    const int t    = threadIdx.x;
    const int lane = t & 63;
    const int w    = t >> 6;
    const int rb   = blockIdx.x * 128;
    const int rtA  = (rb >> 4) + w * 2;
    const int rtB  = rtA + 1;

    v4f acc[2][4];
    #pragma unroll
    for (int s = 0; s < 2; s++)
        #pragma unroll
        for (int i = 0; i < 4; i++) acc[s][i] = (v4f){0.f, 0.f, 0.f, 0.f};

    #pragma unroll 2
    for (int kcl = 0; kcl < 16; ++kcl) {
        const size_t baseA = ((size_t)(rtA * 64 + kcl * 4 + (lane >> 4)) * 16 + (lane & 15)) * 8;
        const size_t baseB = ((size_t)(rtB * 64 + kcl * 4 + (lane >> 4)) * 16 + (lane & 15)) * 8;
        const v8s hhA = *reinterpret_cast<const v8s*>(&hHi[baseA]);
        const v8s hlA = *reinterpret_cast<const v8s*>(&hLo[baseA]);
        const v8s hhB = *reinterpret_cast<const v8s*>(&hHi[baseB]);
        const v8s hlB = *reinterpret_cast<const v8s*>(&hLo[baseB]);
        #pragma unroll
        for (int lt = 0; lt < 4; lt++) {
            const size_t idx = ((size_t)(lt * 16 + kcl) * 64 + lane) * 8;
            const v8s wh = *reinterpret_cast<const v8s*>(&WeoHi[idx]);
            const v8s wl = *reinterpret_cast<const v8s*>(&WeoLo[idx]);
            acc[0][lt] = __builtin_amdgcn_mfma_f32_16x16x32_bf16(wh, hhA, acc[0][lt], 0, 0, 0);
            acc[0][lt] = __builtin_amdgcn_mfma_f32_16x16x32_bf16(wl, hhA, acc[0][lt], 0, 0, 0);
            acc[0][lt] = __builtin_amdgcn_mfma_f32_16x16x32_bf16(wh, hlA, acc[0][lt], 0, 0, 0);
            acc[1][lt] = __builtin_amdgcn_mfma_f32_16x16x32_bf16(wh, hhB, acc[1][lt], 0, 0, 0);
            acc[1][lt] = __builtin_amdgcn_mfma_f32_16x16x32_bf16(wl, hhB, acc[1][lt], 0, 0, 0);
            acc[1][lt] = __builtin_amdgcn_mfma_f32_16x16x32_bf16(wh, hlB, acc[1][lt], 0, 0, 0);
        }
    }
    #pragma unroll
    for (int s = 0; s < 2; s++) {
        const int row = w * 32 + s * 16 + (lane & 15);
        #pragma unroll
        for (int lt = 0; lt < 4; lt++) {
            const int l0 = lt * 16 + ((lane >> 4) << 2);
            const float4 be = *reinterpret_cast<const float4*>(&b_eo[l0]);
            const float4 lb = *reinterpret_cast<const float4*>(&lat_b[l0]);
            float4 o;
            o.x = acc[s][lt][0] + be.x + lb.x;
            o.y = acc[s][lt][1] + be.y + lb.y;
            o.z = acc[s][lt][2] + be.z + lb.z;
            o.w = acc[s][lt][3] + be.w + lb.w;
            *reinterpret_cast<float4*>(&pa[row][l0]) = o;
        }
    }
    __syncthreads();
    if (t < 128) {
        int r = t;
        unsigned long long used = 0ULL;
        float bv[5];
        #pragma unroll
        for (int p = 0; p < 5; p++) {
            float best = -3.402823466e38f; int bidx = 0;
            for (int j = 0; j < 64; j++) {
                float v = pa[r][j];
                if (!((used >> j) & 1ULL) && v > best) { best = v; bidx = j; }
            }
            used |= 1ULL << bidx;
            bv[p] = best;
        }
        mbits[r] = used;
        float v6 = -3.402823466e38f;
        for (int j = 0; j < 64; j++) {
            float v = pa[r][j];
            if (!((used >> j) & 1ULL) && v > v6) v6 = v;
        }
        if (bv[4] - v6 < GAP_TAU) {
            int slot = atomicAdd(fcount, 1);
            flist[slot] = rb + r;
        }
    }
    __syncthreads();
    // fully-coalesced output writes: 16 lanes x float4 = 4 consecutive rows per wave-instr
    {
        const int c = (t & 15) * 4;
        #pragma unroll
        for (int pass = 0; pass < 8; pass++) {
            const int row = pass * 16 + (t >> 4);
            const size_t gr = (size_t)(rb + row);
            const unsigned long long bits = mbits[row];
            const float p0 = pa[row][c + 0], p1 = pa[row][c + 1];
            const float p2 = pa[row][c + 2], p3 = pa[row][c + 3];
            const float m0 = (float)((bits >> (c + 0)) & 1ULL);
            const float m1 = (float)((bits >> (c + 1)) & 1ULL);
            const float m2 = (float)((bits >> (c + 2)) & 1ULL);
            const float m3 = (float)((bits >> (c + 3)) & 1ULL);
            float4 pv = {p0, p1, p2, p3};
            float4 mv = {m0, m1, m2, m3};
            float4 sv = {m0 * p0, m1 * p1, m2 * p2, m3 * p3};
            *reinterpret_cast<float4*>(&pre_out[gr * 64 + c])  = pv;
            *reinterpret_cast<float4*>(&mask_out[gr * 64 + c]) = mv;
            *reinterpret_cast<float4*>(&sl_out[gr * 64 + c])   = sv;
        }
    }
}

// ---------------- K2b: fp32 exact repair of gap-flagged rows ----------------
// Coalesced transposed-weight GEMVs + wave-parallel top-5. Accumulation order
// bit-identical to prior rounds (ascending k, same partial grouping).
__global__ __launch_bounds__(256)
void k_repair(const float* __restrict__ x,
              const float* __restrict__ pre_bias,
              const float* __restrict__ WehT,     // [256][512] fp32 transposed
              const float* __restrict__ b_eh,
              const float* __restrict__ WeoT,     // [512][64] fp32 transposed
              const float* __restrict__ b_eo,
              const float* __restrict__ lat_b,
              const int* __restrict__ fcount,
              const int* __restrict__ flist,
              float* __restrict__ pre_out,
              float* __restrict__ mask_out,
              float* __restrict__ sl_out)
{
    __shared__ float xs[256];
    __shared__ float hs[512];
    __shared__ float part[64][4];
    const int t = threadIdx.x;
    const int n = *fcount;
    #pragma unroll 1
    for (int it = blockIdx.x; it < n; it += gridDim.x) {
        const int r = flist[it];
        xs[t] = x[(size_t)r * 256 + t] - pre_bias[t];
        __syncthreads();
        // h GEMV: thread t owns j = t and j = t+256; coalesced WehT reads
        {
            float a0 = 0.f, a1 = 0.f;
            #pragma unroll 8
            for (int k = 0; k < 256; ++k) {
                const float xk = xs[k];
                a0 = fmaf(WehT[(size_t)k * 512 + t], xk, a0);
                a1 = fmaf(WehT[(size_t)k * 512 + t + 256], xk, a1);
            }
            hs[t]       = fmaxf(a0 + b_eh[t], 0.f);
            hs[t + 256] = fmaxf(a1 + b_eh[t + 256], 0.f);
        }
        __syncthreads();
        // pre_act partials: wave q covers k in [q*128, q*128+128); coalesced WeoT reads
        {
            const int l = t & 63, q = t >> 6;
            float acc = 0.f;
            const int k0 = q * 128;
            #pragma unroll 8
            for (int k = k0; k < k0 + 128; ++k)
                acc = fmaf(WeoT[(size_t)k * 64 + l], hs[k], acc);
            part[l][q] = acc;
        }
        __syncthreads();
        // wave 0: assemble pre_act, wave-parallel top-5, write outputs
        if (t < 64) {
            const float v = ((part[t][0] + part[t][1]) + (part[t][2] + part[t][3]))
                            + b_eo[t] + lat_b[t];
            unsigned long long used = 0ULL;
            #pragma unroll
            for (int p = 0; p < 5; p++) {
                float cand = ((used >> t) & 1ULL) ? -3.402823466e38f : v;
                float m = cand;
                #pragma unroll
                for (int off = 1; off < 64; off <<= 1)
                    m = fmaxf(m, __shfl_xor(m, off));
                const unsigned long long msk = __ballot(cand == m);
                const int idx = __ffsll((long long)msk) - 1;
                used |= 1ULL << idx;
            }
            const size_t gr = (size_t)r;
            const float mb = (float)((used >> t) & 1ULL);
            pre_out[gr * 64 + t]  = v;
            mask_out[gr * 64 + t] = mb;
            sl_out[gr * 64 + t]   = mb * v;
        }
        __syncthreads();
    }
}

// ---------------- K3 phase 1: hd-tile GEMM (swapped operands -> A-frag-native D) ----------------
__device__ __forceinline__ void hd_phase1(unsigned short* __restrict__ buf,
                                          const unsigned short* __restrict__ slA,
                                          const unsigned short* __restrict__ WdhB,
                                          const float* __restrict__ b_dh,
                                          int c, int w, int lane)
{
    v4f ah[2][4];
    #pragma unroll
    for (int htl = 0; htl < 2; htl++) {
        const int h0 = (c * 8 + w * 2 + htl) * 16 + ((lane >> 4) << 2);
        const float4 bd = *reinterpret_cast<const float4*>(&b_dh[h0]);
        #pragma unroll
        for (int mt = 0; mt < 4; mt++) ah[htl][mt] = (v4f){bd.x, bd.y, bd.z, bd.w};
    }
    #pragma unroll
    for (int kc = 0; kc < 2; kc++) {
        v8s sa[4];
        #pragma unroll
        for (int mt = 0; mt < 4; mt++)
            sa[mt] = *reinterpret_cast<const v8s*>(&slA[((kc * 4 + mt) * 64 + lane) * 8]);
        #pragma unroll
        for (int htl = 0; htl < 2; htl++) {
            const int ht = c * 8 + w * 2 + htl;
            const v8s wb = *reinterpret_cast<const v8s*>(&WdhB[((size_t)(ht * 2 + kc) * 64 + lane) * 8]);
            #pragma unroll
            for (int mt = 0; mt < 4; mt++)
                ah[htl][mt] = __builtin_amdgcn_mfma_f32_16x16x32_bf16(wb, sa[mt], ah[htl][mt], 0, 0, 0);
        }
    }
    #pragma unroll
    for (int htl = 0; htl < 2; htl++) {
        const int hbase = (w * 2 + htl) * 16 + ((lane >> 4) << 2);   // h within 128-chunk
        const int kcgl  = hbase >> 5;
        const int lp    = (((hbase & 31) >> 3) << 4) + (lane & 15);
        const int ii    = hbase & 7;                                 // 0 or 4
        #pragma unroll
        for (int mt = 0; mt < 4; mt++) {
            uint2 o;
            o.x = pack2(fmaxf(ah[htl][mt][0], 0.f), fmaxf(ah[htl][mt][1], 0.f));
            o.y = pack2(fmaxf(ah[htl][mt][2], 0.f), fmaxf(ah[htl][mt][3], 0.f));
            *reinterpret_cast<uint2*>(&buf[((kcgl * 4 + mt) * 64 + lp) * 8 + ii]) = o;
        }
    }
}

// ---------------- K3: recon fully via MFMA, double-buffered hd, 1 barrier/chunk ----------------
__global__ __launch_bounds__(256)
void k_dec(const float* __restrict__ sl,              // [B][64] f32 (post-repair)
           const float* __restrict__ b_dh,            // [512]
           const unsigned short* __restrict__ WdhB,
           const unsigned short* __restrict__ Wdo_frag,
           const float* __restrict__ bias3,
           float* __restrict__ recon)                 // global [B][256]
{
    __shared__ __align__(16) unsigned short slA[2 * 4 * 64 * 8];      // 4 KB
    __shared__ __align__(16) unsigned short hdA[2][4 * 4 * 64 * 8];   // 2 x 16 KB
    const int t    = threadIdx.x;
    const int rb   = blockIdx.x * 64;
    const int lane = t & 63;
    const int w    = t >> 6;

    // ---- stage sl rows as bf16 frags ----
    {
        const int row = t >> 2;
        const int seg = (t & 3) * 16;
        const float* sp = &sl[(size_t)(rb + row) * 64 + seg];
        const int mt = row >> 4;
        #pragma unroll
        for (int q = 0; q < 4; q++) {
            const float4 v = *reinterpret_cast<const float4*>(sp + q * 4);
            const float vals[4] = {v.x, v.y, v.z, v.w};
            #pragma unroll
            for (int e = 0; e < 4; e++) {
                const int k  = seg + q * 4 + e;
                const int kc = k >> 5;
                const int lp = ((k & 31) >> 3) * 16 + (row & 15);
                slA[((kc * 4 + mt) * 64 + lp) * 8 + (k & 7)] = f2bf(vals[e]);
            }
        }
    }
    __syncthreads();

    const int g  = w >> 1;      // main-GEMM row-group
    const int ch = w & 1;       // main-GEMM col-half

    v4f accM[2][8];
    #pragma unroll
    for (int s = 0; s < 2; s++)
        #pragma unroll
        for (int n = 0; n < 8; n++) accM[s][n] = (v4f){0.f, 0.f, 0.f, 0.f};

    hd_phase1(hdA[0], slA, WdhB, b_dh, 0, w, lane);
    __syncthreads();

    #pragma unroll 1
    for (int c = 0; c < 4; ++c) {
        if (c < 3)
            hd_phase1(hdA[(c + 1) & 1], slA, WdhB, b_dh, c + 1, w, lane);
        const unsigned short* buf = hdA[c & 1];
        #pragma unroll
        for (int kcgl = 0; kcgl < 4; ++kcgl) {
            const int kcg = c * 4 + kcgl;
            const v8s af0 = *reinterpret_cast<const v8s*>(&buf[((kcgl * 4 + g * 2 + 0) * 64 + lane) * 8]);
            const v8s af1 = *reinterpret_cast<const v8s*>(&buf[((kcgl * 4 + g * 2 + 1) * 64 + lane) * 8]);
            #pragma unroll
            for (int ntl = 0; ntl < 8; ntl++) {
                const int ntg = ch * 8 + ntl;
                const v8s bf = *reinterpret_cast<const v8s*>(
                    Wdo_frag + ((size_t)(ntg * 16 + kcg) * 64 + lane) * 8);
                accM[0][ntl] = __builtin_amdgcn_mfma_f32_16x16x32_bf16(af0, bf, accM[0][ntl], 0, 0, 0);
                accM[1][ntl] = __builtin_amdgcn_mfma_f32_16x16x32_bf16(af1, bf, accM[1][ntl], 0, 0, 0);
            }
        }
        __syncthreads();
    }
    // ---- epilogue: D col=lane&15 (Wdo col), row=(lane>>4)*4+j ----
    #pragma unroll
    for (int s = 0; s < 2; s++) {
        const int rowbase = rb + (g * 2 + s) * 16;
        #pragma unroll
        for (int ntl = 0; ntl < 8; ntl++) {
            const int col = ch * 128 + ntl * 16 + (lane & 15);
            const float bz = bias3[col];
            #pragma unroll
            for (int j = 0; j < 4; j++) {
                const size_t row = (size_t)(rowbase + (lane >> 4) * 4 + j);
                recon[row * 256 + col] = accM[s][ntl][j] + bz;
            }
        }
    }
}

// ---------------- host ----------------
extern "C" void kernel_launch(void* const* d_in, const int* in_sizes, int n_in,
                              void* d_out, int out_size, void* d_ws, size_t ws_size,
                              hipStream_t stream)
{
    const float* x        = (const float*)d_in[0];
    const float* pre_bias = (const float*)d_in[1];
    const float* W_eh     = (const float*)d_in[2];
    const float* b_eh     = (const float*)d_in[3];
    const float* W_eo     = (const float*)d_in[4];
    const float* b_eo     = (const float*)d_in[5];
    const float* lat_b    = (const float*)d_in[6];
    const float* W_dh     = (const float*)d_in[7];
    const float* b_dh     = (const float*)d_in[8];
    const float* W_do     = (const float*)d_in[9];
    const float* b_do     = (const float*)d_in[10];
    const float* dec_b    = (const float*)d_in[11];

    float* out = (float*)d_out;
    float* recon_out = out;
    float* sl_out    = out + (size_t)B_TOT * 256;
    float* pre_out   = sl_out + (size_t)B_TOT * 64;
    float* mask_out  = pre_out + (size_t)B_TOT * 64;
    float* spars_out = mask_out + (size_t)B_TOT * 64;

    char* ws = (char*)d_ws;
    unsigned short* WdhB  = (unsigned short*)ws;            // 64 KB (of 128 KB slot)
    float* bias3          = (float*)(ws + 131072);
    unsigned short* WdoF  = (unsigned short*)(ws + 132096);
    unsigned short* WehHi = (unsigned short*)(ws + 394240);
    unsigned short* WehLo = (unsigned short*)(ws + 656384);
    unsigned short* WeoHi = (unsigned short*)(ws + 918528);
    unsigned short* WeoLo = (unsigned short*)(ws + 984064);
    int* fcount           = (int*)(ws + 1049600);
    int* flist            = (int*)(ws + 1049664);           // 512 KB
    float* WehT           = (float*)(ws + 1573952);         // 512 KB
    float* WeoT           = (float*)(ws + 2098240);         // 128 KB
    unsigned short* hHi   = (unsigned short*)(ws + 2229312);
    unsigned short* hLo   = hHi + (size_t)B_TOT * 512;

    k_prep<<<32, 256, 0, stream>>>(W_dh, b_do, dec_b, pre_bias, W_do, W_eh, W_eo,
                                   WdhB, bias3, WdoF, WehHi, WehLo, WeoHi, WeoLo,
                                   WehT, WeoT, spars_out, fcount);

    k_enc1<<<B_TOT / 64, 512, 0, stream>>>(x, pre_bias, WehHi, WehLo, b_eh, hHi, hLo);

    k_enc2_topk<<<B_TOT / 128, 256, 0, stream>>>(hHi, hLo, WeoHi, WeoLo, b_eo, lat_b,
                                                 pre_out, mask_out, sl_out,
                                                 fcount, flist);

    k_repair<<<256, 256, 0, stream>>>(x, pre_bias, WehT, b_eh, WeoT, b_eo, lat_b,
                                      fcount, flist, pre_out, mask_out, sl_out);

    k_dec<<<B_TOT / 64, 256, 0, stream>>>(sl_out, b_dh, WdhB, WdoF, bias3, recon_out);
}

// Round 18
// 404.118 us; speedup vs baseline: 1.9778x; 1.0074x over previous
//
#include <hip/hip_runtime.h>
#include <hip/hip_bf16.h>
#include <stdint.h>

#define B_TOT 131072
#define GAP_TAU 2.5e-4f

typedef short v8s __attribute__((ext_vector_type(8)));
typedef float v4f __attribute__((ext_vector_type(4)));

// Native RNE conversion: compiler emits v_cvt_pk_bf16_f32 for pairs (T12/m240).
// Bit-identical to integer-RNE for normal inputs.
__device__ __forceinline__ unsigned short f2bf(float f) {
    union { __hip_bfloat16 b; unsigned short s; } v;
    v.b = __float2bfloat16(f);
    return v.s;
}
__device__ __forceinline__ float bf2f(unsigned short s) {
    union { unsigned u; float f; } v; v.u = ((unsigned)s) << 16;
    return v.f;
}
__device__ __forceinline__ unsigned pack2(float lo, float hi) {
    return (unsigned)f2bf(lo) | ((unsigned)f2bf(hi) << 16);
}

// ---------------- K0: prep (weights swizzle + transposes + fcount zero) ----------------
__global__ void k_prep(const float* __restrict__ W_dh,      // [512][64]
                       const float* __restrict__ b_do,
                       const float* __restrict__ dec_b,
                       const float* __restrict__ pre_bias,
                       const float* __restrict__ W_do,
                       const float* __restrict__ W_eh,
                       const float* __restrict__ W_eo,
                       unsigned short* __restrict__ WdhB,    // hd-GEMM W-frags [32ht][2kc][64][8]
                       float* __restrict__ bias3,
                       unsigned short* __restrict__ Wdo_frag,
                       unsigned short* __restrict__ WehHi,
                       unsigned short* __restrict__ WehLo,
                       unsigned short* __restrict__ WeoHi,
                       unsigned short* __restrict__ WeoLo,
                       float* __restrict__ WehT,             // fp32 [256][512]
                       float* __restrict__ WeoT,             // fp32 [512][64]
                       float* __restrict__ spars_out,
                       int* __restrict__ fcount)
{
    int t = blockIdx.x * blockDim.x + threadIdx.x;
    int nthr = gridDim.x * blockDim.x;
    for (int g = t; g < 32 * 2 * 64; g += nthr) {
        int lane = g & 63;
        int rem = g >> 6;
        int kc = rem & 1, ht = rem >> 1;
        int h = ht * 16 + (lane & 15);
        int l = kc * 32 + (lane >> 4) * 8;
        const float* src = &W_dh[(size_t)h * 64 + l];
        unsigned short* dst = &WdhB[(size_t)g * 8];
        #pragma unroll
        for (int i = 0; i < 8; i++) dst[i] = f2bf(src[i]);
    }
    for (int g = t; g < 16384; g += nthr) {     // Wdo B-frag
        int lane = g & 63;
        int q = g >> 6;
        int nt = q >> 4, kc = q & 15;
        int col = nt * 16 + (lane & 15);
        int kbase = kc * 32 + (lane >> 4) * 8;
        const float* src = &W_do[(size_t)col * 512 + kbase];
        unsigned short* dst = &Wdo_frag[(size_t)g * 8];
        #pragma unroll
        for (int i = 0; i < 8; i++) dst[i] = f2bf(src[i]);
    }
    for (int g = t; g < 32 * 8 * 64; g += nthr) {   // W_eh hi/lo A-frag
        int lane = g & 63;
        int rem = g >> 6;
        int kcg = rem & 7, ct = rem >> 3;
        int c = ct * 16 + (lane & 15);
        int k = kcg * 32 + (lane >> 4) * 8;
        const float* src = &W_eh[(size_t)c * 256 + k];
        #pragma unroll
        for (int i = 0; i < 8; i++) {
            unsigned short hi = f2bf(src[i]);
            WehHi[(size_t)g * 8 + i] = hi;
            WehLo[(size_t)g * 8 + i] = f2bf(src[i] - bf2f(hi));
        }
    }
    for (int g = t; g < 4 * 16 * 64; g += nthr) {   // W_eo hi/lo A-frag
        int lane = g & 63;
        int rem = g >> 6;
        int kcg = rem & 15, lt = rem >> 4;
        int l = lt * 16 + (lane & 15);
        int k = kcg * 32 + (lane >> 4) * 8;
        const float* src = &W_eo[(size_t)l * 512 + k];
        #pragma unroll
        for (int i = 0; i < 8; i++) {
            unsigned short hi = f2bf(src[i]);
            WeoHi[(size_t)g * 8 + i] = hi;
            WeoLo[(size_t)g * 8 + i] = f2bf(src[i] - bf2f(hi));
        }
    }
    for (int i = t; i < 256 * 512; i += nthr) {     // WehT[k][j] = W_eh[j][k]
        int k = i >> 9, j = i & 511;
        WehT[i] = W_eh[(size_t)j * 256 + k];
    }
    for (int i = t; i < 512 * 64; i += nthr) {      // WeoT[k][l] = W_eo[l][k]
        int k = i >> 6, l = i & 63;
        WeoT[i] = W_eo[(size_t)l * 512 + k];
    }
    if (t < 256) bias3[t] = b_do[t] + dec_b[t] + pre_bias[t];
    if (t == 0) { spars_out[0] = 5.0f / 64.0f; *fcount = 0; }
}

// h planes OCTET layout: element H(row,k) = ((rowtile*64 + k/8)*16 + row%16)*8 + k%8

// ---------------- K1: h = relu((x-pb) @ W_eh^T + b_eh), split-bf16 MFMA ----------------
// 2-pass column split; native cvt; accumulation order bit-identical.
__global__ __launch_bounds__(512, 4)
void k_enc1(const float* __restrict__ x,
            const float* __restrict__ pre_bias,
            const unsigned short* __restrict__ WehHi,
            const unsigned short* __restrict__ WehLo,
            const float* __restrict__ b_eh,
            unsigned short* __restrict__ hHi,   // octet layout
            unsigned short* __restrict__ hLo)
{
    __shared__ __align__(16) unsigned short aH[64 * 256];  // 32 KB, swizzled rows
    __shared__ __align__(16) unsigned short aL[64 * 256];  // 32 KB
    const int t    = threadIdx.x;
    const int lane = t & 63;
    const int w    = t >> 6;        // 0..7
    const int rb   = blockIdx.x * 64;

    #pragma unroll
    for (int i = 0; i < 4; i++) {
        const int f    = t + i * 512;       // 0..2047
        const int srow = f >> 5;            // 0..63
        const int kc   = (f >> 2) & 7;      // 0..7
        const int skq  = f & 3;             // 0..3
        const float* xp = &x[(size_t)(rb + srow) * 256 + kc * 32 + skq * 8];
        const float* pp = &pre_bias[kc * 32 + skq * 8];
        const float4 v0 = *reinterpret_cast<const float4*>(xp);
        const float4 v1 = *reinterpret_cast<const float4*>(xp + 4);
        const float4 p0 = *reinterpret_cast<const float4*>(pp);
        const float4 p1 = *reinterpret_cast<const float4*>(pp + 4);
        float fv[8] = {v0.x - p0.x, v0.y - p0.y, v0.z - p0.z, v0.w - p0.w,
                       v1.x - p1.x, v1.y - p1.y, v1.z - p1.z, v1.w - p1.w};
        unsigned hi2[4], lo2[4];
        #pragma unroll
        for (int q = 0; q < 4; q++) {
            unsigned short h0 = f2bf(fv[q * 2]), h1 = f2bf(fv[q * 2 + 1]);
            hi2[q] = (unsigned)h0 | ((unsigned)h1 << 16);
            lo2[q] = pack2(fv[q * 2] - bf2f(h0), fv[q * 2 + 1] - bf2f(h1));
        }
        const int off = srow * 512 + ((kc * 64 + skq * 16) ^ ((srow & 7) << 4));
        *reinterpret_cast<uint4*>((char*)aH + off) = *reinterpret_cast<uint4*>(hi2);
        *reinterpret_cast<uint4*>((char*)aL + off) = *reinterpret_cast<uint4*>(lo2);
    }
    __syncthreads();

    const int rt0 = rb >> 4;
    const int q   = lane >> 4;

    #pragma unroll 1
    for (int pass = 0; pass < 2; ++pass) {
        const int ct0 = w * 4 + pass * 2;

        v4f acc[4][2];
        #pragma unroll
        for (int i = 0; i < 4; i++)
            #pragma unroll
            for (int j = 0; j < 2; j++) acc[i][j] = (v4f){0.f, 0.f, 0.f, 0.f};

        #pragma unroll 4
        for (int kc = 0; kc < 8; ++kc) {
            v8s wh[2], wl[2];
            #pragma unroll
            for (int ntl = 0; ntl < 2; ntl++) {
                const size_t idx = ((size_t)((ct0 + ntl) * 8 + kc) * 64 + lane) * 8;
                wh[ntl] = *reinterpret_cast<const v8s*>(&WehHi[idx]);
                wl[ntl] = *reinterpret_cast<const v8s*>(&WehLo[idx]);
            }
            v8s ah[4], al[4];
            #pragma unroll
            for (int mt = 0; mt < 4; mt++) {
                const int row = mt * 16 + (lane & 15);
                const int off = row * 512 + ((kc * 64 + (lane >> 4) * 16) ^ ((row & 7) << 4));
                ah[mt] = *reinterpret_cast<const v8s*>((const char*)aH + off);
                al[mt] = *reinterpret_cast<const v8s*>((const char*)aL + off);
            }
            #pragma unroll
            for (int mt = 0; mt < 4; mt++) {
                #pragma unroll
                for (int ntl = 0; ntl < 2; ntl++) {
                    acc[mt][ntl] = __builtin_amdgcn_mfma_f32_16x16x32_bf16(wh[ntl], ah[mt], acc[mt][ntl], 0, 0, 0);
                    acc[mt][ntl] = __builtin_amdgcn_mfma_f32_16x16x32_bf16(wl[ntl], ah[mt], acc[mt][ntl], 0, 0, 0);
                    acc[mt][ntl] = __builtin_amdgcn_mfma_f32_16x16x32_bf16(wh[ntl], al[mt], acc[mt][ntl], 0, 0, 0);
                }
            }
        }
        // epilogue for this pass's 2 col-tiles
        #pragma unroll
        for (int mt = 0; mt < 4; mt++) {
            #pragma unroll
            for (int ntl = 0; ntl < 2; ntl++) {
                const int ct = ct0 + ntl;
                const int c  = ct * 16 + q * 4;
                const float4 be = *reinterpret_cast<const float4*>(&b_eh[c]);
                float h0 = fmaxf(acc[mt][ntl][0] + be.x, 0.f);
                float h1 = fmaxf(acc[mt][ntl][1] + be.y, 0.f);
                float h2 = fmaxf(acc[mt][ntl][2] + be.z, 0.f);
                float h3 = fmaxf(acc[mt][ntl][3] + be.w, 0.f);
                unsigned short s0 = f2bf(h0), s1 = f2bf(h1), s2 = f2bf(h2), s3 = f2bf(h3);
                uint2 phi = { (unsigned)s0 | ((unsigned)s1 << 16), (unsigned)s2 | ((unsigned)s3 << 16) };
                uint2 plo = { pack2(h0 - bf2f(s0), h1 - bf2f(s1)),
                              pack2(h2 - bf2f(s2), h3 - bf2f(s3)) };
                const int oct = ct * 2 + (q >> 1);
                const size_t base = (((size_t)(rt0 + mt) * 64 + oct) * 16 + (lane & 15)) * 8 + (q & 1) * 4;
                *reinterpret_cast<uint2*>(&hHi[base]) = phi;
                *reinterpret_cast<uint2*>(&hLo[base]) = plo;
            }
        }
    }
}

// ---------------- K2: pre_act (split-bf16 MFMA); top-5; gap-flag; outputs ----------------
// 128 rows/block; wave w owns row-tiles {2w, 2w+1}; W frags shared across both.
__global__ __launch_bounds__(256, 4)
void k_enc2_topk(const unsigned short* __restrict__ hHi,   // octet layout
                 const unsigned short* __restrict__ hLo,
                 const unsigned short* __restrict__ WeoHi,
                 const unsigned short* __restrict__ WeoLo,
                 const float* __restrict__ b_eo,
                 const float* __restrict__ lat_b,
                 float* __restrict__ pre_out,
                 float* __restrict__ mask_out,
                 float* __restrict__ sl_out,
                 int*   __restrict__ fcount,
                 int*   __restrict__ flist)
{
    __shared__ float pa[128][68];
    __shared__ unsigned long long mbits[128];
    const int t    = threadIdx.x;
    const int lane = t & 63;
    const int w    = t >> 6;
    const int rb   = blockIdx.x * 128;
    const int rtA  = (rb >> 4) + w * 2;
    const int rtB  = rtA + 1;

    v4f acc[2][4];
    #pragma unroll
    for (int s = 0; s < 2; s++)
        #pragma unroll
        for (int i = 0; i < 4; i++) acc[s][i] = (v4f){0.f, 0.f, 0.f, 0.f};

    #pragma unroll 2
    for (int kcl = 0; kcl < 16; ++kcl) {
        const size_t baseA = ((size_t)(rtA * 64 + kcl * 4 + (lane >> 4)) * 16 + (lane & 15)) * 8;
        const size_t baseB = ((size_t)(rtB * 64 + kcl * 4 + (lane >> 4)) * 16 + (lane & 15)) * 8;
        const v8s hhA = *reinterpret_cast<const v8s*>(&hHi[baseA]);
        const v8s hlA = *reinterpret_cast<const v8s*>(&hLo[baseA]);
        const v8s hhB = *reinterpret_cast<const v8s*>(&hHi[baseB]);
        const v8s hlB = *reinterpret_cast<const v8s*>(&hLo[baseB]);
        #pragma unroll
        for (int lt = 0; lt < 4; lt++) {
            const size_t idx = ((size_t)(lt * 16 + kcl) * 64 + lane) * 8;
            const v8s wh = *reinterpret_cast<const v8s*>(&WeoHi[idx]);
            const v8s wl = *reinterpret_cast<const v8s*>(&WeoLo[idx]);
            acc[0][lt] = __builtin_amdgcn_mfma_f32_16x16x32_bf16(wh, hhA, acc[0][lt], 0, 0, 0);
            acc[0][lt] = __builtin_amdgcn_mfma_f32_16x16x32_bf16(wl, hhA, acc[0][lt], 0, 0, 0);
            acc[0][lt] = __builtin_amdgcn_mfma_f32_16x16x32_bf16(wh, hlA, acc[0][lt], 0, 0, 0);
            acc[1][lt] = __builtin_amdgcn_mfma_f32_16x16x32_bf16(wh, hhB, acc[1][lt], 0, 0, 0);
            acc[1][lt] = __builtin_amdgcn_mfma_f32_16x16x32_bf16(wl, hhB, acc[1][lt], 0, 0, 0);
            acc[1][lt] = __builtin_amdgcn_mfma_f32_16x16x32_bf16(wh, hlB, acc[1][lt], 0, 0, 0);
        }
    }
    #pragma unroll
    for (int s = 0; s < 2; s++) {
        const int row = w * 32 + s * 16 + (lane & 15);
        #pragma unroll
        for (int lt = 0; lt < 4; lt++) {
            const int l0 = lt * 16 + ((lane >> 4) << 2);
            const float4 be = *reinterpret_cast<const float4*>(&b_eo[l0]);
            const float4 lb = *reinterpret_cast<const float4*>(&lat_b[l0]);
            float4 o;
            o.x = acc[s][lt][0] + be.x + lb.x;
            o.y = acc[s][lt][1] + be.y + lb.y;
            o.z = acc[s][lt][2] + be.z + lb.z;
            o.w = acc[s][lt][3] + be.w + lb.w;
            *reinterpret_cast<float4*>(&pa[row][l0]) = o;
        }
    }
    __syncthreads();
    if (t < 128) {
        int r = t;
        unsigned long long used = 0ULL;
        float bv[5];
        #pragma unroll
        for (int p = 0; p < 5; p++) {
            float best = -3.402823466e38f; int bidx = 0;
            for (int j = 0; j < 64; j++) {
                float v = pa[r][j];
                if (!((used >> j) & 1ULL) && v > best) { best = v; bidx = j; }
            }
            used |= 1ULL << bidx;
            bv[p] = best;
        }
        mbits[r] = used;
        float v6 = -3.402823466e38f;
        for (int j = 0; j < 64; j++) {
            float v = pa[r][j];
            if (!((used >> j) & 1ULL) && v > v6) v6 = v;
        }
        if (bv[4] - v6 < GAP_TAU) {
            int slot = atomicAdd(fcount, 1);
            flist[slot] = rb + r;
        }
    }
    __syncthreads();
    {
        const int c = (t & 15) * 4;
        #pragma unroll
        for (int pass = 0; pass < 8; pass++) {
            const int row = pass * 16 + (t >> 4);
            const size_t gr = (size_t)(rb + row);
            const unsigned long long bits = mbits[row];
            const float p0 = pa[row][c + 0], p1 = pa[row][c + 1];
            const float p2 = pa[row][c + 2], p3 = pa[row][c + 3];
            const float m0 = (float)((bits >> (c + 0)) & 1ULL);
            const float m1 = (float)((bits >> (c + 1)) & 1ULL);
            const float m2 = (float)((bits >> (c + 2)) & 1ULL);
            const float m3 = (float)((bits >> (c + 3)) & 1ULL);
            float4 pv = {p0, p1, p2, p3};
            float4 mv = {m0, m1, m2, m3};
            float4 sv = {m0 * p0, m1 * p1, m2 * p2, m3 * p3};
            *reinterpret_cast<float4*>(&pre_out[gr * 64 + c])  = pv;
            *reinterpret_cast<float4*>(&mask_out[gr * 64 + c]) = mv;
            *reinterpret_cast<float4*>(&sl_out[gr * 64 + c])   = sv;
        }
    }
}

// ---------------- K2b: fp32 exact repair of gap-flagged rows ----------------
__global__ __launch_bounds__(256)
void k_repair(const float* __restrict__ x,
              const float* __restrict__ pre_bias,
              const float* __restrict__ WehT,     // [256][512] fp32 transposed
              const float* __restrict__ b_eh,
              const float* __restrict__ WeoT,     // [512][64] fp32 transposed
              const float* __restrict__ b_eo,
              const float* __restrict__ lat_b,
              const int* __restrict__ fcount,
              const int* __restrict__ flist,
              float* __restrict__ pre_out,
              float* __restrict__ mask_out,
              float* __restrict__ sl_out)
{
    __shared__ float xs[256];
    __shared__ float hs[512];
    __shared__ float part[64][4];
    const int t = threadIdx.x;
    const int n = *fcount;
    #pragma unroll 1
    for (int it = blockIdx.x; it < n; it += gridDim.x) {
        const int r = flist[it];
        xs[t] = x[(size_t)r * 256 + t] - pre_bias[t];
        __syncthreads();
        {
            float a0 = 0.f, a1 = 0.f;
            #pragma unroll 8
            for (int k = 0; k < 256; ++k) {
                const float xk = xs[k];
                a0 = fmaf(WehT[(size_t)k * 512 + t], xk, a0);
                a1 = fmaf(WehT[(size_t)k * 512 + t + 256], xk, a1);
            }
            hs[t]       = fmaxf(a0 + b_eh[t], 0.f);
            hs[t + 256] = fmaxf(a1 + b_eh[t + 256], 0.f);
        }
        __syncthreads();
        {
            const int l = t & 63, q = t >> 6;
            float acc = 0.f;
            const int k0 = q * 128;
            #pragma unroll 8
            for (int k = k0; k < k0 + 128; ++k)
                acc = fmaf(WeoT[(size_t)k * 64 + l], hs[k], acc);
            part[l][q] = acc;
        }
        __syncthreads();
        if (t < 64) {
            const float v = ((part[t][0] + part[t][1]) + (part[t][2] + part[t][3]))
                            + b_eo[t] + lat_b[t];
            unsigned long long used = 0ULL;
            #pragma unroll
            for (int p = 0; p < 5; p++) {
                float cand = ((used >> t) & 1ULL) ? -3.402823466e38f : v;
                float m = cand;
                #pragma unroll
                for (int off = 1; off < 64; off <<= 1)
                    m = fmaxf(m, __shfl_xor(m, off));
                const unsigned long long msk = __ballot(cand == m);
                const int idx = __ffsll((long long)msk) - 1;
                used |= 1ULL << idx;
            }
            const size_t gr = (size_t)r;
            const float mb = (float)((used >> t) & 1ULL);
            pre_out[gr * 64 + t]  = v;
            mask_out[gr * 64 + t] = mb;
            sl_out[gr * 64 + t]   = mb * v;
        }
        __syncthreads();
    }
}

// ---------------- K3 phase 1: hd-tile GEMM (swapped operands -> A-frag-native D) ----------------
__device__ __forceinline__ void hd_phase1(unsigned short* __restrict__ buf,
                                          const unsigned short* __restrict__ slA,
                                          const unsigned short* __restrict__ WdhB,
                                          const float* __restrict__ b_dh,
                                          int c, int w, int lane)
{
    v4f ah[2][4];
    #pragma unroll
    for (int htl = 0; htl < 2; htl++) {
        const int h0 = (c * 8 + w * 2 + htl) * 16 + ((lane >> 4) << 2);
        const float4 bd = *reinterpret_cast<const float4*>(&b_dh[h0]);
        #pragma unroll
        for (int mt = 0; mt < 4; mt++) ah[htl][mt] = (v4f){bd.x, bd.y, bd.z, bd.w};
    }
    #pragma unroll
    for (int kc = 0; kc < 2; kc++) {
        v8s sa[4];
        #pragma unroll
        for (int mt = 0; mt < 4; mt++)
            sa[mt] = *reinterpret_cast<const v8s*>(&slA[((kc * 4 + mt) * 64 + lane) * 8]);
        #pragma unroll
        for (int htl = 0; htl < 2; htl++) {
            const int ht = c * 8 + w * 2 + htl;
            const v8s wb = *reinterpret_cast<const v8s*>(&WdhB[((size_t)(ht * 2 + kc) * 64 + lane) * 8]);
            #pragma unroll
            for (int mt = 0; mt < 4; mt++)
                ah[htl][mt] = __builtin_amdgcn_mfma_f32_16x16x32_bf16(wb, sa[mt], ah[htl][mt], 0, 0, 0);
        }
    }
    #pragma unroll
    for (int htl = 0; htl < 2; htl++) {
        const int hbase = (w * 2 + htl) * 16 + ((lane >> 4) << 2);   // h within 128-chunk
        const int kcgl  = hbase >> 5;
        const int lp    = (((hbase & 31) >> 3) << 4) + (lane & 15);
        const int ii    = hbase & 7;                                 // 0 or 4
        #pragma unroll
        for (int mt = 0; mt < 4; mt++) {
            uint2 o;
            o.x = pack2(fmaxf(ah[htl][mt][0], 0.f), fmaxf(ah[htl][mt][1], 0.f));
            o.y = pack2(fmaxf(ah[htl][mt][2], 0.f), fmaxf(ah[htl][mt][3], 0.f));
            *reinterpret_cast<uint2*>(&buf[((kcgl * 4 + mt) * 64 + lp) * 8 + ii]) = o;
        }
    }
}

// ---------------- K3: recon fully via MFMA, double-buffered hd, 1 barrier/chunk ----------------
__global__ __launch_bounds__(256)
void k_dec(const float* __restrict__ sl,              // [B][64] f32 (post-repair)
           const float* __restrict__ b_dh,            // [512]
           const unsigned short* __restrict__ WdhB,
           const unsigned short* __restrict__ Wdo_frag,
           const float* __restrict__ bias3,
           float* __restrict__ recon)                 // global [B][256]
{
    __shared__ __align__(16) unsigned short slA[2 * 4 * 64 * 8];      // 4 KB
    __shared__ __align__(16) unsigned short hdA[2][4 * 4 * 64 * 8];   // 2 x 16 KB
    const int t    = threadIdx.x;
    const int rb   = blockIdx.x * 64;
    const int lane = t & 63;
    const int w    = t >> 6;

    {
        const int row = t >> 2;
        const int seg = (t & 3) * 16;
        const float* sp = &sl[(size_t)(rb + row) * 64 + seg];
        const int mt = row >> 4;
        #pragma unroll
        for (int q = 0; q < 4; q++) {
            const float4 v = *reinterpret_cast<const float4*>(sp + q * 4);
            const float vals[4] = {v.x, v.y, v.z, v.w};
            #pragma unroll
            for (int e = 0; e < 4; e++) {
                const int k  = seg + q * 4 + e;
                const int kc = k >> 5;
                const int lp = ((k & 31) >> 3) * 16 + (row & 15);
                slA[((kc * 4 + mt) * 64 + lp) * 8 + (k & 7)] = f2bf(vals[e]);
            }
        }
    }
    __syncthreads();

    const int g  = w >> 1;      // main-GEMM row-group
    const int ch = w & 1;       // main-GEMM col-half

    v4f accM[2][8];
    #pragma unroll
    for (int s = 0; s < 2; s++)
        #pragma unroll
        for (int n = 0; n < 8; n++) accM[s][n] = (v4f){0.f, 0.f, 0.f, 0.f};

    hd_phase1(hdA[0], slA, WdhB, b_dh, 0, w, lane);
    __syncthreads();

    #pragma unroll 1
    for (int c = 0; c < 4; ++c) {
        if (c < 3)
            hd_phase1(hdA[(c + 1) & 1], slA, WdhB, b_dh, c + 1, w, lane);
        const unsigned short* buf = hdA[c & 1];
        #pragma unroll
        for (int kcgl = 0; kcgl < 4; ++kcgl) {
            const int kcg = c * 4 + kcgl;
            const v8s af0 = *reinterpret_cast<const v8s*>(&buf[((kcgl * 4 + g * 2 + 0) * 64 + lane) * 8]);
            const v8s af1 = *reinterpret_cast<const v8s*>(&buf[((kcgl * 4 + g * 2 + 1) * 64 + lane) * 8]);
            #pragma unroll
            for (int ntl = 0; ntl < 8; ntl++) {
                const int ntg = ch * 8 + ntl;
                const v8s bf = *reinterpret_cast<const v8s*>(
                    Wdo_frag + ((size_t)(ntg * 16 + kcg) * 64 + lane) * 8);
                accM[0][ntl] = __builtin_amdgcn_mfma_f32_16x16x32_bf16(af0, bf, accM[0][ntl], 0, 0, 0);
                accM[1][ntl] = __builtin_amdgcn_mfma_f32_16x16x32_bf16(af1, bf, accM[1][ntl], 0, 0, 0);
            }
        }
        __syncthreads();
    }
    #pragma unroll
    for (int s = 0; s < 2; s++) {
        const int rowbase = rb + (g * 2 + s) * 16;
        #pragma unroll
        for (int ntl = 0; ntl < 8; ntl++) {
            const int col = ch * 128 + ntl * 16 + (lane & 15);
            const float bz = bias3[col];
            #pragma unroll
            for (int j = 0; j < 4; j++) {
                const size_t row = (size_t)(rowbase + (lane >> 4) * 4 + j);
                recon[row * 256 + col] = accM[s][ntl][j] + bz;
            }
        }
    }
}

// ---------------- host ----------------
extern "C" void kernel_launch(void* const* d_in, const int* in_sizes, int n_in,
                              void* d_out, int out_size, void* d_ws, size_t ws_size,
                              hipStream_t stream)
{
    const float* x        = (const float*)d_in[0];
    const float* pre_bias = (const float*)d_in[1];
    const float* W_eh     = (const float*)d_in[2];
    const float* b_eh     = (const float*)d_in[3];
    const float* W_eo     = (const float*)d_in[4];
    const float* b_eo     = (const float*)d_in[5];
    const float* lat_b    = (const float*)d_in[6];
    const float* W_dh     = (const float*)d_in[7];
    const float* b_dh     = (const float*)d_in[8];
    const float* W_do     = (const float*)d_in[9];
    const float* b_do     = (const float*)d_in[10];
    const float* dec_b    = (const float*)d_in[11];

    float* out = (float*)d_out;
    float* recon_out = out;
    float* sl_out    = out + (size_t)B_TOT * 256;
    float* pre_out   = sl_out + (size_t)B_TOT * 64;
    float* mask_out  = pre_out + (size_t)B_TOT * 64;
    float* spars_out = mask_out + (size_t)B_TOT * 64;

    char* ws = (char*)d_ws;
    unsigned short* WdhB  = (unsigned short*)ws;            // 64 KB (of 128 KB slot)
    float* bias3          = (float*)(ws + 131072);
    unsigned short* WdoF  = (unsigned short*)(ws + 132096);
    unsigned short* WehHi = (unsigned short*)(ws + 394240);
    unsigned short* WehLo = (unsigned short*)(ws + 656384);
    unsigned short* WeoHi = (unsigned short*)(ws + 918528);
    unsigned short* WeoLo = (unsigned short*)(ws + 984064);
    int* fcount           = (int*)(ws + 1049600);
    int* flist            = (int*)(ws + 1049664);           // 512 KB
    float* WehT           = (float*)(ws + 1573952);         // 512 KB
    float* WeoT           = (float*)(ws + 2098240);         // 128 KB
    unsigned short* hHi   = (unsigned short*)(ws + 2229312);
    unsigned short* hLo   = hHi + (size_t)B_TOT * 512;

    k_prep<<<32, 256, 0, stream>>>(W_dh, b_do, dec_b, pre_bias, W_do, W_eh, W_eo,
                                   WdhB, bias3, WdoF, WehHi, WehLo, WeoHi, WeoLo,
                                   WehT, WeoT, spars_out, fcount);

    k_enc1<<<B_TOT / 64, 512, 0, stream>>>(x, pre_bias, WehHi, WehLo, b_eh, hHi, hLo);

    k_enc2_topk<<<B_TOT / 128, 256, 0, stream>>>(hHi, hLo, WeoHi, WeoLo, b_eo, lat_b,
                                                 pre_out, mask_out, sl_out,
                                                 fcount, flist);

    k_repair<<<256, 256, 0, stream>>>(x, pre_bias, WehT, b_eh, WeoT, b_eo, lat_b,
                                      fcount, flist, pre_out, mask_out, sl_out);

    k_dec<<<B_TOT / 64, 256, 0, stream>>>(sl_out, b_dh, WdhB, WdoF, bias3, recon_out);
}